// Round 1
// baseline (3071.147 us; speedup 1.0000x reference)
//
#include <hip/hip_runtime.h>
#include <hip/hip_bf16.h>

// Problem constants
#define NTOK 2048
#define DIM 1024
#define NH 16
#define KVH 8
#define GQ 2
#define HD 64
#define WS 64
#define CBS 32
#define STRIDE 16
#define SEL_BLK 32
#define NSEL 4
#define NMEM 1
#define NCB 128          // N/STRIDE
#define NFB 64           // N/SEL_BLK
#define HIDN 2048        // CBS*HD
#define SCALE 0.125f
#define NEGF (-3.4028234663852886e38f)
#define NEG10F (-3.4028234663852886e37f)

// ---------------- RMSNorm ----------------
__global__ __launch_bounds__(256) void rmsnorm_kernel(const float* __restrict__ inp,
                                                      const float* __restrict__ g,
                                                      float* __restrict__ x) {
    int n = blockIdx.x;
    const float* row = inp + (size_t)n * DIM;
    float ss = 0.f;
    for (int c = threadIdx.x; c < DIM; c += 256) { float v = row[c]; ss += v * v; }
    __shared__ float red[4];
    for (int o = 32; o; o >>= 1) ss += __shfl_down(ss, o, 64);
    if ((threadIdx.x & 63) == 0) red[threadIdx.x >> 6] = ss;
    __syncthreads();
    if (threadIdx.x == 0) red[0] = red[0] + red[1] + red[2] + red[3];
    __syncthreads();
    float rs = 1.0f / sqrtf(red[0] / (float)DIM + 1.1920928955078125e-07f);
    float* xr = x + (size_t)n * DIM;
    for (int c = threadIdx.x; c < DIM; c += 256) xr[c] = row[c] * rs * g[c];
}

// ---------------- Generic GEMM: C = act(A@B + bias) ----------------
// A: MxK row-major, B: KxN row-major. ACT: 0 none, 1 relu, 2 sigmoid
template <int ACT>
__global__ __launch_bounds__(256) void gemm_bias_act(const float* __restrict__ A,
                                                     const float* __restrict__ B,
                                                     const float* __restrict__ bias,
                                                     float* __restrict__ C,
                                                     int M, int K, int N) {
    __shared__ float As[16][65];
    __shared__ float Bs[16][65];
    int tid = threadIdx.x;
    int tx = tid & 15, ty = tid >> 4;
    int m0 = blockIdx.y * 64;
    int n0 = blockIdx.x * 64;
    float acc[4][4] = {};
    for (int k0 = 0; k0 < K; k0 += 16) {
        for (int i = tid; i < 64 * 16; i += 256) {
            int m = i >> 4, k = i & 15;
            int gm = m0 + m, gk = k0 + k;
            As[k][m] = (gm < M && gk < K) ? A[(size_t)gm * K + gk] : 0.f;
        }
        for (int i = tid; i < 16 * 64; i += 256) {
            int k = i >> 6, nn = i & 63;
            int gk = k0 + k, gn = n0 + nn;
            Bs[k][nn] = (gk < K && gn < N) ? B[(size_t)gk * N + gn] : 0.f;
        }
        __syncthreads();
#pragma unroll
        for (int kk = 0; kk < 16; kk++) {
            float a[4], b[4];
#pragma unroll
            for (int r = 0; r < 4; r++) a[r] = As[kk][ty * 4 + r];
#pragma unroll
            for (int c = 0; c < 4; c++) b[c] = Bs[kk][tx * 4 + c];
#pragma unroll
            for (int r = 0; r < 4; r++)
#pragma unroll
                for (int c = 0; c < 4; c++) acc[r][c] += a[r] * b[c];
        }
        __syncthreads();
    }
    for (int r = 0; r < 4; r++) {
        int gm = m0 + ty * 4 + r;
        if (gm >= M) continue;
        for (int c = 0; c < 4; c++) {
            int gn = n0 + tx * 4 + c;
            if (gn >= N) continue;
            float v = acc[r][c];
            if (bias) v += bias[gn];
            if (ACT == 1) v = fmaxf(v, 0.f);
            else if (ACT == 2) v = 1.f / (1.f + expf(-v));
            C[(size_t)gm * N + gn] = v;
        }
    }
}

// ---------------- Build compressed windows (flattened MLP input) ----------------
// kwflat[r=h*128+i, c=j*64+d] = (p>=0 ? k[p,h,d] : 0) + k_pos[h,j,d], p=i*16+j-16
__global__ __launch_bounds__(256) void buildwin_kernel(const float* __restrict__ qkv,
                                                       const float* __restrict__ k_pos,
                                                       const float* __restrict__ v_pos,
                                                       float* __restrict__ kwflat,
                                                       float* __restrict__ vwflat) {
    size_t total = (size_t)(KVH * NCB) * HIDN;
    for (size_t e = (size_t)blockIdx.x * 256 + threadIdx.x; e < total;
         e += (size_t)gridDim.x * 256) {
        int r = (int)(e >> 11);
        int c = (int)(e & 2047);
        int j = c >> 6, d = c & 63;
        int h = r >> 7, i = r & 127;
        int p = i * STRIDE + j - (CBS - STRIDE);
        float kb = k_pos[((size_t)h * CBS + j) * HD + d];
        float vb = v_pos[((size_t)h * CBS + j) * HD + d];
        float kv = 0.f, vv = 0.f;
        if (p >= 0) {
            kv = qkv[(size_t)p * 2048 + 1024 + h * HD + d];
            vv = qkv[(size_t)p * 2048 + 1536 + h * HD + d];
        }
        kwflat[e] = kv + kb;
        vwflat[e] = vv + vb;
    }
}

// ---------------- RoPE + transpose ----------------
__global__ __launch_bounds__(256) void rope_kernel(const float* __restrict__ qkv,
                                                   float* __restrict__ rq,
                                                   float* __restrict__ rk,
                                                   float* __restrict__ vt) {
    int n = blockIdx.x;
    int t = threadIdx.x;
    // q: 16 heads * 32 pairs
    for (int idx = t; idx < NH * 32; idx += 256) {
        int h = idx >> 5, f = idx & 31;
        float inv = powf(10000.f, -((float)(2 * f)) / 64.f);
        float ang = (float)n * inv;
        float cc = cosf(ang), ssn = sinf(ang);
        float a = qkv[(size_t)n * 2048 + h * HD + 2 * f];
        float b = qkv[(size_t)n * 2048 + h * HD + 2 * f + 1];
        float* o = rq + ((size_t)h * NTOK + n) * HD + 2 * f;
        o[0] = a * cc - b * ssn;
        o[1] = b * cc + a * ssn;
    }
    // k: 8 heads * 32 pairs
    for (int idx = t; idx < KVH * 32; idx += 256) {
        int h = idx >> 5, f = idx & 31;
        float inv = powf(10000.f, -((float)(2 * f)) / 64.f);
        float ang = (float)n * inv;
        float cc = cosf(ang), ssn = sinf(ang);
        float a = qkv[(size_t)n * 2048 + 1024 + h * HD + 2 * f];
        float b = qkv[(size_t)n * 2048 + 1024 + h * HD + 2 * f + 1];
        float* o = rk + ((size_t)h * NTOK + n) * HD + 2 * f;
        o[0] = a * cc - b * ssn;
        o[1] = b * cc + a * ssn;
    }
    // v transpose copy
    for (int idx = t; idx < KVH * HD; idx += 256) {
        int h = idx >> 6, d = idx & 63;
        vt[((size_t)h * NTOK + n) * HD + d] = qkv[(size_t)n * 2048 + 1536 + h * HD + d];
    }
}

// ---------------- Compressed attention + importance ----------------
// block per (h, i); 129 keys (mem + 128 compressed)
__global__ __launch_bounds__(256) void cattn_kernel(const float* __restrict__ qkv,
                                                    const float* __restrict__ ckraw,
                                                    const float* __restrict__ cvraw,
                                                    const float* __restrict__ memkv,
                                                    float* __restrict__ cout,
                                                    float* __restrict__ imp) {
    int h = blockIdx.x >> 11;
    int i = blockIdx.x & 2047;
    int t = threadIdx.x;
    __shared__ float qs[2][64];
    __shared__ float sraw[2][129];
    __shared__ float prob[2][129];
    __shared__ float impl[64];
    __shared__ float impstat[2];
    if (t < 128) {
        int g = t >> 6, d = t & 63;
        qs[g][d] = qkv[(size_t)i * 2048 + (h * 2 + g) * HD + d];
    }
    __syncthreads();
    if (t < 129) {
        const float* kp = (t == 0) ? (memkv + h * HD)
                                   : (ckraw + ((size_t)h * NCB + (t - 1)) * HD);
        float s0 = 0.f, s1 = 0.f;
        for (int d = 0; d < 64; d++) {
            float kv = kp[d];
            s0 += qs[0][d] * kv;
            s1 += qs[1][d] * kv;
        }
        sraw[0][t] = s0 * SCALE;
        sraw[1][t] = s1 * SCALE;
    }
    __syncthreads();
    if (t < 64) {
        float v = 0.25f * (sraw[0][2 * t + 1] + sraw[0][2 * t + 2] +
                           sraw[1][2 * t + 1] + sraw[1][2 * t + 2]);
        if (t == (i >> 5)) v = NEGF;
        impl[t] = v;
    }
    __syncthreads();
    if (t < 2) {
        float m = NEGF;
        for (int j = 0; j < 129; j++) m = fmaxf(m, sraw[t][j]);
        float den = 0.f;
        for (int j = 0; j < 129; j++) {
            float e = expf(sraw[t][j] - m);
            prob[t][j] = e;
            den += e;
        }
        float invd = 1.f / den;
        for (int j = 0; j < 129; j++) prob[t][j] *= invd;
    } else if (t == 2) {
        float m = -1000.f;
        for (int j = 0; j < 64; j++) m = fmaxf(m, impl[j]);
        float den = expf(-1000.f - m);
        for (int j = 0; j < 64; j++) den += expf(impl[j] - m);
        impstat[0] = m;
        impstat[1] = 1.f / den;
    }
    __syncthreads();
    if (t < 128) {
        int g = t >> 6, d = t & 63;
        float o = 0.f;
        for (int j = 0; j < 129; j++) {
            const float* vp = (j == 0) ? (memkv + (KVH + h) * HD)
                                       : (cvraw + ((size_t)h * NCB + (j - 1)) * HD);
            o += prob[g][j] * vp[d];
        }
        cout[(((size_t)(h * 2 + g)) * NTOK + i) * HD + d] = o;
    }
    if (t < 64) {
        imp[((size_t)h * NTOK + i) * NFB + t] = expf(impl[t] - impstat[0]) * impstat[1];
    }
}

// ---------------- Top-k selection ----------------
__global__ __launch_bounds__(256) void topk_kernel(const float* __restrict__ imp,
                                                   int* __restrict__ selidx,
                                                   int* __restrict__ selmask) {
    int idx = blockIdx.x * 256 + threadIdx.x;
    if (idx >= KVH * NTOK) return;
    const float* ip = imp + (size_t)idx * NFB;
    float v[NFB];
    for (int j = 0; j < NFB; j++) v[j] = ip[j];
    unsigned long long taken = 0ull;
    int mk = 0;
    int i = idx & 2047;
    for (int p = 0; p < NSEL; p++) {
        float bv = NEGF;
        int bi = 0;
        for (int j = 0; j < NFB; j++) {
            if (!((taken >> j) & 1ull) && v[j] > bv) { bv = v[j]; bi = j; }
        }
        taken |= 1ull << bi;
        selidx[(size_t)idx * 5 + p] = bi;
        if (bv > 1e-10f) mk |= 1 << p;
    }
    selidx[(size_t)idx * 5 + 4] = i >> 5;
    selmask[idx] = mk;
}

// ---------------- Fine (selected) attention ----------------
__global__ __launch_bounds__(256) void fattn_kernel(const float* __restrict__ rq,
                                                    const float* __restrict__ rk,
                                                    const float* __restrict__ vt,
                                                    const int* __restrict__ selidx,
                                                    const int* __restrict__ selmask,
                                                    float* __restrict__ fout) {
    int h = blockIdx.x >> 11, i = blockIdx.x & 2047;
    int t = threadIdx.x;
    __shared__ float qs[2][64];
    __shared__ float s[2][160];
    __shared__ int selb[5];
    __shared__ int mk;
    if (t < 128) {
        int g = t >> 6, d = t & 63;
        qs[g][d] = rq[(((size_t)(h * 2 + g)) * NTOK + i) * HD + d];
    }
    if (t < 5) selb[t] = selidx[((size_t)h * NTOK + i) * 5 + t];
    if (t == 5) mk = selmask[h * NTOK + i];
    __syncthreads();
    if (t < 160) {
        int slot = t >> 5, jj = t & 31;
        int blk = selb[slot];
        int kpos = blk * SEL_BLK + jj;
        bool valid = (slot < 4) ? (((mk >> slot) & 1) != 0) : (jj <= (i & 31));
        const float* kp = rk + ((size_t)h * NTOK + kpos) * HD;
        float s0 = 0.f, s1 = 0.f;
        for (int d = 0; d < 64; d++) {
            float kv = kp[d];
            s0 += qs[0][d] * kv;
            s1 += qs[1][d] * kv;
        }
        s[0][t] = valid ? s0 * SCALE : NEG10F;
        s[1][t] = valid ? s1 * SCALE : NEG10F;
    }
    __syncthreads();
    if (t < 2) {
        float m = NEGF;
        for (int j = 0; j < 160; j++) m = fmaxf(m, s[t][j]);
        float den = 0.f;
        for (int j = 0; j < 160; j++) {
            float e = expf(s[t][j] - m);
            s[t][j] = e;
            den += e;
        }
        float inv = 1.f / den;
        for (int j = 0; j < 160; j++) s[t][j] *= inv;
    }
    __syncthreads();
    if (t < 128) {
        int g = t >> 6, d = t & 63;
        float o = 0.f;
        for (int j = 0; j < 160; j++) {
            int kpos = selb[j >> 5] * SEL_BLK + (j & 31);
            o += s[g][j] * vt[((size_t)h * NTOK + kpos) * HD + d];
        }
        fout[(((size_t)(h * 2 + g)) * NTOK + i) * HD + d] = o;
    }
}

// ---------------- Sliding-window attention ----------------
__global__ __launch_bounds__(256) void sattn_kernel(const float* __restrict__ rq,
                                                    const float* __restrict__ rk,
                                                    const float* __restrict__ vt,
                                                    float* __restrict__ sout) {
    int h = blockIdx.x >> 11, i = blockIdx.x & 2047;
    int t = threadIdx.x;
    __shared__ float qs[2][64];
    __shared__ float s[2][64];
    if (t < 128) {
        int g = t >> 6, d = t & 63;
        qs[g][d] = rq[(((size_t)(h * 2 + g)) * NTOK + i) * HD + d];
    }
    __syncthreads();
    if (t < 64) {
        int kpos = i - 63 + t;
        if (kpos >= 0) {
            const float* kp = rk + ((size_t)h * NTOK + kpos) * HD;
            float s0 = 0.f, s1 = 0.f;
            for (int d = 0; d < 64; d++) {
                float kv = kp[d];
                s0 += qs[0][d] * kv;
                s1 += qs[1][d] * kv;
            }
            s[0][t] = s0 * SCALE;
            s[1][t] = s1 * SCALE;
        } else {
            s[0][t] = NEGF;
            s[1][t] = NEGF;
        }
    }
    __syncthreads();
    if (t < 2) {
        float m = NEGF;
        for (int j = 0; j < 64; j++) m = fmaxf(m, s[t][j]);
        float den = 0.f;
        for (int j = 0; j < 64; j++) {
            float e = expf(s[t][j] - m);
            s[t][j] = e;
            den += e;
        }
        float inv = 1.f / den;
        for (int j = 0; j < 64; j++) s[t][j] *= inv;
    }
    __syncthreads();
    if (t < 128) {
        int g = t >> 6, d = t & 63;
        float o = 0.f;
        for (int j = 0; j < 64; j++) {
            int kpos = i - 63 + j;
            if (kpos >= 0) o += s[g][j] * vt[((size_t)h * NTOK + kpos) * HD + d];
        }
        sout[(((size_t)(h * 2 + g)) * NTOK + i) * HD + d] = o;
    }
}

// ---------------- Gated combine ----------------
__global__ __launch_bounds__(256) void combine_kernel(const float* __restrict__ gates,
                                                      const float* __restrict__ cout,
                                                      const float* __restrict__ fout,
                                                      const float* __restrict__ sout,
                                                      float* __restrict__ att) {
    int n = blockIdx.x;
    for (int c = threadIdx.x; c < NH * HD; c += 256) {
        int hd = c >> 6, d = c & 63;
        float g0 = gates[(size_t)n * (NH * 3) + hd * 3 + 0];
        float g1 = gates[(size_t)n * (NH * 3) + hd * 3 + 1];
        float g2 = gates[(size_t)n * (NH * 3) + hd * 3 + 2];
        size_t o = ((size_t)hd * NTOK + n) * HD + d;
        att[(size_t)n * (NH * HD) + c] = g0 * cout[o] + g1 * fout[o] + g2 * sout[o];
    }
}

extern "C" void kernel_launch(void* const* d_in, const int* in_sizes, int n_in,
                              void* d_out, int out_size, void* d_ws, size_t ws_size,
                              hipStream_t stream) {
    const float* inp    = (const float*)d_in[0];
    const float* norm_g = (const float*)d_in[1];
    const float* Wqkv   = (const float*)d_in[2];
    const float* mem_kv = (const float*)d_in[3];
    const float* k_pos  = (const float*)d_in[4];
    const float* v_pos  = (const float*)d_in[5];
    const float* kW1    = (const float*)d_in[6];
    const float* kb1    = (const float*)d_in[7];
    const float* kW2    = (const float*)d_in[8];
    const float* kb2    = (const float*)d_in[9];
    const float* vW1    = (const float*)d_in[10];
    const float* vb1    = (const float*)d_in[11];
    const float* vW2    = (const float*)d_in[12];
    const float* vb2    = (const float*)d_in[13];
    const float* combW  = (const float*)d_in[14];
    const float* combB  = (const float*)d_in[15];
    const float* Wout   = (const float*)d_in[16];
    float* out = (float*)d_out;

    float* ws = (float*)d_ws;
    size_t off = 0;
    auto alloc = [&](size_t n) { float* p = ws + off; off += n; return p; };
    float* x      = alloc((size_t)NTOK * DIM);          // 2M
    float* qkv    = alloc((size_t)NTOK * 2048);         // 4M
    float* kwflat = alloc((size_t)KVH * NCB * HIDN);    // 2M
    float* vwflat = alloc((size_t)KVH * NCB * HIDN);    // 2M
    float* hid    = alloc((size_t)KVH * NCB * HIDN);    // 2M (reused k then v)
    float* ckraw  = alloc((size_t)KVH * NCB * HD);      // 64K
    float* cvraw  = alloc((size_t)KVH * NCB * HD);      // 64K
    float* rq     = alloc((size_t)NH * NTOK * HD);      // 2M
    float* rk     = alloc((size_t)KVH * NTOK * HD);     // 1M
    float* vt     = alloc((size_t)KVH * NTOK * HD);     // 1M
    float* coutb  = alloc((size_t)NH * NTOK * HD);      // 2M
    float* foutb  = alloc((size_t)NH * NTOK * HD);      // 2M
    float* soutb  = alloc((size_t)NH * NTOK * HD);      // 2M
    float* impb   = alloc((size_t)KVH * NTOK * NFB);    // 1M
    float* gatesb = alloc((size_t)NTOK * NH * 3);       // 96K
    float* attb   = alloc((size_t)NTOK * DIM);          // 2M
    int* selidx   = (int*)(ws + off); off += (size_t)KVH * NTOK * 5;
    int* selmask  = (int*)(ws + off); off += (size_t)KVH * NTOK;
    (void)ws_size; (void)in_sizes; (void)n_in; (void)out_size;

    // 1. RMSNorm
    rmsnorm_kernel<<<NTOK, 256, 0, stream>>>(inp, norm_g, x);
    // 2. qkv = x @ Wqkv
    gemm_bias_act<0><<<dim3(32, 32), 256, 0, stream>>>(x, Wqkv, nullptr, qkv, NTOK, DIM, 2048);
    // 3. gates = sigmoid(x @ combW + combB)
    gemm_bias_act<2><<<dim3(1, 32), 256, 0, stream>>>(x, combW, combB, gatesb, NTOK, DIM, NH * 3);
    // 4. build compressed windows
    buildwin_kernel<<<4096, 256, 0, stream>>>(qkv, k_pos, v_pos, kwflat, vwflat);
    // 5. compressed-K MLP
    gemm_bias_act<1><<<dim3(32, 16), 256, 0, stream>>>(kwflat, kW1, kb1, hid, KVH * NCB, HIDN, HIDN);
    gemm_bias_act<0><<<dim3(1, 16), 256, 0, stream>>>(hid, kW2, kb2, ckraw, KVH * NCB, HIDN, HD);
    // 6. compressed-V MLP
    gemm_bias_act<1><<<dim3(32, 16), 256, 0, stream>>>(vwflat, vW1, vb1, hid, KVH * NCB, HIDN, HIDN);
    gemm_bias_act<0><<<dim3(1, 16), 256, 0, stream>>>(hid, vW2, vb2, cvraw, KVH * NCB, HIDN, HD);
    // 7. RoPE + transposes
    rope_kernel<<<NTOK, 256, 0, stream>>>(qkv, rq, rk, vt);
    // 8. compressed attention + importance softmax
    cattn_kernel<<<KVH * NTOK, 256, 0, stream>>>(qkv, ckraw, cvraw, mem_kv, coutb, impb);
    // 9. top-k block selection
    topk_kernel<<<(KVH * NTOK) / 256, 256, 0, stream>>>(impb, selidx, selmask);
    // 10. fine attention
    fattn_kernel<<<KVH * NTOK, 256, 0, stream>>>(rq, rk, vt, selidx, selmask, foutb);
    // 11. sliding-window attention
    sattn_kernel<<<KVH * NTOK, 256, 0, stream>>>(rq, rk, vt, soutb);
    // 12. gated combine
    combine_kernel<<<NTOK, 256, 0, stream>>>(gatesb, coutb, foutb, soutb, attb);
    // 13. out projection
    gemm_bias_act<0><<<dim3(16, 32), 256, 0, stream>>>(attb, Wout, nullptr, out, NTOK, DIM, DIM);
}

// Round 2
// 1680.064 us; speedup vs baseline: 1.8280x; 1.8280x over previous
//
#include <hip/hip_runtime.h>
#include <hip/hip_bf16.h>

// Problem constants
#define NTOK 2048
#define DIM 1024
#define NH 16
#define KVH 8
#define GQ 2
#define HD 64
#define WS 64
#define CBS 32
#define STRIDE 16
#define SEL_BLK 32
#define NSEL 4
#define NMEM 1
#define NCB 128          // N/STRIDE
#define NFB 64           // N/SEL_BLK
#define HIDN 2048        // CBS*HD
#define SCALE 0.125f
#define NEGF (-3.4028234663852886e38f)
#define NEG10F (-3.4028234663852886e37f)

typedef __attribute__((ext_vector_type(8))) short bf16x8;
typedef __attribute__((ext_vector_type(4))) float f32x4;

// ---------------- RMSNorm (writes fp32 x and bf16 xb) ----------------
__global__ __launch_bounds__(256) void rmsnorm_kernel(const float* __restrict__ inp,
                                                      const float* __restrict__ g,
                                                      float* __restrict__ x,
                                                      __hip_bfloat16* __restrict__ xb) {
    int n = blockIdx.x;
    const float* row = inp + (size_t)n * DIM;
    float ss = 0.f;
    for (int c = threadIdx.x; c < DIM; c += 256) { float v = row[c]; ss += v * v; }
    __shared__ float red[4];
    for (int o = 32; o; o >>= 1) ss += __shfl_down(ss, o, 64);
    if ((threadIdx.x & 63) == 0) red[threadIdx.x >> 6] = ss;
    __syncthreads();
    if (threadIdx.x == 0) red[0] = red[0] + red[1] + red[2] + red[3];
    __syncthreads();
    float rs = 1.0f / sqrtf(red[0] / (float)DIM + 1.1920928955078125e-07f);
    float* xr = x + (size_t)n * DIM;
    __hip_bfloat16* xbr = xb + (size_t)n * DIM;
    for (int c = threadIdx.x; c < DIM; c += 256) {
        float v = row[c] * rs * g[c];
        xr[c] = v;
        xbr[c] = __float2bfloat16(v);
    }
}

// ---------------- Transpose + cast fp32 B[K][N] -> bf16 Bt[N][K] ----------------
__global__ __launch_bounds__(256) void transpose_cast_kernel(const float* __restrict__ B,
                                                             __hip_bfloat16* __restrict__ Bt,
                                                             int K, int N) {
    __shared__ float tile[32][33];
    int n0 = blockIdx.x * 32, k0 = blockIdx.y * 32;
    int x = threadIdx.x & 31, y = threadIdx.x >> 5;  // y in 0..7
    for (int i = 0; i < 4; i++)
        tile[y + 8 * i][x] = B[(size_t)(k0 + y + 8 * i) * N + n0 + x];
    __syncthreads();
    for (int i = 0; i < 4; i++)
        Bt[(size_t)(n0 + y + 8 * i) * K + k0 + x] = __float2bfloat16(tile[x][y + 8 * i]);
}

// ---------------- bf16 MFMA GEMM: C = act(A @ Bt^T + bias) ----------------
// A: MxK bf16 row-major. Bt: NxK bf16 row-major (i.e. B transposed).
// C: MxN fp32. Requires M%128==0, N%128==0, K%32==0.
// Block = 256 threads = 4 waves in 2x2, each wave computes 64x64 via 4x4 MFMA tiles.
template <int ACT>
__global__ __launch_bounds__(256) void mfma_gemm(const __hip_bfloat16* __restrict__ A,
                                                 const __hip_bfloat16* __restrict__ Bt,
                                                 const float* __restrict__ bias,
                                                 float* __restrict__ C,
                                                 int M, int N, int K) {
    __shared__ __align__(16) short As[128 * 32];
    __shared__ __align__(16) short Bs[128 * 32];
    int tid = threadIdx.x;
    int lane = tid & 63, wave = tid >> 6;
    int wm = (wave >> 1) * 64, wn = (wave & 1) * 64;
    int m0 = blockIdx.y * 128, n0 = blockIdx.x * 128;
    f32x4 acc[4][4];
    for (int r = 0; r < 4; r++)
        for (int c = 0; c < 4; c++)
            acc[r][c] = (f32x4){0.f, 0.f, 0.f, 0.f};

    int r0 = tid >> 2, kc0 = tid & 3;           // staging unit 0
    int r1 = (tid + 256) >> 2, kc1 = tid & 3;   // staging unit 1 (rows 64..127)

    for (int k0 = 0; k0 < K; k0 += 32) {
        __syncthreads();
        *(uint4*)&As[r0 * 32 + kc0 * 8] =
            *(const uint4*)(A + (size_t)(m0 + r0) * K + k0 + kc0 * 8);
        *(uint4*)&As[r1 * 32 + kc1 * 8] =
            *(const uint4*)(A + (size_t)(m0 + r1) * K + k0 + kc1 * 8);
        *(uint4*)&Bs[r0 * 32 + kc0 * 8] =
            *(const uint4*)(Bt + (size_t)(n0 + r0) * K + k0 + kc0 * 8);
        *(uint4*)&Bs[r1 * 32 + kc1 * 8] =
            *(const uint4*)(Bt + (size_t)(n0 + r1) * K + k0 + kc1 * 8);
        __syncthreads();
        bf16x8 af[4], bfr[4];
#pragma unroll
        for (int r = 0; r < 4; r++)
            af[r] = *(const bf16x8*)&As[(wm + r * 16 + (lane & 15)) * 32 + (lane >> 4) * 8];
#pragma unroll
        for (int c = 0; c < 4; c++)
            bfr[c] = *(const bf16x8*)&Bs[(wn + c * 16 + (lane & 15)) * 32 + (lane >> 4) * 8];
#pragma unroll
        for (int r = 0; r < 4; r++)
#pragma unroll
            for (int c = 0; c < 4; c++)
                acc[r][c] = __builtin_amdgcn_mfma_f32_16x16x32_bf16(af[r], bfr[c], acc[r][c], 0, 0, 0);
    }
    // epilogue: C/D layout col=lane&15, row=(lane>>4)*4+reg
    for (int r = 0; r < 4; r++) {
        int grow = m0 + wm + r * 16 + (lane >> 4) * 4;
        for (int c = 0; c < 4; c++) {
            int gcol = n0 + wn + c * 16 + (lane & 15);
            float bv = bias ? bias[gcol] : 0.f;
#pragma unroll
            for (int v = 0; v < 4; v++) {
                float val = acc[r][c][v] + bv;
                if (ACT == 1) val = fmaxf(val, 0.f);
                C[(size_t)(grow + v) * N + gcol] = val;
            }
        }
    }
}

// ---------------- fp32 GEMM (small N): C = act(A@B + bias) ----------------
template <int ACT>
__global__ __launch_bounds__(256) void gemm_bias_act(const float* __restrict__ A,
                                                     const float* __restrict__ B,
                                                     const float* __restrict__ bias,
                                                     float* __restrict__ C,
                                                     int M, int K, int N) {
    __shared__ float As[16][65];
    __shared__ float Bs[16][65];
    int tid = threadIdx.x;
    int tx = tid & 15, ty = tid >> 4;
    int m0 = blockIdx.y * 64;
    int n0 = blockIdx.x * 64;
    float acc[4][4] = {};
    for (int k0 = 0; k0 < K; k0 += 16) {
        for (int i = tid; i < 64 * 16; i += 256) {
            int m = i >> 4, k = i & 15;
            int gm = m0 + m, gk = k0 + k;
            As[k][m] = (gm < M && gk < K) ? A[(size_t)gm * K + gk] : 0.f;
        }
        for (int i = tid; i < 16 * 64; i += 256) {
            int k = i >> 6, nn = i & 63;
            int gk = k0 + k, gn = n0 + nn;
            Bs[k][nn] = (gk < K && gn < N) ? B[(size_t)gk * N + gn] : 0.f;
        }
        __syncthreads();
#pragma unroll
        for (int kk = 0; kk < 16; kk++) {
            float a[4], b[4];
#pragma unroll
            for (int r = 0; r < 4; r++) a[r] = As[kk][ty * 4 + r];
#pragma unroll
            for (int c = 0; c < 4; c++) b[c] = Bs[kk][tx * 4 + c];
#pragma unroll
            for (int r = 0; r < 4; r++)
#pragma unroll
                for (int c = 0; c < 4; c++) acc[r][c] += a[r] * b[c];
        }
        __syncthreads();
    }
    for (int r = 0; r < 4; r++) {
        int gm = m0 + ty * 4 + r;
        if (gm >= M) continue;
        for (int c = 0; c < 4; c++) {
            int gn = n0 + tx * 4 + c;
            if (gn >= N) continue;
            float v = acc[r][c];
            if (bias) v += bias[gn];
            if (ACT == 1) v = fmaxf(v, 0.f);
            else if (ACT == 2) v = 1.f / (1.f + expf(-v));
            C[(size_t)gm * N + gn] = v;
        }
    }
}

// ---------------- Build compressed windows (bf16 MLP input) ----------------
__global__ __launch_bounds__(256) void buildwin_kernel(const float* __restrict__ qkv,
                                                       const float* __restrict__ k_pos,
                                                       const float* __restrict__ v_pos,
                                                       __hip_bfloat16* __restrict__ kwflat,
                                                       __hip_bfloat16* __restrict__ vwflat) {
    size_t total = (size_t)(KVH * NCB) * HIDN;
    for (size_t e = (size_t)blockIdx.x * 256 + threadIdx.x; e < total;
         e += (size_t)gridDim.x * 256) {
        int r = (int)(e >> 11);
        int c = (int)(e & 2047);
        int j = c >> 6, d = c & 63;
        int h = r >> 7, i = r & 127;
        int p = i * STRIDE + j - (CBS - STRIDE);
        float kb = k_pos[((size_t)h * CBS + j) * HD + d];
        float vb = v_pos[((size_t)h * CBS + j) * HD + d];
        float kv = 0.f, vv = 0.f;
        if (p >= 0) {
            kv = qkv[(size_t)p * 2048 + 1024 + h * HD + d];
            vv = qkv[(size_t)p * 2048 + 1536 + h * HD + d];
        }
        kwflat[e] = __float2bfloat16(kv + kb);
        vwflat[e] = __float2bfloat16(vv + vb);
    }
}

// ---------------- RoPE + transpose ----------------
__global__ __launch_bounds__(256) void rope_kernel(const float* __restrict__ qkv,
                                                   float* __restrict__ rq,
                                                   float* __restrict__ rk,
                                                   float* __restrict__ vt) {
    int n = blockIdx.x;
    int t = threadIdx.x;
    for (int idx = t; idx < NH * 32; idx += 256) {
        int h = idx >> 5, f = idx & 31;
        float inv = powf(10000.f, -((float)(2 * f)) / 64.f);
        float ang = (float)n * inv;
        float cc = cosf(ang), ssn = sinf(ang);
        float a = qkv[(size_t)n * 2048 + h * HD + 2 * f];
        float b = qkv[(size_t)n * 2048 + h * HD + 2 * f + 1];
        float* o = rq + ((size_t)h * NTOK + n) * HD + 2 * f;
        o[0] = a * cc - b * ssn;
        o[1] = b * cc + a * ssn;
    }
    for (int idx = t; idx < KVH * 32; idx += 256) {
        int h = idx >> 5, f = idx & 31;
        float inv = powf(10000.f, -((float)(2 * f)) / 64.f);
        float ang = (float)n * inv;
        float cc = cosf(ang), ssn = sinf(ang);
        float a = qkv[(size_t)n * 2048 + 1024 + h * HD + 2 * f];
        float b = qkv[(size_t)n * 2048 + 1024 + h * HD + 2 * f + 1];
        float* o = rk + ((size_t)h * NTOK + n) * HD + 2 * f;
        o[0] = a * cc - b * ssn;
        o[1] = b * cc + a * ssn;
    }
    for (int idx = t; idx < KVH * HD; idx += 256) {
        int h = idx >> 6, d = idx & 63;
        vt[((size_t)h * NTOK + n) * HD + d] = qkv[(size_t)n * 2048 + 1536 + h * HD + d];
    }
}

// ---------------- Compressed attention + importance (tiled) ----------------
// Block per (h, 32-query tile). 256 threads.
__global__ __launch_bounds__(256) void cattn2_kernel(const float* __restrict__ qkv,
                                                     const float* __restrict__ ckraw,
                                                     const float* __restrict__ cvraw,
                                                     const float* __restrict__ memkv,
                                                     float* __restrict__ cout,
                                                     float* __restrict__ imp) {
    int h = blockIdx.x >> 6;
    int i0 = (blockIdx.x & 63) * 32;
    int t = threadIdx.x;
    __shared__ float qs[64][68];        // row = g*32+qi
    __shared__ float sc[64][132];       // cols 0..128 (0=mem)
    __shared__ float scratch[32 * 68];  // K chunk / impl / V chunk
    __shared__ float memk[64], memv[64];
    __shared__ float impm[32], impd[32];

    for (int idx = t; idx < 4096; idx += 256) {
        int row = idx >> 6, d = idx & 63;
        int g = row >> 5, qi = row & 31;
        qs[row][d] = qkv[(size_t)(i0 + qi) * 2048 + (h * 2 + g) * 64 + d];
    }
    if (t < 64) { memk[t] = memkv[h * 64 + t]; memv[t] = memkv[(8 + h) * 64 + t]; }
    __syncthreads();
    // mem key scores (col 0)
    if (t < 64) {
        float s = 0.f;
        for (int d = 0; d < 64; d++) s += qs[t][d] * memk[d];
        sc[t][0] = s * SCALE;
    }
    int rg = t >> 3, kg = t & 7;  // rows rg*2, rg*2+1; keys kg + kk*8
    for (int c = 0; c < 4; c++) {
        __syncthreads();
        for (int idx = t; idx < 2048; idx += 256) {
            int jj = idx >> 6, d = idx & 63;
            scratch[jj * 68 + d] = ckraw[((size_t)h * 128 + c * 32 + jj) * 64 + d];
        }
        __syncthreads();
        float a0[4] = {}, a1[4] = {};
        for (int d = 0; d < 64; d += 4) {
            float4 q0 = *(const float4*)&qs[rg * 2][d];
            float4 q1 = *(const float4*)&qs[rg * 2 + 1][d];
#pragma unroll
            for (int kk = 0; kk < 4; kk++) {
                float4 kv = *(const float4*)&scratch[(kg + kk * 8) * 68 + d];
                a0[kk] += q0.x * kv.x + q0.y * kv.y + q0.z * kv.z + q0.w * kv.w;
                a1[kk] += q1.x * kv.x + q1.y * kv.y + q1.z * kv.z + q1.w * kv.w;
            }
        }
#pragma unroll
        for (int kk = 0; kk < 4; kk++) {
            sc[rg * 2][1 + c * 32 + kg + kk * 8] = a0[kk] * SCALE;
            sc[rg * 2 + 1][1 + c * 32 + kg + kk * 8] = a1[kk] * SCALE;
        }
    }
    __syncthreads();
    // importance raw values -> scratch (stride 66)
    for (int idx = t; idx < 2048; idx += 256) {
        int qi = idx >> 6, fb = idx & 63;
        float v = 0.25f * (sc[qi][1 + 2 * fb] + sc[qi][2 + 2 * fb] +
                           sc[32 + qi][1 + 2 * fb] + sc[32 + qi][2 + 2 * fb]);
        if (fb == ((i0 + qi) >> 5)) v = NEGF;
        scratch[qi * 66 + fb] = v;
    }
    __syncthreads();
    if (t < 32) {  // importance softmax stats
        float m = -1000.f;
        for (int j = 0; j < 64; j++) m = fmaxf(m, scratch[t * 66 + j]);
        float den = expf(-1000.f - m);
        for (int j = 0; j < 64; j++) den += expf(scratch[t * 66 + j] - m);
        impm[t] = m; impd[t] = 1.f / den;
    } else if (t >= 64 && t < 128) {  // score softmax (rows 0..63)
        int r = t - 64;
        float m = NEGF;
        for (int j = 0; j < 129; j++) m = fmaxf(m, sc[r][j]);
        float den = 0.f;
        for (int j = 0; j < 129; j++) { float e = expf(sc[r][j] - m); sc[r][j] = e; den += e; }
        float inv = 1.f / den;
        for (int j = 0; j < 129; j++) sc[r][j] *= inv;
    }
    __syncthreads();
    for (int idx = t; idx < 2048; idx += 256) {
        int qi = idx >> 6, fb = idx & 63;
        imp[((size_t)h * NTOK + i0 + qi) * 64 + fb] =
            expf(scratch[qi * 66 + fb] - impm[qi]) * impd[qi];
    }
    // PV
    int dg = t & 7;  // d = dg + dd*8
    float o0[8], o1[8];
    {
        float p0 = sc[rg * 2][0], p1 = sc[rg * 2 + 1][0];
#pragma unroll
        for (int dd = 0; dd < 8; dd++) {
            float v = memv[dg + dd * 8];
            o0[dd] = p0 * v;
            o1[dd] = p1 * v;
        }
    }
    for (int c = 0; c < 4; c++) {
        __syncthreads();
        for (int idx = t; idx < 2048; idx += 256) {
            int jj = idx >> 6, d = idx & 63;
            scratch[jj * 68 + d] = cvraw[((size_t)h * 128 + c * 32 + jj) * 64 + d];
        }
        __syncthreads();
        for (int jj = 0; jj < 32; jj++) {
            float p0 = sc[rg * 2][1 + c * 32 + jj];
            float p1 = sc[rg * 2 + 1][1 + c * 32 + jj];
#pragma unroll
            for (int dd = 0; dd < 8; dd++) {
                float v = scratch[jj * 68 + dg + dd * 8];
                o0[dd] += p0 * v;
                o1[dd] += p1 * v;
            }
        }
    }
    {
        int row = rg * 2;
        int g = row >> 5, qi = row & 31;
        int g2 = (row + 1) >> 5, qi2 = (row + 1) & 31;
#pragma unroll
        for (int dd = 0; dd < 8; dd++) {
            cout[(((size_t)(h * 2 + g)) * NTOK + i0 + qi) * 64 + dd * 8 + dg] = o0[dd];
            cout[(((size_t)(h * 2 + g2)) * NTOK + i0 + qi2) * 64 + dd * 8 + dg] = o1[dd];
        }
    }
}

// ---------------- Top-k selection ----------------
__global__ __launch_bounds__(256) void topk_kernel(const float* __restrict__ imp,
                                                   int* __restrict__ selidx,
                                                   int* __restrict__ selmask) {
    int idx = blockIdx.x * 256 + threadIdx.x;
    if (idx >= KVH * NTOK) return;
    const float* ip = imp + (size_t)idx * NFB;
    float v[NFB];
    for (int j = 0; j < NFB; j++) v[j] = ip[j];
    unsigned long long taken = 0ull;
    int mk = 0;
    int i = idx & 2047;
    for (int p = 0; p < NSEL; p++) {
        float bv = NEGF;
        int bi = 0;
        for (int j = 0; j < NFB; j++) {
            if (!((taken >> j) & 1ull) && v[j] > bv) { bv = v[j]; bi = j; }
        }
        taken |= 1ull << bi;
        selidx[(size_t)idx * 5 + p] = bi;
        if (bv > 1e-10f) mk |= 1 << p;
    }
    selidx[(size_t)idx * 5 + 4] = i >> 5;
    selmask[idx] = mk;
}

// ---------------- Fine (selected) attention ----------------
__global__ __launch_bounds__(256) void fattn_kernel(const float* __restrict__ rq,
                                                    const float* __restrict__ rk,
                                                    const float* __restrict__ vt,
                                                    const int* __restrict__ selidx,
                                                    const int* __restrict__ selmask,
                                                    float* __restrict__ fout) {
    int h = blockIdx.x >> 11, i = blockIdx.x & 2047;
    int t = threadIdx.x;
    __shared__ float qs[2][64];
    __shared__ float s[2][160];
    __shared__ int selb[5];
    __shared__ int mk;
    if (t < 128) {
        int g = t >> 6, d = t & 63;
        qs[g][d] = rq[(((size_t)(h * 2 + g)) * NTOK + i) * HD + d];
    }
    if (t < 5) selb[t] = selidx[((size_t)h * NTOK + i) * 5 + t];
    if (t == 5) mk = selmask[h * NTOK + i];
    __syncthreads();
    if (t < 160) {
        int slot = t >> 5, jj = t & 31;
        int blk = selb[slot];
        int kpos = blk * SEL_BLK + jj;
        bool valid = (slot < 4) ? (((mk >> slot) & 1) != 0) : (jj <= (i & 31));
        const float* kp = rk + ((size_t)h * NTOK + kpos) * HD;
        float s0 = 0.f, s1 = 0.f;
        for (int d = 0; d < 64; d++) {
            float kv = kp[d];
            s0 += qs[0][d] * kv;
            s1 += qs[1][d] * kv;
        }
        s[0][t] = valid ? s0 * SCALE : NEG10F;
        s[1][t] = valid ? s1 * SCALE : NEG10F;
    }
    __syncthreads();
    if (t < 2) {
        float m = NEGF;
        for (int j = 0; j < 160; j++) m = fmaxf(m, s[t][j]);
        float den = 0.f;
        for (int j = 0; j < 160; j++) {
            float e = expf(s[t][j] - m);
            s[t][j] = e;
            den += e;
        }
        float inv = 1.f / den;
        for (int j = 0; j < 160; j++) s[t][j] *= inv;
    }
    __syncthreads();
    if (t < 128) {
        int g = t >> 6, d = t & 63;
        float o = 0.f;
        for (int j = 0; j < 160; j++) {
            int kpos = selb[j >> 5] * SEL_BLK + (j & 31);
            o += s[g][j] * vt[((size_t)h * NTOK + kpos) * HD + d];
        }
        fout[(((size_t)(h * 2 + g)) * NTOK + i) * HD + d] = o;
    }
}

// ---------------- Sliding-window attention ----------------
__global__ __launch_bounds__(256) void sattn_kernel(const float* __restrict__ rq,
                                                    const float* __restrict__ rk,
                                                    const float* __restrict__ vt,
                                                    float* __restrict__ sout) {
    int h = blockIdx.x >> 11, i = blockIdx.x & 2047;
    int t = threadIdx.x;
    __shared__ float qs[2][64];
    __shared__ float s[2][64];
    if (t < 128) {
        int g = t >> 6, d = t & 63;
        qs[g][d] = rq[(((size_t)(h * 2 + g)) * NTOK + i) * HD + d];
    }
    __syncthreads();
    if (t < 64) {
        int kpos = i - 63 + t;
        if (kpos >= 0) {
            const float* kp = rk + ((size_t)h * NTOK + kpos) * HD;
            float s0 = 0.f, s1 = 0.f;
            for (int d = 0; d < 64; d++) {
                float kv = kp[d];
                s0 += qs[0][d] * kv;
                s1 += qs[1][d] * kv;
            }
            s[0][t] = s0 * SCALE;
            s[1][t] = s1 * SCALE;
        } else {
            s[0][t] = NEGF;
            s[1][t] = NEGF;
        }
    }
    __syncthreads();
    if (t < 2) {
        float m = NEGF;
        for (int j = 0; j < 64; j++) m = fmaxf(m, s[t][j]);
        float den = 0.f;
        for (int j = 0; j < 64; j++) {
            float e = expf(s[t][j] - m);
            s[t][j] = e;
            den += e;
        }
        float inv = 1.f / den;
        for (int j = 0; j < 64; j++) s[t][j] *= inv;
    }
    __syncthreads();
    if (t < 128) {
        int g = t >> 6, d = t & 63;
        float o = 0.f;
        for (int j = 0; j < 64; j++) {
            int kpos = i - 63 + j;
            if (kpos >= 0) o += s[g][j] * vt[((size_t)h * NTOK + kpos) * HD + d];
        }
        sout[(((size_t)(h * 2 + g)) * NTOK + i) * HD + d] = o;
    }
}

// ---------------- Gated combine (writes bf16 for Wout MFMA GEMM) ----------------
__global__ __launch_bounds__(256) void combine_kernel(const float* __restrict__ gates,
                                                      const float* __restrict__ cout,
                                                      const float* __restrict__ fout,
                                                      const float* __restrict__ sout,
                                                      __hip_bfloat16* __restrict__ att) {
    int n = blockIdx.x;
    for (int c = threadIdx.x; c < NH * HD; c += 256) {
        int hd = c >> 6, d = c & 63;
        float g0 = gates[(size_t)n * (NH * 3) + hd * 3 + 0];
        float g1 = gates[(size_t)n * (NH * 3) + hd * 3 + 1];
        float g2 = gates[(size_t)n * (NH * 3) + hd * 3 + 2];
        size_t o = ((size_t)hd * NTOK + n) * HD + d;
        att[(size_t)n * (NH * HD) + c] =
            __float2bfloat16(g0 * cout[o] + g1 * fout[o] + g2 * sout[o]);
    }
}

extern "C" void kernel_launch(void* const* d_in, const int* in_sizes, int n_in,
                              void* d_out, int out_size, void* d_ws, size_t ws_size,
                              hipStream_t stream) {
    const float* inp    = (const float*)d_in[0];
    const float* norm_g = (const float*)d_in[1];
    const float* Wqkv   = (const float*)d_in[2];
    const float* mem_kv = (const float*)d_in[3];
    const float* k_pos  = (const float*)d_in[4];
    const float* v_pos  = (const float*)d_in[5];
    const float* kW1    = (const float*)d_in[6];
    const float* kb1    = (const float*)d_in[7];
    const float* kW2    = (const float*)d_in[8];
    const float* kb2    = (const float*)d_in[9];
    const float* vW1    = (const float*)d_in[10];
    const float* vb1    = (const float*)d_in[11];
    const float* vW2    = (const float*)d_in[12];
    const float* vb2    = (const float*)d_in[13];
    const float* combW  = (const float*)d_in[14];
    const float* combB  = (const float*)d_in[15];
    const float* Wout   = (const float*)d_in[16];
    float* out = (float*)d_out;

    char* base = (char*)d_ws;
    size_t off = 0;
    auto alloc = [&](size_t bytes) {
        void* p = base + off;
        off += (bytes + 255) & ~(size_t)255;
        return p;
    };
    float* x            = (float*)alloc((size_t)NTOK * DIM * 4);
    __hip_bfloat16* xb  = (__hip_bfloat16*)alloc((size_t)NTOK * DIM * 2);
    float* qkv          = (float*)alloc((size_t)NTOK * 2048 * 4);
    __hip_bfloat16* Wqkvt = (__hip_bfloat16*)alloc((size_t)2048 * 1024 * 2);
    __hip_bfloat16* kW1t  = (__hip_bfloat16*)alloc((size_t)2048 * 2048 * 2);
    __hip_bfloat16* vW1t  = (__hip_bfloat16*)alloc((size_t)2048 * 2048 * 2);
    __hip_bfloat16* Woutt = (__hip_bfloat16*)alloc((size_t)1024 * 1024 * 2);
    __hip_bfloat16* kwflat = (__hip_bfloat16*)alloc((size_t)KVH * NCB * HIDN * 2);
    __hip_bfloat16* vwflat = (__hip_bfloat16*)alloc((size_t)KVH * NCB * HIDN * 2);
    float* hid          = (float*)alloc((size_t)KVH * NCB * HIDN * 4);
    float* ckraw        = (float*)alloc((size_t)KVH * NCB * HD * 4);
    float* cvraw        = (float*)alloc((size_t)KVH * NCB * HD * 4);
    float* rq           = (float*)alloc((size_t)NH * NTOK * HD * 4);
    float* rk           = (float*)alloc((size_t)KVH * NTOK * HD * 4);
    float* vt           = (float*)alloc((size_t)KVH * NTOK * HD * 4);
    float* coutb        = (float*)alloc((size_t)NH * NTOK * HD * 4);
    float* foutb        = (float*)alloc((size_t)NH * NTOK * HD * 4);
    float* soutb        = (float*)alloc((size_t)NH * NTOK * HD * 4);
    float* impb         = (float*)alloc((size_t)KVH * NTOK * NFB * 4);
    float* gatesb       = (float*)alloc((size_t)NTOK * NH * 3 * 4);
    __hip_bfloat16* attb = (__hip_bfloat16*)alloc((size_t)NTOK * DIM * 2);
    int* selidx         = (int*)alloc((size_t)KVH * NTOK * 5 * 4);
    int* selmask        = (int*)alloc((size_t)KVH * NTOK * 4);
    (void)ws_size; (void)in_sizes; (void)n_in; (void)out_size;

    // 1. RMSNorm (fp32 + bf16)
    rmsnorm_kernel<<<NTOK, 256, 0, stream>>>(inp, norm_g, x, xb);
    // 2. transpose-cast weights to bf16 NxK
    transpose_cast_kernel<<<dim3(2048 / 32, 1024 / 32), 256, 0, stream>>>(Wqkv, Wqkvt, 1024, 2048);
    transpose_cast_kernel<<<dim3(2048 / 32, 2048 / 32), 256, 0, stream>>>(kW1, kW1t, 2048, 2048);
    transpose_cast_kernel<<<dim3(2048 / 32, 2048 / 32), 256, 0, stream>>>(vW1, vW1t, 2048, 2048);
    transpose_cast_kernel<<<dim3(1024 / 32, 1024 / 32), 256, 0, stream>>>(Wout, Woutt, 1024, 1024);
    // 3. qkv = x @ Wqkv  (MFMA)
    mfma_gemm<0><<<dim3(16, 16), 256, 0, stream>>>(xb, Wqkvt, nullptr, qkv, 2048, 2048, 1024);
    // 4. gates = sigmoid(x @ combW + combB)
    gemm_bias_act<2><<<dim3(1, 32), 256, 0, stream>>>(x, combW, combB, gatesb, NTOK, DIM, NH * 3);
    // 5. build compressed windows (bf16)
    buildwin_kernel<<<4096, 256, 0, stream>>>(qkv, k_pos, v_pos, kwflat, vwflat);
    // 6. compressed-K MLP
    mfma_gemm<1><<<dim3(16, 8), 256, 0, stream>>>(kwflat, kW1t, kb1, hid, 1024, 2048, 2048);
    gemm_bias_act<0><<<dim3(1, 16), 256, 0, stream>>>(hid, kW2, kb2, ckraw, KVH * NCB, HIDN, HD);
    // 7. compressed-V MLP
    mfma_gemm<1><<<dim3(16, 8), 256, 0, stream>>>(vwflat, vW1t, vb1, hid, 1024, 2048, 2048);
    gemm_bias_act<0><<<dim3(1, 16), 256, 0, stream>>>(hid, vW2, vb2, cvraw, KVH * NCB, HIDN, HD);
    // 8. RoPE + transposes
    rope_kernel<<<NTOK, 256, 0, stream>>>(qkv, rq, rk, vt);
    // 9. compressed attention + importance (tiled)
    cattn2_kernel<<<KVH * (NTOK / 32), 256, 0, stream>>>(qkv, ckraw, cvraw, mem_kv, coutb, impb);
    // 10. top-k block selection
    topk_kernel<<<(KVH * NTOK) / 256, 256, 0, stream>>>(impb, selidx, selmask);
    // 11. fine attention
    fattn_kernel<<<KVH * NTOK, 256, 0, stream>>>(rq, rk, vt, selidx, selmask, foutb);
    // 12. sliding-window attention
    sattn_kernel<<<KVH * NTOK, 256, 0, stream>>>(rq, rk, vt, soutb);
    // 13. gated combine (bf16)
    combine_kernel<<<NTOK, 256, 0, stream>>>(gatesb, coutb, foutb, soutb, attb);
    // 14. out projection (MFMA)
    mfma_gemm<0><<<dim3(8, 16), 256, 0, stream>>>(attb, Woutt, nullptr, out, 2048, 1024, 1024);
}

// Round 3
// 819.327 us; speedup vs baseline: 3.7484x; 2.0505x over previous
//
#include <hip/hip_runtime.h>
#include <hip/hip_bf16.h>

// Problem constants
#define NTOK 2048
#define DIM 1024
#define NH 16
#define KVH 8
#define GQ 2
#define HD 64
#define WS 64
#define CBS 32
#define STRIDE 16
#define SEL_BLK 32
#define NSEL 4
#define NMEM 1
#define NCB 128          // N/STRIDE
#define NFB 64           // N/SEL_BLK
#define HIDN 2048        // CBS*HD
#define SCALE 0.125f
#define NEGF (-3.4028234663852886e38f)
#define NEG10F (-3.4028234663852886e37f)

typedef __attribute__((ext_vector_type(8))) short bf16x8;
typedef __attribute__((ext_vector_type(4))) float f32x4;

// ---------------- RMSNorm (writes fp32 x and bf16 xb) ----------------
__global__ __launch_bounds__(256) void rmsnorm_kernel(const float* __restrict__ inp,
                                                      const float* __restrict__ g,
                                                      float* __restrict__ x,
                                                      __hip_bfloat16* __restrict__ xb) {
    int n = blockIdx.x;
    const float* row = inp + (size_t)n * DIM;
    float ss = 0.f;
    for (int c = threadIdx.x; c < DIM; c += 256) { float v = row[c]; ss += v * v; }
    __shared__ float red[4];
    for (int o = 32; o; o >>= 1) ss += __shfl_down(ss, o, 64);
    if ((threadIdx.x & 63) == 0) red[threadIdx.x >> 6] = ss;
    __syncthreads();
    if (threadIdx.x == 0) red[0] = red[0] + red[1] + red[2] + red[3];
    __syncthreads();
    float rs = 1.0f / sqrtf(red[0] / (float)DIM + 1.1920928955078125e-07f);
    float* xr = x + (size_t)n * DIM;
    __hip_bfloat16* xbr = xb + (size_t)n * DIM;
    for (int c = threadIdx.x; c < DIM; c += 256) {
        float v = row[c] * rs * g[c];
        xr[c] = v;
        xbr[c] = __float2bfloat16(v);
    }
}

// ---------------- Transpose + cast fp32 B[K][N] -> bf16 Bt[N][K] (bounds-checked) ----
__global__ __launch_bounds__(256) void transpose_cast_kernel(const float* __restrict__ B,
                                                             __hip_bfloat16* __restrict__ Bt,
                                                             int K, int N) {
    __shared__ float tile[32][33];
    int n0 = blockIdx.x * 32, k0 = blockIdx.y * 32;
    int x = threadIdx.x & 31, y = threadIdx.x >> 5;  // y in 0..7
    for (int i = 0; i < 4; i++) {
        int k = k0 + y + 8 * i, n = n0 + x;
        tile[y + 8 * i][x] = (k < K && n < N) ? B[(size_t)k * N + n] : 0.f;
    }
    __syncthreads();
    for (int i = 0; i < 4; i++) {
        int n = n0 + y + 8 * i, k = k0 + x;
        if (n < N && k < K) Bt[(size_t)n * K + k] = __float2bfloat16(tile[x][y + 8 * i]);
    }
}

// ---------------- bf16 MFMA GEMM: C = act(A @ Bt^T + bias) ----------------
// A: MxK bf16 row-major. Bt: NxK bf16 row-major. C: MxN (fp32 or bf16).
// Requires M%128==0, N%128==0, K%32==0.
template <int ACT, int OUTBF16>
__global__ __launch_bounds__(256) void mfma_gemm(const __hip_bfloat16* __restrict__ A,
                                                 const __hip_bfloat16* __restrict__ Bt,
                                                 const float* __restrict__ bias,
                                                 void* __restrict__ Cp,
                                                 int M, int N, int K) {
    __shared__ __align__(16) short As[128 * 32];
    __shared__ __align__(16) short Bs[128 * 32];
    int tid = threadIdx.x;
    int lane = tid & 63, wave = tid >> 6;
    int wm = (wave >> 1) * 64, wn = (wave & 1) * 64;
    int m0 = blockIdx.y * 128, n0 = blockIdx.x * 128;
    f32x4 acc[4][4];
    for (int r = 0; r < 4; r++)
        for (int c = 0; c < 4; c++)
            acc[r][c] = (f32x4){0.f, 0.f, 0.f, 0.f};

    int r0 = tid >> 2, kc0 = tid & 3;
    int r1 = (tid + 256) >> 2, kc1 = tid & 3;

    for (int k0 = 0; k0 < K; k0 += 32) {
        __syncthreads();
        *(uint4*)&As[r0 * 32 + kc0 * 8] =
            *(const uint4*)(A + (size_t)(m0 + r0) * K + k0 + kc0 * 8);
        *(uint4*)&As[r1 * 32 + kc1 * 8] =
            *(const uint4*)(A + (size_t)(m0 + r1) * K + k0 + kc1 * 8);
        *(uint4*)&Bs[r0 * 32 + kc0 * 8] =
            *(const uint4*)(Bt + (size_t)(n0 + r0) * K + k0 + kc0 * 8);
        *(uint4*)&Bs[r1 * 32 + kc1 * 8] =
            *(const uint4*)(Bt + (size_t)(n0 + r1) * K + k0 + kc1 * 8);
        __syncthreads();
        bf16x8 af[4], bfr[4];
#pragma unroll
        for (int r = 0; r < 4; r++)
            af[r] = *(const bf16x8*)&As[(wm + r * 16 + (lane & 15)) * 32 + (lane >> 4) * 8];
#pragma unroll
        for (int c = 0; c < 4; c++)
            bfr[c] = *(const bf16x8*)&Bs[(wn + c * 16 + (lane & 15)) * 32 + (lane >> 4) * 8];
#pragma unroll
        for (int r = 0; r < 4; r++)
#pragma unroll
            for (int c = 0; c < 4; c++)
                acc[r][c] = __builtin_amdgcn_mfma_f32_16x16x32_bf16(af[r], bfr[c], acc[r][c], 0, 0, 0);
    }
    for (int r = 0; r < 4; r++) {
        int grow = m0 + wm + r * 16 + (lane >> 4) * 4;
        for (int c = 0; c < 4; c++) {
            int gcol = n0 + wn + c * 16 + (lane & 15);
            float bv = bias ? bias[gcol] : 0.f;
#pragma unroll
            for (int v = 0; v < 4; v++) {
                float val = acc[r][c][v] + bv;
                if (ACT == 1) val = fmaxf(val, 0.f);
                if (OUTBF16)
                    ((__hip_bfloat16*)Cp)[(size_t)(grow + v) * N + gcol] = __float2bfloat16(val);
                else
                    ((float*)Cp)[(size_t)(grow + v) * N + gcol] = val;
            }
        }
    }
}

// ---------------- Split-K skinny MFMA GEMM: C += A @ Bt^T (atomicAdd) ----------------
// A: MxK bf16, Bt: NoutxK bf16 (Nout<=64), C: MxNout fp32 pre-initialized with bias.
// Block tile: 128M x 64N, 4 waves each 32M x 64N (2x4 frags). grid=(1, M/128, SPLITK).
__global__ __launch_bounds__(256) void skgemm_kernel(const __hip_bfloat16* __restrict__ A,
                                                     const __hip_bfloat16* __restrict__ Bt,
                                                     float* __restrict__ C,
                                                     int M, int Nout, int K) {
    __shared__ __align__(16) short As[128 * 32];
    __shared__ __align__(16) short Bs[64 * 32];
    int tid = threadIdx.x;
    int lane = tid & 63, wave = tid >> 6;
    int m0 = blockIdx.y * 128;
    int wm = wave * 32;
    int kchunk = K / (int)gridDim.z;
    int kbase = blockIdx.z * kchunk;
    f32x4 acc[2][4];
    for (int r = 0; r < 2; r++)
        for (int c = 0; c < 4; c++) acc[r][c] = (f32x4){0.f, 0.f, 0.f, 0.f};

    int ra = tid >> 2, kc = (tid & 3) * 8;
    for (int k0 = kbase; k0 < kbase + kchunk; k0 += 32) {
        __syncthreads();
        *(uint4*)&As[ra * 32 + kc] = *(const uint4*)(A + (size_t)(m0 + ra) * K + k0 + kc);
        *(uint4*)&As[(ra + 64) * 32 + kc] =
            *(const uint4*)(A + (size_t)(m0 + ra + 64) * K + k0 + kc);
        uint4 bv = (uint4){0u, 0u, 0u, 0u};
        if (ra < Nout) bv = *(const uint4*)(Bt + (size_t)ra * K + k0 + kc);
        *(uint4*)&Bs[ra * 32 + kc] = bv;
        __syncthreads();
        bf16x8 af[2], bfr[4];
#pragma unroll
        for (int r = 0; r < 2; r++)
            af[r] = *(const bf16x8*)&As[(wm + r * 16 + (lane & 15)) * 32 + (lane >> 4) * 8];
#pragma unroll
        for (int c = 0; c < 4; c++)
            bfr[c] = *(const bf16x8*)&Bs[(c * 16 + (lane & 15)) * 32 + (lane >> 4) * 8];
#pragma unroll
        for (int r = 0; r < 2; r++)
#pragma unroll
            for (int c = 0; c < 4; c++)
                acc[r][c] = __builtin_amdgcn_mfma_f32_16x16x32_bf16(af[r], bfr[c], acc[r][c], 0, 0, 0);
    }
    for (int r = 0; r < 2; r++) {
        int grow = m0 + wm + r * 16 + (lane >> 4) * 4;
        for (int c = 0; c < 4; c++) {
            int gcol = c * 16 + (lane & 15);
            if (gcol >= Nout) continue;
#pragma unroll
            for (int v = 0; v < 4; v++)
                atomicAdd(&C[(size_t)(grow + v) * Nout + gcol], acc[r][c][v]);
        }
    }
}

// ---------------- init C with broadcast bias ----------------
__global__ __launch_bounds__(256) void initbias_kernel(float* __restrict__ C,
                                                       const float* __restrict__ bias,
                                                       int M, int Nout) {
    int idx = blockIdx.x * 256 + threadIdx.x;
    if (idx < M * Nout) C[idx] = bias[idx % Nout];
}

// ---------------- Build compressed windows (bf16 MLP input) ----------------
__global__ __launch_bounds__(256) void buildwin_kernel(const float* __restrict__ qkv,
                                                       const float* __restrict__ k_pos,
                                                       const float* __restrict__ v_pos,
                                                       __hip_bfloat16* __restrict__ kwflat,
                                                       __hip_bfloat16* __restrict__ vwflat) {
    size_t total = (size_t)(KVH * NCB) * HIDN;
    for (size_t e = (size_t)blockIdx.x * 256 + threadIdx.x; e < total;
         e += (size_t)gridDim.x * 256) {
        int r = (int)(e >> 11);
        int c = (int)(e & 2047);
        int j = c >> 6, d = c & 63;
        int h = r >> 7, i = r & 127;
        int p = i * STRIDE + j - (CBS - STRIDE);
        float kb = k_pos[((size_t)h * CBS + j) * HD + d];
        float vb = v_pos[((size_t)h * CBS + j) * HD + d];
        float kv = 0.f, vv = 0.f;
        if (p >= 0) {
            kv = qkv[(size_t)p * 2048 + 1024 + h * HD + d];
            vv = qkv[(size_t)p * 2048 + 1536 + h * HD + d];
        }
        kwflat[e] = __float2bfloat16(kv + kb);
        vwflat[e] = __float2bfloat16(vv + vb);
    }
}

// ---------------- RoPE + transpose ----------------
__global__ __launch_bounds__(256) void rope_kernel(const float* __restrict__ qkv,
                                                   float* __restrict__ rq,
                                                   float* __restrict__ rk,
                                                   float* __restrict__ vt) {
    int n = blockIdx.x;
    int t = threadIdx.x;
    for (int idx = t; idx < NH * 32; idx += 256) {
        int h = idx >> 5, f = idx & 31;
        float inv = powf(10000.f, -((float)(2 * f)) / 64.f);
        float ang = (float)n * inv;
        float cc = cosf(ang), ssn = sinf(ang);
        float a = qkv[(size_t)n * 2048 + h * HD + 2 * f];
        float b = qkv[(size_t)n * 2048 + h * HD + 2 * f + 1];
        float* o = rq + ((size_t)h * NTOK + n) * HD + 2 * f;
        o[0] = a * cc - b * ssn;
        o[1] = b * cc + a * ssn;
    }
    for (int idx = t; idx < KVH * 32; idx += 256) {
        int h = idx >> 5, f = idx & 31;
        float inv = powf(10000.f, -((float)(2 * f)) / 64.f);
        float ang = (float)n * inv;
        float cc = cosf(ang), ssn = sinf(ang);
        float a = qkv[(size_t)n * 2048 + 1024 + h * HD + 2 * f];
        float b = qkv[(size_t)n * 2048 + 1024 + h * HD + 2 * f + 1];
        float* o = rk + ((size_t)h * NTOK + n) * HD + 2 * f;
        o[0] = a * cc - b * ssn;
        o[1] = b * cc + a * ssn;
    }
    for (int idx = t; idx < KVH * HD; idx += 256) {
        int h = idx >> 6, d = idx & 63;
        vt[((size_t)h * NTOK + n) * HD + d] = qkv[(size_t)n * 2048 + 1536 + h * HD + d];
    }
}

// ---------------- Compressed attention + importance (tiled) ----------------
__global__ __launch_bounds__(256) void cattn2_kernel(const float* __restrict__ qkv,
                                                     const float* __restrict__ ckraw,
                                                     const float* __restrict__ cvraw,
                                                     const float* __restrict__ memkv,
                                                     float* __restrict__ cout,
                                                     float* __restrict__ imp) {
    int h = blockIdx.x >> 6;
    int i0 = (blockIdx.x & 63) * 32;
    int t = threadIdx.x;
    __shared__ float qs[64][68];
    __shared__ float sc[64][132];
    __shared__ float scratch[32 * 68];
    __shared__ float memk[64], memv[64];
    __shared__ float impm[32], impd[32];

    for (int idx = t; idx < 4096; idx += 256) {
        int row = idx >> 6, d = idx & 63;
        int g = row >> 5, qi = row & 31;
        qs[row][d] = qkv[(size_t)(i0 + qi) * 2048 + (h * 2 + g) * 64 + d];
    }
    if (t < 64) { memk[t] = memkv[h * 64 + t]; memv[t] = memkv[(8 + h) * 64 + t]; }
    __syncthreads();
    if (t < 64) {
        float s = 0.f;
        for (int d = 0; d < 64; d++) s += qs[t][d] * memk[d];
        sc[t][0] = s * SCALE;
    }
    int rg = t >> 3, kg = t & 7;
    for (int c = 0; c < 4; c++) {
        __syncthreads();
        for (int idx = t; idx < 2048; idx += 256) {
            int jj = idx >> 6, d = idx & 63;
            scratch[jj * 68 + d] = ckraw[((size_t)h * 128 + c * 32 + jj) * 64 + d];
        }
        __syncthreads();
        float a0[4] = {}, a1[4] = {};
        for (int d = 0; d < 64; d += 4) {
            float4 q0 = *(const float4*)&qs[rg * 2][d];
            float4 q1 = *(const float4*)&qs[rg * 2 + 1][d];
#pragma unroll
            for (int kk = 0; kk < 4; kk++) {
                float4 kv = *(const float4*)&scratch[(kg + kk * 8) * 68 + d];
                a0[kk] += q0.x * kv.x + q0.y * kv.y + q0.z * kv.z + q0.w * kv.w;
                a1[kk] += q1.x * kv.x + q1.y * kv.y + q1.z * kv.z + q1.w * kv.w;
            }
        }
#pragma unroll
        for (int kk = 0; kk < 4; kk++) {
            sc[rg * 2][1 + c * 32 + kg + kk * 8] = a0[kk] * SCALE;
            sc[rg * 2 + 1][1 + c * 32 + kg + kk * 8] = a1[kk] * SCALE;
        }
    }
    __syncthreads();
    for (int idx = t; idx < 2048; idx += 256) {
        int qi = idx >> 6, fb = idx & 63;
        float v = 0.25f * (sc[qi][1 + 2 * fb] + sc[qi][2 + 2 * fb] +
                           sc[32 + qi][1 + 2 * fb] + sc[32 + qi][2 + 2 * fb]);
        if (fb == ((i0 + qi) >> 5)) v = NEGF;
        scratch[qi * 66 + fb] = v;
    }
    __syncthreads();
    if (t < 32) {
        float m = -1000.f;
        for (int j = 0; j < 64; j++) m = fmaxf(m, scratch[t * 66 + j]);
        float den = expf(-1000.f - m);
        for (int j = 0; j < 64; j++) den += expf(scratch[t * 66 + j] - m);
        impm[t] = m; impd[t] = 1.f / den;
    } else if (t >= 64 && t < 128) {
        int r = t - 64;
        float m = NEGF;
        for (int j = 0; j < 129; j++) m = fmaxf(m, sc[r][j]);
        float den = 0.f;
        for (int j = 0; j < 129; j++) { float e = expf(sc[r][j] - m); sc[r][j] = e; den += e; }
        float inv = 1.f / den;
        for (int j = 0; j < 129; j++) sc[r][j] *= inv;
    }
    __syncthreads();
    for (int idx = t; idx < 2048; idx += 256) {
        int qi = idx >> 6, fb = idx & 63;
        imp[((size_t)h * NTOK + i0 + qi) * 64 + fb] =
            expf(scratch[qi * 66 + fb] - impm[qi]) * impd[qi];
    }
    int dg = t & 7;
    float o0[8], o1[8];
    {
        float p0 = sc[rg * 2][0], p1 = sc[rg * 2 + 1][0];
#pragma unroll
        for (int dd = 0; dd < 8; dd++) {
            float v = memv[dg + dd * 8];
            o0[dd] = p0 * v;
            o1[dd] = p1 * v;
        }
    }
    for (int c = 0; c < 4; c++) {
        __syncthreads();
        for (int idx = t; idx < 2048; idx += 256) {
            int jj = idx >> 6, d = idx & 63;
            scratch[jj * 68 + d] = cvraw[((size_t)h * 128 + c * 32 + jj) * 64 + d];
        }
        __syncthreads();
        for (int jj = 0; jj < 32; jj++) {
            float p0 = sc[rg * 2][1 + c * 32 + jj];
            float p1 = sc[rg * 2 + 1][1 + c * 32 + jj];
#pragma unroll
            for (int dd = 0; dd < 8; dd++) {
                float v = scratch[jj * 68 + dg + dd * 8];
                o0[dd] += p0 * v;
                o1[dd] += p1 * v;
            }
        }
    }
    {
        int row = rg * 2;
        int g = row >> 5, qi = row & 31;
        int g2 = (row + 1) >> 5, qi2 = (row + 1) & 31;
#pragma unroll
        for (int dd = 0; dd < 8; dd++) {
            cout[(((size_t)(h * 2 + g)) * NTOK + i0 + qi) * 64 + dd * 8 + dg] = o0[dd];
            cout[(((size_t)(h * 2 + g2)) * NTOK + i0 + qi2) * 64 + dd * 8 + dg] = o1[dd];
        }
    }
}

// ---------------- Top-k selection ----------------
__global__ __launch_bounds__(256) void topk_kernel(const float* __restrict__ imp,
                                                   int* __restrict__ selidx,
                                                   int* __restrict__ selmask) {
    int idx = blockIdx.x * 256 + threadIdx.x;
    if (idx >= KVH * NTOK) return;
    const float* ip = imp + (size_t)idx * NFB;
    float v[NFB];
    for (int j = 0; j < NFB; j++) v[j] = ip[j];
    unsigned long long taken = 0ull;
    int mk = 0;
    int i = idx & 2047;
    for (int p = 0; p < NSEL; p++) {
        float bv = NEGF;
        int bi = 0;
        for (int j = 0; j < NFB; j++) {
            if (!((taken >> j) & 1ull) && v[j] > bv) { bv = v[j]; bi = j; }
        }
        taken |= 1ull << bi;
        selidx[(size_t)idx * 5 + p] = bi;
        if (bv > 1e-10f) mk |= 1 << p;
    }
    selidx[(size_t)idx * 5 + 4] = i >> 5;
    selmask[idx] = mk;
}

// ---------------- Fine (selected) attention ----------------
__global__ __launch_bounds__(256) void fattn_kernel(const float* __restrict__ rq,
                                                    const float* __restrict__ rk,
                                                    const float* __restrict__ vt,
                                                    const int* __restrict__ selidx,
                                                    const int* __restrict__ selmask,
                                                    float* __restrict__ fout) {
    int h = blockIdx.x >> 11, i = blockIdx.x & 2047;
    int t = threadIdx.x;
    __shared__ float qs[2][64];
    __shared__ float s[2][160];
    __shared__ int selb[5];
    __shared__ int mk;
    if (t < 128) {
        int g = t >> 6, d = t & 63;
        qs[g][d] = rq[(((size_t)(h * 2 + g)) * NTOK + i) * HD + d];
    }
    if (t < 5) selb[t] = selidx[((size_t)h * NTOK + i) * 5 + t];
    if (t == 5) mk = selmask[h * NTOK + i];
    __syncthreads();
    if (t < 160) {
        int slot = t >> 5, jj = t & 31;
        int blk = selb[slot];
        int kpos = blk * SEL_BLK + jj;
        bool valid = (slot < 4) ? (((mk >> slot) & 1) != 0) : (jj <= (i & 31));
        const float* kp = rk + ((size_t)h * NTOK + kpos) * HD;
        float s0 = 0.f, s1 = 0.f;
        for (int d = 0; d < 64; d++) {
            float kv = kp[d];
            s0 += qs[0][d] * kv;
            s1 += qs[1][d] * kv;
        }
        s[0][t] = valid ? s0 * SCALE : NEG10F;
        s[1][t] = valid ? s1 * SCALE : NEG10F;
    }
    __syncthreads();
    if (t < 2) {
        float m = NEGF;
        for (int j = 0; j < 160; j++) m = fmaxf(m, s[t][j]);
        float den = 0.f;
        for (int j = 0; j < 160; j++) {
            float e = expf(s[t][j] - m);
            s[t][j] = e;
            den += e;
        }
        float inv = 1.f / den;
        for (int j = 0; j < 160; j++) s[t][j] *= inv;
    }
    __syncthreads();
    if (t < 128) {
        int g = t >> 6, d = t & 63;
        float o = 0.f;
        for (int j = 0; j < 160; j++) {
            int kpos = selb[j >> 5] * SEL_BLK + (j & 31);
            o += s[g][j] * vt[((size_t)h * NTOK + kpos) * HD + d];
        }
        fout[(((size_t)(h * 2 + g)) * NTOK + i) * HD + d] = o;
    }
}

// ---------------- Sliding-window attention ----------------
__global__ __launch_bounds__(256) void sattn_kernel(const float* __restrict__ rq,
                                                    const float* __restrict__ rk,
                                                    const float* __restrict__ vt,
                                                    float* __restrict__ sout) {
    int h = blockIdx.x >> 11, i = blockIdx.x & 2047;
    int t = threadIdx.x;
    __shared__ float qs[2][64];
    __shared__ float s[2][64];
    if (t < 128) {
        int g = t >> 6, d = t & 63;
        qs[g][d] = rq[(((size_t)(h * 2 + g)) * NTOK + i) * HD + d];
    }
    __syncthreads();
    if (t < 64) {
        int kpos = i - 63 + t;
        if (kpos >= 0) {
            const float* kp = rk + ((size_t)h * NTOK + kpos) * HD;
            float s0 = 0.f, s1 = 0.f;
            for (int d = 0; d < 64; d++) {
                float kv = kp[d];
                s0 += qs[0][d] * kv;
                s1 += qs[1][d] * kv;
            }
            s[0][t] = s0 * SCALE;
            s[1][t] = s1 * SCALE;
        } else {
            s[0][t] = NEGF;
            s[1][t] = NEGF;
        }
    }
    __syncthreads();
    if (t < 2) {
        float m = NEGF;
        for (int j = 0; j < 64; j++) m = fmaxf(m, s[t][j]);
        float den = 0.f;
        for (int j = 0; j < 64; j++) {
            float e = expf(s[t][j] - m);
            s[t][j] = e;
            den += e;
        }
        float inv = 1.f / den;
        for (int j = 0; j < 64; j++) s[t][j] *= inv;
    }
    __syncthreads();
    if (t < 128) {
        int g = t >> 6, d = t & 63;
        float o = 0.f;
        for (int j = 0; j < 64; j++) {
            int kpos = i - 63 + j;
            if (kpos >= 0) o += s[g][j] * vt[((size_t)h * NTOK + kpos) * HD + d];
        }
        sout[(((size_t)(h * 2 + g)) * NTOK + i) * HD + d] = o;
    }
}

// ---------------- Gated combine (sigmoid applied here; writes bf16) ----------------
__global__ __launch_bounds__(256) void combine_kernel(const float* __restrict__ gateslin,
                                                      const float* __restrict__ cout,
                                                      const float* __restrict__ fout,
                                                      const float* __restrict__ sout,
                                                      __hip_bfloat16* __restrict__ att) {
    int n = blockIdx.x;
    for (int c = threadIdx.x; c < NH * HD; c += 256) {
        int hd = c >> 6, d = c & 63;
        float g0 = 1.f / (1.f + expf(-gateslin[(size_t)n * (NH * 3) + hd * 3 + 0]));
        float g1 = 1.f / (1.f + expf(-gateslin[(size_t)n * (NH * 3) + hd * 3 + 1]));
        float g2 = 1.f / (1.f + expf(-gateslin[(size_t)n * (NH * 3) + hd * 3 + 2]));
        size_t o = ((size_t)hd * NTOK + n) * HD + d;
        att[(size_t)n * (NH * HD) + c] =
            __float2bfloat16(g0 * cout[o] + g1 * fout[o] + g2 * sout[o]);
    }
}

extern "C" void kernel_launch(void* const* d_in, const int* in_sizes, int n_in,
                              void* d_out, int out_size, void* d_ws, size_t ws_size,
                              hipStream_t stream) {
    const float* inp    = (const float*)d_in[0];
    const float* norm_g = (const float*)d_in[1];
    const float* Wqkv   = (const float*)d_in[2];
    const float* mem_kv = (const float*)d_in[3];
    const float* k_pos  = (const float*)d_in[4];
    const float* v_pos  = (const float*)d_in[5];
    const float* kW1    = (const float*)d_in[6];
    const float* kb1    = (const float*)d_in[7];
    const float* kW2    = (const float*)d_in[8];
    const float* kb2    = (const float*)d_in[9];
    const float* vW1    = (const float*)d_in[10];
    const float* vb1    = (const float*)d_in[11];
    const float* vW2    = (const float*)d_in[12];
    const float* vb2    = (const float*)d_in[13];
    const float* combW  = (const float*)d_in[14];
    const float* combB  = (const float*)d_in[15];
    const float* Wout   = (const float*)d_in[16];
    float* out = (float*)d_out;

    char* base = (char*)d_ws;
    size_t off = 0;
    auto alloc = [&](size_t bytes) {
        void* p = base + off;
        off += (bytes + 255) & ~(size_t)255;
        return p;
    };
    float* x            = (float*)alloc((size_t)NTOK * DIM * 4);
    __hip_bfloat16* xb  = (__hip_bfloat16*)alloc((size_t)NTOK * DIM * 2);
    float* qkv          = (float*)alloc((size_t)NTOK * 2048 * 4);
    __hip_bfloat16* Wqkvt = (__hip_bfloat16*)alloc((size_t)2048 * 1024 * 2);
    __hip_bfloat16* kW1t  = (__hip_bfloat16*)alloc((size_t)2048 * 2048 * 2);
    __hip_bfloat16* vW1t  = (__hip_bfloat16*)alloc((size_t)2048 * 2048 * 2);
    __hip_bfloat16* Woutt = (__hip_bfloat16*)alloc((size_t)1024 * 1024 * 2);
    __hip_bfloat16* combWt = (__hip_bfloat16*)alloc((size_t)48 * 1024 * 2);
    __hip_bfloat16* kW2t  = (__hip_bfloat16*)alloc((size_t)64 * 2048 * 2);
    __hip_bfloat16* vW2t  = (__hip_bfloat16*)alloc((size_t)64 * 2048 * 2);
    __hip_bfloat16* kwflat = (__hip_bfloat16*)alloc((size_t)KVH * NCB * HIDN * 2);
    __hip_bfloat16* vwflat = (__hip_bfloat16*)alloc((size_t)KVH * NCB * HIDN * 2);
    __hip_bfloat16* hidb  = (__hip_bfloat16*)alloc((size_t)KVH * NCB * HIDN * 2);
    float* ckraw        = (float*)alloc((size_t)KVH * NCB * HD * 4);
    float* cvraw        = (float*)alloc((size_t)KVH * NCB * HD * 4);
    float* rq           = (float*)alloc((size_t)NH * NTOK * HD * 4);
    float* rk           = (float*)alloc((size_t)KVH * NTOK * HD * 4);
    float* vt           = (float*)alloc((size_t)KVH * NTOK * HD * 4);
    float* coutb        = (float*)alloc((size_t)NH * NTOK * HD * 4);
    float* foutb        = (float*)alloc((size_t)NH * NTOK * HD * 4);
    float* soutb        = (float*)alloc((size_t)NH * NTOK * HD * 4);
    float* impb         = (float*)alloc((size_t)KVH * NTOK * NFB * 4);
    float* gatesb       = (float*)alloc((size_t)NTOK * NH * 3 * 4);
    __hip_bfloat16* attb = (__hip_bfloat16*)alloc((size_t)NTOK * DIM * 2);
    int* selidx         = (int*)alloc((size_t)KVH * NTOK * 5 * 4);
    int* selmask        = (int*)alloc((size_t)KVH * NTOK * 4);
    (void)ws_size; (void)in_sizes; (void)n_in; (void)out_size;

    // 1. RMSNorm (fp32 + bf16)
    rmsnorm_kernel<<<NTOK, 256, 0, stream>>>(inp, norm_g, x, xb);
    // 2. transpose-cast weights to bf16 NxK
    transpose_cast_kernel<<<dim3(64, 32), 256, 0, stream>>>(Wqkv, Wqkvt, 1024, 2048);
    transpose_cast_kernel<<<dim3(64, 64), 256, 0, stream>>>(kW1, kW1t, 2048, 2048);
    transpose_cast_kernel<<<dim3(64, 64), 256, 0, stream>>>(vW1, vW1t, 2048, 2048);
    transpose_cast_kernel<<<dim3(32, 32), 256, 0, stream>>>(Wout, Woutt, 1024, 1024);
    transpose_cast_kernel<<<dim3(2, 32), 256, 0, stream>>>(combW, combWt, 1024, 48);
    transpose_cast_kernel<<<dim3(2, 64), 256, 0, stream>>>(kW2, kW2t, 2048, 64);
    transpose_cast_kernel<<<dim3(2, 64), 256, 0, stream>>>(vW2, vW2t, 2048, 64);
    // 3. qkv = x @ Wqkv  (MFMA)
    mfma_gemm<0, 0><<<dim3(16, 16), 256, 0, stream>>>(xb, Wqkvt, nullptr, qkv, 2048, 2048, 1024);
    // 4. gates linear = x @ combW + combB  (split-K MFMA, sigmoid in combine)
    initbias_kernel<<<(NTOK * 48 + 255) / 256, 256, 0, stream>>>(gatesb, combB, NTOK, 48);
    skgemm_kernel<<<dim3(1, 16, 4), 256, 0, stream>>>(xb, combWt, gatesb, 2048, 48, 1024);
    // 5. build compressed windows (bf16)
    buildwin_kernel<<<4096, 256, 0, stream>>>(qkv, k_pos, v_pos, kwflat, vwflat);
    // 6. compressed-K MLP: hidb = relu(kw @ kW1 + kb1) bf16; ckraw = hidb @ kW2 + kb2
    mfma_gemm<1, 1><<<dim3(16, 8), 256, 0, stream>>>(kwflat, kW1t, kb1, hidb, 1024, 2048, 2048);
    initbias_kernel<<<(1024 * 64 + 255) / 256, 256, 0, stream>>>(ckraw, kb2, 1024, 64);
    skgemm_kernel<<<dim3(1, 8, 8), 256, 0, stream>>>(hidb, kW2t, ckraw, 1024, 64, 2048);
    // 7. compressed-V MLP
    mfma_gemm<1, 1><<<dim3(16, 8), 256, 0, stream>>>(vwflat, vW1t, vb1, hidb, 1024, 2048, 2048);
    initbias_kernel<<<(1024 * 64 + 255) / 256, 256, 0, stream>>>(cvraw, vb2, 1024, 64);
    skgemm_kernel<<<dim3(1, 8, 8), 256, 0, stream>>>(hidb, vW2t, cvraw, 1024, 64, 2048);
    // 8. RoPE + transposes
    rope_kernel<<<NTOK, 256, 0, stream>>>(qkv, rq, rk, vt);
    // 9. compressed attention + importance (tiled)
    cattn2_kernel<<<KVH * (NTOK / 32), 256, 0, stream>>>(qkv, ckraw, cvraw, mem_kv, coutb, impb);
    // 10. top-k block selection
    topk_kernel<<<(KVH * NTOK) / 256, 256, 0, stream>>>(impb, selidx, selmask);
    // 11. fine attention
    fattn_kernel<<<KVH * NTOK, 256, 0, stream>>>(rq, rk, vt, selidx, selmask, foutb);
    // 12. sliding-window attention
    sattn_kernel<<<KVH * NTOK, 256, 0, stream>>>(rq, rk, vt, soutb);
    // 13. gated combine (sigmoid here, bf16 out)
    combine_kernel<<<NTOK, 256, 0, stream>>>(gatesb, coutb, foutb, soutb, attb);
    // 14. out projection (MFMA)
    mfma_gemm<0, 0><<<dim3(8, 16), 256, 0, stream>>>(attb, Woutt, nullptr, out, 2048, 1024, 1024);
}

// Round 4
// 557.733 us; speedup vs baseline: 5.5065x; 1.4690x over previous
//
#include <hip/hip_runtime.h>
#include <hip/hip_bf16.h>

// Problem constants
#define NTOK 2048
#define DIM 1024
#define NH 16
#define KVH 8
#define GQ 2
#define HD 64
#define WS 64
#define CBS 32
#define STRIDE 16
#define SEL_BLK 32
#define NSEL 4
#define NMEM 1
#define NCB 128          // N/STRIDE
#define NFB 64           // N/SEL_BLK
#define HIDN 2048        // CBS*HD
#define SCALE 0.125f
#define NEGF (-3.4028234663852886e38f)
#define NEG10F (-3.4028234663852886e37f)

typedef __attribute__((ext_vector_type(8))) short bf16x8;
typedef __attribute__((ext_vector_type(4))) float f32x4;

// ---------------- RMSNorm (writes fp32 x and bf16 xb) ----------------
__global__ __launch_bounds__(256) void rmsnorm_kernel(const float* __restrict__ inp,
                                                      const float* __restrict__ g,
                                                      float* __restrict__ x,
                                                      __hip_bfloat16* __restrict__ xb) {
    int n = blockIdx.x;
    const float* row = inp + (size_t)n * DIM;
    float ss = 0.f;
    for (int c = threadIdx.x; c < DIM; c += 256) { float v = row[c]; ss += v * v; }
    __shared__ float red[4];
    for (int o = 32; o; o >>= 1) ss += __shfl_down(ss, o, 64);
    if ((threadIdx.x & 63) == 0) red[threadIdx.x >> 6] = ss;
    __syncthreads();
    if (threadIdx.x == 0) red[0] = red[0] + red[1] + red[2] + red[3];
    __syncthreads();
    float rs = 1.0f / sqrtf(red[0] / (float)DIM + 1.1920928955078125e-07f);
    float* xr = x + (size_t)n * DIM;
    __hip_bfloat16* xbr = xb + (size_t)n * DIM;
    for (int c = threadIdx.x; c < DIM; c += 256) {
        float v = row[c] * rs * g[c];
        xr[c] = v;
        xbr[c] = __float2bfloat16(v);
    }
}

// ---------------- Transpose + cast fp32 B[K][N] -> bf16 Bt[N][K] (bounds-checked) ----
__global__ __launch_bounds__(256) void transpose_cast_kernel(const float* __restrict__ B,
                                                             __hip_bfloat16* __restrict__ Bt,
                                                             int K, int N) {
    __shared__ float tile[32][33];
    int n0 = blockIdx.x * 32, k0 = blockIdx.y * 32;
    int x = threadIdx.x & 31, y = threadIdx.x >> 5;  // y in 0..7
    for (int i = 0; i < 4; i++) {
        int k = k0 + y + 8 * i, n = n0 + x;
        tile[y + 8 * i][x] = (k < K && n < N) ? B[(size_t)k * N + n] : 0.f;
    }
    __syncthreads();
    for (int i = 0; i < 4; i++) {
        int n = n0 + y + 8 * i, k = k0 + x;
        if (n < N && k < K) Bt[(size_t)n * K + k] = __float2bfloat16(tile[x][y + 8 * i]);
    }
}

// ---------------- bf16 MFMA GEMM: C = act(A @ Bt^T + bias) ----------------
template <int ACT, int OUTBF16>
__global__ __launch_bounds__(256) void mfma_gemm(const __hip_bfloat16* __restrict__ A,
                                                 const __hip_bfloat16* __restrict__ Bt,
                                                 const float* __restrict__ bias,
                                                 void* __restrict__ Cp,
                                                 int M, int N, int K) {
    __shared__ __align__(16) short As[128 * 32];
    __shared__ __align__(16) short Bs[128 * 32];
    int tid = threadIdx.x;
    int lane = tid & 63, wave = tid >> 6;
    int wm = (wave >> 1) * 64, wn = (wave & 1) * 64;
    int m0 = blockIdx.y * 128, n0 = blockIdx.x * 128;
    f32x4 acc[4][4];
    for (int r = 0; r < 4; r++)
        for (int c = 0; c < 4; c++)
            acc[r][c] = (f32x4){0.f, 0.f, 0.f, 0.f};

    int r0 = tid >> 2, kc0 = tid & 3;
    int r1 = (tid + 256) >> 2, kc1 = tid & 3;

    for (int k0 = 0; k0 < K; k0 += 32) {
        __syncthreads();
        *(uint4*)&As[r0 * 32 + kc0 * 8] =
            *(const uint4*)(A + (size_t)(m0 + r0) * K + k0 + kc0 * 8);
        *(uint4*)&As[r1 * 32 + kc1 * 8] =
            *(const uint4*)(A + (size_t)(m0 + r1) * K + k0 + kc1 * 8);
        *(uint4*)&Bs[r0 * 32 + kc0 * 8] =
            *(const uint4*)(Bt + (size_t)(n0 + r0) * K + k0 + kc0 * 8);
        *(uint4*)&Bs[r1 * 32 + kc1 * 8] =
            *(const uint4*)(Bt + (size_t)(n0 + r1) * K + k0 + kc1 * 8);
        __syncthreads();
        bf16x8 af[4], bfr[4];
#pragma unroll
        for (int r = 0; r < 4; r++)
            af[r] = *(const bf16x8*)&As[(wm + r * 16 + (lane & 15)) * 32 + (lane >> 4) * 8];
#pragma unroll
        for (int c = 0; c < 4; c++)
            bfr[c] = *(const bf16x8*)&Bs[(wn + c * 16 + (lane & 15)) * 32 + (lane >> 4) * 8];
#pragma unroll
        for (int r = 0; r < 4; r++)
#pragma unroll
            for (int c = 0; c < 4; c++)
                acc[r][c] = __builtin_amdgcn_mfma_f32_16x16x32_bf16(af[r], bfr[c], acc[r][c], 0, 0, 0);
    }
    for (int r = 0; r < 4; r++) {
        int grow = m0 + wm + r * 16 + (lane >> 4) * 4;
        for (int c = 0; c < 4; c++) {
            int gcol = n0 + wn + c * 16 + (lane & 15);
            float bv = bias ? bias[gcol] : 0.f;
#pragma unroll
            for (int v = 0; v < 4; v++) {
                float val = acc[r][c][v] + bv;
                if (ACT == 1) val = fmaxf(val, 0.f);
                if (OUTBF16)
                    ((__hip_bfloat16*)Cp)[(size_t)(grow + v) * N + gcol] = __float2bfloat16(val);
                else
                    ((float*)Cp)[(size_t)(grow + v) * N + gcol] = val;
            }
        }
    }
}

// ---------------- Split-K skinny MFMA GEMM: C += A @ Bt^T (atomicAdd) ----------------
__global__ __launch_bounds__(256) void skgemm_kernel(const __hip_bfloat16* __restrict__ A,
                                                     const __hip_bfloat16* __restrict__ Bt,
                                                     float* __restrict__ C,
                                                     int M, int Nout, int K) {
    __shared__ __align__(16) short As[128 * 32];
    __shared__ __align__(16) short Bs[64 * 32];
    int tid = threadIdx.x;
    int lane = tid & 63, wave = tid >> 6;
    int m0 = blockIdx.y * 128;
    int wm = wave * 32;
    int kchunk = K / (int)gridDim.z;
    int kbase = blockIdx.z * kchunk;
    f32x4 acc[2][4];
    for (int r = 0; r < 2; r++)
        for (int c = 0; c < 4; c++) acc[r][c] = (f32x4){0.f, 0.f, 0.f, 0.f};

    int ra = tid >> 2, kc = (tid & 3) * 8;
    for (int k0 = kbase; k0 < kbase + kchunk; k0 += 32) {
        __syncthreads();
        *(uint4*)&As[ra * 32 + kc] = *(const uint4*)(A + (size_t)(m0 + ra) * K + k0 + kc);
        *(uint4*)&As[(ra + 64) * 32 + kc] =
            *(const uint4*)(A + (size_t)(m0 + ra + 64) * K + k0 + kc);
        uint4 bv = (uint4){0u, 0u, 0u, 0u};
        if (ra < Nout) bv = *(const uint4*)(Bt + (size_t)ra * K + k0 + kc);
        *(uint4*)&Bs[ra * 32 + kc] = bv;
        __syncthreads();
        bf16x8 af[2], bfr[4];
#pragma unroll
        for (int r = 0; r < 2; r++)
            af[r] = *(const bf16x8*)&As[(wm + r * 16 + (lane & 15)) * 32 + (lane >> 4) * 8];
#pragma unroll
        for (int c = 0; c < 4; c++)
            bfr[c] = *(const bf16x8*)&Bs[(c * 16 + (lane & 15)) * 32 + (lane >> 4) * 8];
#pragma unroll
        for (int r = 0; r < 2; r++)
#pragma unroll
            for (int c = 0; c < 4; c++)
                acc[r][c] = __builtin_amdgcn_mfma_f32_16x16x32_bf16(af[r], bfr[c], acc[r][c], 0, 0, 0);
    }
    for (int r = 0; r < 2; r++) {
        int grow = m0 + wm + r * 16 + (lane >> 4) * 4;
        for (int c = 0; c < 4; c++) {
            int gcol = c * 16 + (lane & 15);
            if (gcol >= Nout) continue;
#pragma unroll
            for (int v = 0; v < 4; v++)
                atomicAdd(&C[(size_t)(grow + v) * Nout + gcol], acc[r][c][v]);
        }
    }
}

// ---------------- init C with broadcast bias ----------------
__global__ __launch_bounds__(256) void initbias_kernel(float* __restrict__ C,
                                                       const float* __restrict__ bias,
                                                       int M, int Nout) {
    int idx = blockIdx.x * 256 + threadIdx.x;
    if (idx < M * Nout) C[idx] = bias[idx % Nout];
}

// ---------------- Build compressed windows (bf16 MLP input) ----------------
__global__ __launch_bounds__(256) void buildwin_kernel(const float* __restrict__ qkv,
                                                       const float* __restrict__ k_pos,
                                                       const float* __restrict__ v_pos,
                                                       __hip_bfloat16* __restrict__ kwflat,
                                                       __hip_bfloat16* __restrict__ vwflat) {
    size_t total = (size_t)(KVH * NCB) * HIDN;
    for (size_t e = (size_t)blockIdx.x * 256 + threadIdx.x; e < total;
         e += (size_t)gridDim.x * 256) {
        int r = (int)(e >> 11);
        int c = (int)(e & 2047);
        int j = c >> 6, d = c & 63;
        int h = r >> 7, i = r & 127;
        int p = i * STRIDE + j - (CBS - STRIDE);
        float kb = k_pos[((size_t)h * CBS + j) * HD + d];
        float vb = v_pos[((size_t)h * CBS + j) * HD + d];
        float kv = 0.f, vv = 0.f;
        if (p >= 0) {
            kv = qkv[(size_t)p * 2048 + 1024 + h * HD + d];
            vv = qkv[(size_t)p * 2048 + 1536 + h * HD + d];
        }
        kwflat[e] = __float2bfloat16(kv + kb);
        vwflat[e] = __float2bfloat16(vv + vb);
    }
}

// ---------------- RoPE + transpose ----------------
__global__ __launch_bounds__(256) void rope_kernel(const float* __restrict__ qkv,
                                                   float* __restrict__ rq,
                                                   float* __restrict__ rk,
                                                   float* __restrict__ vt) {
    int n = blockIdx.x;
    int t = threadIdx.x;
    for (int idx = t; idx < NH * 32; idx += 256) {
        int h = idx >> 5, f = idx & 31;
        float inv = powf(10000.f, -((float)(2 * f)) / 64.f);
        float ang = (float)n * inv;
        float cc = cosf(ang), ssn = sinf(ang);
        float a = qkv[(size_t)n * 2048 + h * HD + 2 * f];
        float b = qkv[(size_t)n * 2048 + h * HD + 2 * f + 1];
        float* o = rq + ((size_t)h * NTOK + n) * HD + 2 * f;
        o[0] = a * cc - b * ssn;
        o[1] = b * cc + a * ssn;
    }
    for (int idx = t; idx < KVH * 32; idx += 256) {
        int h = idx >> 5, f = idx & 31;
        float inv = powf(10000.f, -((float)(2 * f)) / 64.f);
        float ang = (float)n * inv;
        float cc = cosf(ang), ssn = sinf(ang);
        float a = qkv[(size_t)n * 2048 + 1024 + h * HD + 2 * f];
        float b = qkv[(size_t)n * 2048 + 1024 + h * HD + 2 * f + 1];
        float* o = rk + ((size_t)h * NTOK + n) * HD + 2 * f;
        o[0] = a * cc - b * ssn;
        o[1] = b * cc + a * ssn;
    }
    for (int idx = t; idx < KVH * HD; idx += 256) {
        int h = idx >> 6, d = idx & 63;
        vt[((size_t)h * NTOK + n) * HD + d] = qkv[(size_t)n * 2048 + 1536 + h * HD + d];
    }
}

// ---------------- Compressed attention + importance (tiled) ----------------
__global__ __launch_bounds__(256) void cattn2_kernel(const float* __restrict__ qkv,
                                                     const float* __restrict__ ckraw,
                                                     const float* __restrict__ cvraw,
                                                     const float* __restrict__ memkv,
                                                     float* __restrict__ cout,
                                                     float* __restrict__ imp) {
    int h = blockIdx.x >> 6;
    int i0 = (blockIdx.x & 63) * 32;
    int t = threadIdx.x;
    __shared__ float qs[64][68];
    __shared__ float sc[64][132];
    __shared__ float scratch[32 * 68];
    __shared__ float memk[64], memv[64];
    __shared__ float impm[32], impd[32];

    for (int idx = t; idx < 4096; idx += 256) {
        int row = idx >> 6, d = idx & 63;
        int g = row >> 5, qi = row & 31;
        qs[row][d] = qkv[(size_t)(i0 + qi) * 2048 + (h * 2 + g) * 64 + d];
    }
    if (t < 64) { memk[t] = memkv[h * 64 + t]; memv[t] = memkv[(8 + h) * 64 + t]; }
    __syncthreads();
    if (t < 64) {
        float s = 0.f;
        for (int d = 0; d < 64; d++) s += qs[t][d] * memk[d];
        sc[t][0] = s * SCALE;
    }
    int rg = t >> 3, kg = t & 7;
    for (int c = 0; c < 4; c++) {
        __syncthreads();
        for (int idx = t; idx < 2048; idx += 256) {
            int jj = idx >> 6, d = idx & 63;
            scratch[jj * 68 + d] = ckraw[((size_t)h * 128 + c * 32 + jj) * 64 + d];
        }
        __syncthreads();
        float a0[4] = {}, a1[4] = {};
        for (int d = 0; d < 64; d += 4) {
            float4 q0 = *(const float4*)&qs[rg * 2][d];
            float4 q1 = *(const float4*)&qs[rg * 2 + 1][d];
#pragma unroll
            for (int kk = 0; kk < 4; kk++) {
                float4 kv = *(const float4*)&scratch[(kg + kk * 8) * 68 + d];
                a0[kk] += q0.x * kv.x + q0.y * kv.y + q0.z * kv.z + q0.w * kv.w;
                a1[kk] += q1.x * kv.x + q1.y * kv.y + q1.z * kv.z + q1.w * kv.w;
            }
        }
#pragma unroll
        for (int kk = 0; kk < 4; kk++) {
            sc[rg * 2][1 + c * 32 + kg + kk * 8] = a0[kk] * SCALE;
            sc[rg * 2 + 1][1 + c * 32 + kg + kk * 8] = a1[kk] * SCALE;
        }
    }
    __syncthreads();
    for (int idx = t; idx < 2048; idx += 256) {
        int qi = idx >> 6, fb = idx & 63;
        float v = 0.25f * (sc[qi][1 + 2 * fb] + sc[qi][2 + 2 * fb] +
                           sc[32 + qi][1 + 2 * fb] + sc[32 + qi][2 + 2 * fb]);
        if (fb == ((i0 + qi) >> 5)) v = NEGF;
        scratch[qi * 66 + fb] = v;
    }
    __syncthreads();
    if (t < 32) {
        float m = -1000.f;
        for (int j = 0; j < 64; j++) m = fmaxf(m, scratch[t * 66 + j]);
        float den = expf(-1000.f - m);
        for (int j = 0; j < 64; j++) den += expf(scratch[t * 66 + j] - m);
        impm[t] = m; impd[t] = 1.f / den;
    } else if (t >= 64 && t < 128) {
        int r = t - 64;
        float m = NEGF;
        for (int j = 0; j < 129; j++) m = fmaxf(m, sc[r][j]);
        float den = 0.f;
        for (int j = 0; j < 129; j++) { float e = expf(sc[r][j] - m); sc[r][j] = e; den += e; }
        float inv = 1.f / den;
        for (int j = 0; j < 129; j++) sc[r][j] *= inv;
    }
    __syncthreads();
    for (int idx = t; idx < 2048; idx += 256) {
        int qi = idx >> 6, fb = idx & 63;
        imp[((size_t)h * NTOK + i0 + qi) * 64 + fb] =
            expf(scratch[qi * 66 + fb] - impm[qi]) * impd[qi];
    }
    int dg = t & 7;
    float o0[8], o1[8];
    {
        float p0 = sc[rg * 2][0], p1 = sc[rg * 2 + 1][0];
#pragma unroll
        for (int dd = 0; dd < 8; dd++) {
            float v = memv[dg + dd * 8];
            o0[dd] = p0 * v;
            o1[dd] = p1 * v;
        }
    }
    for (int c = 0; c < 4; c++) {
        __syncthreads();
        for (int idx = t; idx < 2048; idx += 256) {
            int jj = idx >> 6, d = idx & 63;
            scratch[jj * 68 + d] = cvraw[((size_t)h * 128 + c * 32 + jj) * 64 + d];
        }
        __syncthreads();
        for (int jj = 0; jj < 32; jj++) {
            float p0 = sc[rg * 2][1 + c * 32 + jj];
            float p1 = sc[rg * 2 + 1][1 + c * 32 + jj];
#pragma unroll
            for (int dd = 0; dd < 8; dd++) {
                float v = scratch[jj * 68 + dg + dd * 8];
                o0[dd] += p0 * v;
                o1[dd] += p1 * v;
            }
        }
    }
    {
        int row = rg * 2;
        int g = row >> 5, qi = row & 31;
        int g2 = (row + 1) >> 5, qi2 = (row + 1) & 31;
#pragma unroll
        for (int dd = 0; dd < 8; dd++) {
            cout[(((size_t)(h * 2 + g)) * NTOK + i0 + qi) * 64 + dd * 8 + dg] = o0[dd];
            cout[(((size_t)(h * 2 + g2)) * NTOK + i0 + qi2) * 64 + dd * 8 + dg] = o1[dd];
        }
    }
}

// ---------------- Top-k selection ----------------
__global__ __launch_bounds__(256) void topk_kernel(const float* __restrict__ imp,
                                                   int* __restrict__ selidx,
                                                   int* __restrict__ selmask) {
    int idx = blockIdx.x * 256 + threadIdx.x;
    if (idx >= KVH * NTOK) return;
    const float* ip = imp + (size_t)idx * NFB;
    float v[NFB];
    for (int j = 0; j < NFB; j++) v[j] = ip[j];
    unsigned long long taken = 0ull;
    int mk = 0;
    int i = idx & 2047;
    for (int p = 0; p < NSEL; p++) {
        float bv = NEGF;
        int bi = 0;
        for (int j = 0; j < NFB; j++) {
            if (!((taken >> j) & 1ull) && v[j] > bv) { bv = v[j]; bi = j; }
        }
        taken |= 1ull << bi;
        selidx[(size_t)idx * 5 + p] = bi;
        if (bv > 1e-10f) mk |= 1 << p;
    }
    selidx[(size_t)idx * 5 + 4] = i >> 5;
    selmask[idx] = mk;
}

// ---------------- Fine attention: one wave per (h, i) ----------------
// QK phase: lane = c*16+kk -> 16 keys x 4 dim-chunks, shfl_xor reduce over c.
// Softmax: wave-parallel over 160 scores in LDS.
// PV phase: lane = d, probabilities broadcast from LDS.
__global__ __launch_bounds__(256) void fattn2_kernel(const float* __restrict__ rq,
                                                     const float* __restrict__ rk,
                                                     const float* __restrict__ vt,
                                                     const int* __restrict__ selidx,
                                                     const int* __restrict__ selmask,
                                                     float* __restrict__ fout) {
    int ws = threadIdx.x >> 6, lane = threadIdx.x & 63;
    int wid = blockIdx.x * 4 + ws;
    int h = wid >> 11, i = wid & 2047;
    __shared__ float sp[4][2][160];
    __shared__ int sel[4][5];
    __shared__ int smk[4];
    float* p0 = sp[ws][0];
    float* p1 = sp[ws][1];
    if (lane < 5) sel[ws][lane] = selidx[((size_t)h * NTOK + i) * 5 + lane];
    if (lane == 5) smk[ws] = selmask[h * NTOK + i];

    int kk = lane & 15, c = lane >> 4;
    const float* q0p = rq + ((size_t)(h * 2 + 0) * NTOK + i) * 64 + c * 16;
    const float* q1p = rq + ((size_t)(h * 2 + 1) * NTOK + i) * 64 + c * 16;
    float4 q0[4], q1[4];
#pragma unroll
    for (int u = 0; u < 4; u++) {
        q0[u] = *(const float4*)(q0p + u * 4);
        q1[u] = *(const float4*)(q1p + u * 4);
    }
    __syncthreads();  // sel/smk visible
    int mk = smk[ws];
    int iq = i & 31;
#pragma unroll
    for (int kt = 0; kt < 10; kt++) {
        int slot = kt >> 1;
        int blk = sel[ws][slot];
        int key = kt * 16 + kk;
        int jj = key & 31;
        int kpos = blk * 32 + jj;
        bool valid = (slot < 4) ? (((mk >> slot) & 1) != 0) : (jj <= iq);
        const float* kr = rk + ((size_t)h * NTOK + kpos) * 64 + c * 16;
        float s0 = 0.f, s1 = 0.f;
#pragma unroll
        for (int u = 0; u < 4; u++) {
            float4 kv = *(const float4*)(kr + u * 4);
            s0 += q0[u].x * kv.x + q0[u].y * kv.y + q0[u].z * kv.z + q0[u].w * kv.w;
            s1 += q1[u].x * kv.x + q1[u].y * kv.y + q1[u].z * kv.z + q1[u].w * kv.w;
        }
        s0 += __shfl_xor(s0, 16); s0 += __shfl_xor(s0, 32);
        s1 += __shfl_xor(s1, 16); s1 += __shfl_xor(s1, 32);
        if (c == 0) {
            p0[key] = valid ? s0 * SCALE : NEG10F;
            p1[key] = valid ? s1 * SCALE : NEG10F;
        }
    }
    __syncthreads();
    // softmax over 160 (lane owns keys lane, lane+64, lane+128[if lane<32])
    {
        float a0 = p0[lane], b0 = p0[lane + 64];
        float c0 = (lane < 32) ? p0[lane + 128] : NEG10F;
        float a1 = p1[lane], b1 = p1[lane + 64];
        float c1 = (lane < 32) ? p1[lane + 128] : NEG10F;
        float m0 = fmaxf(fmaxf(a0, b0), c0);
        float m1 = fmaxf(fmaxf(a1, b1), c1);
#pragma unroll
        for (int o = 1; o < 64; o <<= 1) {
            m0 = fmaxf(m0, __shfl_xor(m0, o));
            m1 = fmaxf(m1, __shfl_xor(m1, o));
        }
        float ea0 = __expf(a0 - m0), eb0 = __expf(b0 - m0), ec0 = (lane < 32) ? __expf(c0 - m0) : 0.f;
        float ea1 = __expf(a1 - m1), eb1 = __expf(b1 - m1), ec1 = (lane < 32) ? __expf(c1 - m1) : 0.f;
        float d0 = ea0 + eb0 + ec0;
        float d1 = ea1 + eb1 + ec1;
#pragma unroll
        for (int o = 1; o < 64; o <<= 1) {
            d0 += __shfl_xor(d0, o);
            d1 += __shfl_xor(d1, o);
        }
        float inv0 = 1.f / d0, inv1 = 1.f / d1;
        p0[lane] = ea0 * inv0; p0[lane + 64] = eb0 * inv0;
        p1[lane] = ea1 * inv1; p1[lane + 64] = eb1 * inv1;
        if (lane < 32) { p0[lane + 128] = ec0 * inv0; p1[lane + 128] = ec1 * inv1; }
    }
    __syncthreads();
    // PV: lane = d
    int b0s = sel[ws][0], b1s = sel[ws][1], b2s = sel[ws][2], b3s = sel[ws][3], b4s = sel[ws][4];
    const float* vb = vt + (size_t)h * NTOK * 64 + lane;
    float o0 = 0.f, o1 = 0.f;
#pragma unroll 4
    for (int j = 0; j < 32; j++) {
        float v0 = vb[(size_t)(b0s * 32 + j) * 64];
        float v1 = vb[(size_t)(b1s * 32 + j) * 64];
        float v2 = vb[(size_t)(b2s * 32 + j) * 64];
        float v3 = vb[(size_t)(b3s * 32 + j) * 64];
        float v4 = vb[(size_t)(b4s * 32 + j) * 64];
        o0 += p0[j] * v0 + p0[32 + j] * v1 + p0[64 + j] * v2 + p0[96 + j] * v3 + p0[128 + j] * v4;
        o1 += p1[j] * v0 + p1[32 + j] * v1 + p1[64 + j] * v2 + p1[96 + j] * v3 + p1[128 + j] * v4;
    }
    fout[((size_t)(h * 2 + 0) * NTOK + i) * 64 + lane] = o0;
    fout[((size_t)(h * 2 + 1) * NTOK + i) * 64 + lane] = o1;
}

// ---------------- Sliding-window attention: one wave per (h, i) ----------------
__global__ __launch_bounds__(256) void sattn2_kernel(const float* __restrict__ rq,
                                                     const float* __restrict__ rk,
                                                     const float* __restrict__ vt,
                                                     float* __restrict__ sout) {
    int ws = threadIdx.x >> 6, lane = threadIdx.x & 63;
    int wid = blockIdx.x * 4 + ws;
    int h = wid >> 11, i = wid & 2047;
    __shared__ float sp[4][2][64];
    float* p0 = sp[ws][0];
    float* p1 = sp[ws][1];

    int kk = lane & 15, c = lane >> 4;
    const float* q0p = rq + ((size_t)(h * 2 + 0) * NTOK + i) * 64 + c * 16;
    const float* q1p = rq + ((size_t)(h * 2 + 1) * NTOK + i) * 64 + c * 16;
    float4 q0[4], q1[4];
#pragma unroll
    for (int u = 0; u < 4; u++) {
        q0[u] = *(const float4*)(q0p + u * 4);
        q1[u] = *(const float4*)(q1p + u * 4);
    }
#pragma unroll
    for (int kt = 0; kt < 4; kt++) {
        int key = kt * 16 + kk;
        int kpos = i - 63 + key;
        int kp = kpos < 0 ? 0 : kpos;
        const float* kr = rk + ((size_t)h * NTOK + kp) * 64 + c * 16;
        float s0 = 0.f, s1 = 0.f;
#pragma unroll
        for (int u = 0; u < 4; u++) {
            float4 kv = *(const float4*)(kr + u * 4);
            s0 += q0[u].x * kv.x + q0[u].y * kv.y + q0[u].z * kv.z + q0[u].w * kv.w;
            s1 += q1[u].x * kv.x + q1[u].y * kv.y + q1[u].z * kv.z + q1[u].w * kv.w;
        }
        s0 += __shfl_xor(s0, 16); s0 += __shfl_xor(s0, 32);
        s1 += __shfl_xor(s1, 16); s1 += __shfl_xor(s1, 32);
        if (c == 0) {
            p0[key] = (kpos >= 0) ? s0 * SCALE : NEG10F;
            p1[key] = (kpos >= 0) ? s1 * SCALE : NEG10F;
        }
    }
    __syncthreads();
    {
        float a0 = p0[lane], a1 = p1[lane];
        float m0 = a0, m1 = a1;
#pragma unroll
        for (int o = 1; o < 64; o <<= 1) {
            m0 = fmaxf(m0, __shfl_xor(m0, o));
            m1 = fmaxf(m1, __shfl_xor(m1, o));
        }
        float e0 = __expf(a0 - m0), e1 = __expf(a1 - m1);
        float d0 = e0, d1 = e1;
#pragma unroll
        for (int o = 1; o < 64; o <<= 1) {
            d0 += __shfl_xor(d0, o);
            d1 += __shfl_xor(d1, o);
        }
        p0[lane] = e0 / d0;
        p1[lane] = e1 / d1;
    }
    __syncthreads();
    // PV: lane = d
    int base = i - 63;
    int jstart = base < 0 ? -base : 0;
    const float* vb = vt + ((size_t)h * NTOK + base) * 64 + lane;
    float o0 = 0.f, o1 = 0.f;
#pragma unroll 4
    for (int j = jstart; j < 64; j++) {
        float v = vb[(size_t)j * 64];
        o0 += p0[j] * v;
        o1 += p1[j] * v;
    }
    sout[((size_t)(h * 2 + 0) * NTOK + i) * 64 + lane] = o0;
    sout[((size_t)(h * 2 + 1) * NTOK + i) * 64 + lane] = o1;
}

// ---------------- Gated combine (sigmoid applied here; writes bf16) ----------------
__global__ __launch_bounds__(256) void combine_kernel(const float* __restrict__ gateslin,
                                                      const float* __restrict__ cout,
                                                      const float* __restrict__ fout,
                                                      const float* __restrict__ sout,
                                                      __hip_bfloat16* __restrict__ att) {
    int n = blockIdx.x;
    for (int c = threadIdx.x; c < NH * HD; c += 256) {
        int hd = c >> 6, d = c & 63;
        float g0 = 1.f / (1.f + expf(-gateslin[(size_t)n * (NH * 3) + hd * 3 + 0]));
        float g1 = 1.f / (1.f + expf(-gateslin[(size_t)n * (NH * 3) + hd * 3 + 1]));
        float g2 = 1.f / (1.f + expf(-gateslin[(size_t)n * (NH * 3) + hd * 3 + 2]));
        size_t o = ((size_t)hd * NTOK + n) * HD + d;
        att[(size_t)n * (NH * HD) + c] =
            __float2bfloat16(g0 * cout[o] + g1 * fout[o] + g2 * sout[o]);
    }
}

extern "C" void kernel_launch(void* const* d_in, const int* in_sizes, int n_in,
                              void* d_out, int out_size, void* d_ws, size_t ws_size,
                              hipStream_t stream) {
    const float* inp    = (const float*)d_in[0];
    const float* norm_g = (const float*)d_in[1];
    const float* Wqkv   = (const float*)d_in[2];
    const float* mem_kv = (const float*)d_in[3];
    const float* k_pos  = (const float*)d_in[4];
    const float* v_pos  = (const float*)d_in[5];
    const float* kW1    = (const float*)d_in[6];
    const float* kb1    = (const float*)d_in[7];
    const float* kW2    = (const float*)d_in[8];
    const float* kb2    = (const float*)d_in[9];
    const float* vW1    = (const float*)d_in[10];
    const float* vb1    = (const float*)d_in[11];
    const float* vW2    = (const float*)d_in[12];
    const float* vb2    = (const float*)d_in[13];
    const float* combW  = (const float*)d_in[14];
    const float* combB  = (const float*)d_in[15];
    const float* Wout   = (const float*)d_in[16];
    float* out = (float*)d_out;

    char* base = (char*)d_ws;
    size_t off = 0;
    auto alloc = [&](size_t bytes) {
        void* p = base + off;
        off += (bytes + 255) & ~(size_t)255;
        return p;
    };
    float* x            = (float*)alloc((size_t)NTOK * DIM * 4);
    __hip_bfloat16* xb  = (__hip_bfloat16*)alloc((size_t)NTOK * DIM * 2);
    float* qkv          = (float*)alloc((size_t)NTOK * 2048 * 4);
    __hip_bfloat16* Wqkvt = (__hip_bfloat16*)alloc((size_t)2048 * 1024 * 2);
    __hip_bfloat16* kW1t  = (__hip_bfloat16*)alloc((size_t)2048 * 2048 * 2);
    __hip_bfloat16* vW1t  = (__hip_bfloat16*)alloc((size_t)2048 * 2048 * 2);
    __hip_bfloat16* Woutt = (__hip_bfloat16*)alloc((size_t)1024 * 1024 * 2);
    __hip_bfloat16* combWt = (__hip_bfloat16*)alloc((size_t)48 * 1024 * 2);
    __hip_bfloat16* kW2t  = (__hip_bfloat16*)alloc((size_t)64 * 2048 * 2);
    __hip_bfloat16* vW2t  = (__hip_bfloat16*)alloc((size_t)64 * 2048 * 2);
    __hip_bfloat16* kwflat = (__hip_bfloat16*)alloc((size_t)KVH * NCB * HIDN * 2);
    __hip_bfloat16* vwflat = (__hip_bfloat16*)alloc((size_t)KVH * NCB * HIDN * 2);
    __hip_bfloat16* hidb  = (__hip_bfloat16*)alloc((size_t)KVH * NCB * HIDN * 2);
    float* ckraw        = (float*)alloc((size_t)KVH * NCB * HD * 4);
    float* cvraw        = (float*)alloc((size_t)KVH * NCB * HD * 4);
    float* rq           = (float*)alloc((size_t)NH * NTOK * HD * 4);
    float* rk           = (float*)alloc((size_t)KVH * NTOK * HD * 4);
    float* vt           = (float*)alloc((size_t)KVH * NTOK * HD * 4);
    float* coutb        = (float*)alloc((size_t)NH * NTOK * HD * 4);
    float* foutb        = (float*)alloc((size_t)NH * NTOK * HD * 4);
    float* soutb        = (float*)alloc((size_t)NH * NTOK * HD * 4);
    float* impb         = (float*)alloc((size_t)KVH * NTOK * NFB * 4);
    float* gatesb       = (float*)alloc((size_t)NTOK * NH * 3 * 4);
    __hip_bfloat16* attb = (__hip_bfloat16*)alloc((size_t)NTOK * DIM * 2);
    int* selidx         = (int*)alloc((size_t)KVH * NTOK * 5 * 4);
    int* selmask        = (int*)alloc((size_t)KVH * NTOK * 4);
    (void)ws_size; (void)in_sizes; (void)n_in; (void)out_size;

    // 1. RMSNorm (fp32 + bf16)
    rmsnorm_kernel<<<NTOK, 256, 0, stream>>>(inp, norm_g, x, xb);
    // 2. transpose-cast weights to bf16 NxK
    transpose_cast_kernel<<<dim3(64, 32), 256, 0, stream>>>(Wqkv, Wqkvt, 1024, 2048);
    transpose_cast_kernel<<<dim3(64, 64), 256, 0, stream>>>(kW1, kW1t, 2048, 2048);
    transpose_cast_kernel<<<dim3(64, 64), 256, 0, stream>>>(vW1, vW1t, 2048, 2048);
    transpose_cast_kernel<<<dim3(32, 32), 256, 0, stream>>>(Wout, Woutt, 1024, 1024);
    transpose_cast_kernel<<<dim3(2, 32), 256, 0, stream>>>(combW, combWt, 1024, 48);
    transpose_cast_kernel<<<dim3(2, 64), 256, 0, stream>>>(kW2, kW2t, 2048, 64);
    transpose_cast_kernel<<<dim3(2, 64), 256, 0, stream>>>(vW2, vW2t, 2048, 64);
    // 3. qkv = x @ Wqkv  (MFMA)
    mfma_gemm<0, 0><<<dim3(16, 16), 256, 0, stream>>>(xb, Wqkvt, nullptr, qkv, 2048, 2048, 1024);
    // 4. gates linear = x @ combW + combB  (split-K MFMA, sigmoid in combine)
    initbias_kernel<<<(NTOK * 48 + 255) / 256, 256, 0, stream>>>(gatesb, combB, NTOK, 48);
    skgemm_kernel<<<dim3(1, 16, 4), 256, 0, stream>>>(xb, combWt, gatesb, 2048, 48, 1024);
    // 5. build compressed windows (bf16)
    buildwin_kernel<<<4096, 256, 0, stream>>>(qkv, k_pos, v_pos, kwflat, vwflat);
    // 6. compressed-K MLP
    mfma_gemm<1, 1><<<dim3(16, 8), 256, 0, stream>>>(kwflat, kW1t, kb1, hidb, 1024, 2048, 2048);
    initbias_kernel<<<(1024 * 64 + 255) / 256, 256, 0, stream>>>(ckraw, kb2, 1024, 64);
    skgemm_kernel<<<dim3(1, 8, 8), 256, 0, stream>>>(hidb, kW2t, ckraw, 1024, 64, 2048);
    // 7. compressed-V MLP
    mfma_gemm<1, 1><<<dim3(16, 8), 256, 0, stream>>>(vwflat, vW1t, vb1, hidb, 1024, 2048, 2048);
    initbias_kernel<<<(1024 * 64 + 255) / 256, 256, 0, stream>>>(cvraw, vb2, 1024, 64);
    skgemm_kernel<<<dim3(1, 8, 8), 256, 0, stream>>>(hidb, vW2t, cvraw, 1024, 64, 2048);
    // 8. RoPE + transposes
    rope_kernel<<<NTOK, 256, 0, stream>>>(qkv, rq, rk, vt);
    // 9. compressed attention + importance (tiled)
    cattn2_kernel<<<KVH * (NTOK / 32), 256, 0, stream>>>(qkv, ckraw, cvraw, mem_kv, coutb, impb);
    // 10. top-k block selection
    topk_kernel<<<(KVH * NTOK) / 256, 256, 0, stream>>>(impb, selidx, selmask);
    // 11. fine attention (wave per query)
    fattn2_kernel<<<KVH * NTOK / 4, 256, 0, stream>>>(rq, rk, vt, selidx, selmask, foutb);
    // 12. sliding-window attention (wave per query)
    sattn2_kernel<<<KVH * NTOK / 4, 256, 0, stream>>>(rq, rk, vt, soutb);
    // 13. gated combine (sigmoid here, bf16 out)
    combine_kernel<<<NTOK, 256, 0, stream>>>(gatesb, coutb, foutb, soutb, attb);
    // 14. out projection (MFMA)
    mfma_gemm<0, 0><<<dim3(8, 16), 256, 0, stream>>>(attb, Woutt, nullptr, out, 2048, 1024, 1024);
}

// Round 5
// 481.580 us; speedup vs baseline: 6.3772x; 1.1581x over previous
//
#include <hip/hip_runtime.h>
#include <hip/hip_bf16.h>

// Problem constants
#define NTOK 2048
#define DIM 1024
#define NH 16
#define KVH 8
#define GQ 2
#define HD 64
#define WS 64
#define CBS 32
#define STRIDE 16
#define SEL_BLK 32
#define NSEL 4
#define NMEM 1
#define NCB 128          // N/STRIDE
#define NFB 64           // N/SEL_BLK
#define HIDN 2048        // CBS*HD
#define SCALE 0.125f
#define NEGF (-3.4028234663852886e38f)
#define NEG10F (-3.4028234663852886e37f)

typedef __attribute__((ext_vector_type(8))) short bf16x8;
typedef __attribute__((ext_vector_type(4))) float f32x4;

// ---------------- RMSNorm (writes fp32 x and bf16 xb) ----------------
__global__ __launch_bounds__(256) void rmsnorm_kernel(const float* __restrict__ inp,
                                                      const float* __restrict__ g,
                                                      float* __restrict__ x,
                                                      __hip_bfloat16* __restrict__ xb) {
    int n = blockIdx.x;
    const float* row = inp + (size_t)n * DIM;
    float ss = 0.f;
    for (int c = threadIdx.x; c < DIM; c += 256) { float v = row[c]; ss += v * v; }
    __shared__ float red[4];
    for (int o = 32; o; o >>= 1) ss += __shfl_down(ss, o, 64);
    if ((threadIdx.x & 63) == 0) red[threadIdx.x >> 6] = ss;
    __syncthreads();
    if (threadIdx.x == 0) red[0] = red[0] + red[1] + red[2] + red[3];
    __syncthreads();
    float rs = 1.0f / sqrtf(red[0] / (float)DIM + 1.1920928955078125e-07f);
    float* xr = x + (size_t)n * DIM;
    __hip_bfloat16* xbr = xb + (size_t)n * DIM;
    for (int c = threadIdx.x; c < DIM; c += 256) {
        float v = row[c] * rs * g[c];
        xr[c] = v;
        xbr[c] = __float2bfloat16(v);
    }
}

// ---------------- Merged transpose+cast of all 7 weights ----------------
__device__ __forceinline__ void transpose_body(const float* __restrict__ B,
                                               __hip_bfloat16* __restrict__ Bt,
                                               int K, int N, int bx, int by) {
    __shared__ float tile[32][33];
    int n0 = bx * 32, k0 = by * 32;
    int x = threadIdx.x & 31, y = threadIdx.x >> 5;
    for (int i = 0; i < 4; i++) {
        int k = k0 + y + 8 * i, n = n0 + x;
        tile[y + 8 * i][x] = (k < K && n < N) ? B[(size_t)k * N + n] : 0.f;
    }
    __syncthreads();
    for (int i = 0; i < 4; i++) {
        int n = n0 + y + 8 * i, k = k0 + x;
        if (n < N && k < K) Bt[(size_t)n * K + k] = __float2bfloat16(tile[x][y + 8 * i]);
    }
}

__global__ __launch_bounds__(256) void transpose_all_kernel(
    const float* Wqkv, __hip_bfloat16* Wqkvt,
    const float* kW1, __hip_bfloat16* kW1t,
    const float* vW1, __hip_bfloat16* vW1t,
    const float* Wout, __hip_bfloat16* Woutt,
    const float* combW, __hip_bfloat16* combWt,
    const float* kW2, __hip_bfloat16* kW2t,
    const float* vW2, __hip_bfloat16* vW2t) {
    int b = blockIdx.x;
    // segments: Wqkv 64x32=2048 | kW1 64x64=4096 | vW1 4096 | Wout 32x32=1024
    //           combW 2x32=64 | kW2 2x64=128 | vW2 128    (total 11584)
    if (b < 2048) { transpose_body(Wqkv, Wqkvt, 1024, 2048, b % 64, b / 64); return; }
    b -= 2048;
    if (b < 4096) { transpose_body(kW1, kW1t, 2048, 2048, b % 64, b / 64); return; }
    b -= 4096;
    if (b < 4096) { transpose_body(vW1, vW1t, 2048, 2048, b % 64, b / 64); return; }
    b -= 4096;
    if (b < 1024) { transpose_body(Wout, Woutt, 1024, 1024, b % 32, b / 32); return; }
    b -= 1024;
    if (b < 64) { transpose_body(combW, combWt, 1024, 48, b % 2, b / 2); return; }
    b -= 64;
    if (b < 128) { transpose_body(kW2, kW2t, 2048, 64, b % 2, b / 2); return; }
    b -= 128;
    transpose_body(vW2, vW2t, 2048, 64, b % 2, b / 2);
}

// ---------------- bf16 MFMA GEMM body ----------------
template <int ACT, int OUTBF16>
__device__ __forceinline__ void mfma_gemm_body(const __hip_bfloat16* __restrict__ A,
                                               const __hip_bfloat16* __restrict__ Bt,
                                               const float* __restrict__ bias,
                                               void* __restrict__ Cp,
                                               int M, int N, int K, int bx, int by) {
    __shared__ __align__(16) short As[128 * 32];
    __shared__ __align__(16) short Bs[128 * 32];
    int tid = threadIdx.x;
    int lane = tid & 63, wave = tid >> 6;
    int wm = (wave >> 1) * 64, wn = (wave & 1) * 64;
    int m0 = by * 128, n0 = bx * 128;
    f32x4 acc[4][4];
    for (int r = 0; r < 4; r++)
        for (int c = 0; c < 4; c++)
            acc[r][c] = (f32x4){0.f, 0.f, 0.f, 0.f};

    int r0 = tid >> 2, kc0 = tid & 3;
    int r1 = (tid + 256) >> 2, kc1 = tid & 3;

    for (int k0 = 0; k0 < K; k0 += 32) {
        __syncthreads();
        *(uint4*)&As[r0 * 32 + kc0 * 8] =
            *(const uint4*)(A + (size_t)(m0 + r0) * K + k0 + kc0 * 8);
        *(uint4*)&As[r1 * 32 + kc1 * 8] =
            *(const uint4*)(A + (size_t)(m0 + r1) * K + k0 + kc1 * 8);
        *(uint4*)&Bs[r0 * 32 + kc0 * 8] =
            *(const uint4*)(Bt + (size_t)(n0 + r0) * K + k0 + kc0 * 8);
        *(uint4*)&Bs[r1 * 32 + kc1 * 8] =
            *(const uint4*)(Bt + (size_t)(n0 + r1) * K + k0 + kc1 * 8);
        __syncthreads();
        bf16x8 af[4], bfr[4];
#pragma unroll
        for (int r = 0; r < 4; r++)
            af[r] = *(const bf16x8*)&As[(wm + r * 16 + (lane & 15)) * 32 + (lane >> 4) * 8];
#pragma unroll
        for (int c = 0; c < 4; c++)
            bfr[c] = *(const bf16x8*)&Bs[(wn + c * 16 + (lane & 15)) * 32 + (lane >> 4) * 8];
#pragma unroll
        for (int r = 0; r < 4; r++)
#pragma unroll
            for (int c = 0; c < 4; c++)
                acc[r][c] = __builtin_amdgcn_mfma_f32_16x16x32_bf16(af[r], bfr[c], acc[r][c], 0, 0, 0);
    }
    for (int r = 0; r < 4; r++) {
        int grow = m0 + wm + r * 16 + (lane >> 4) * 4;
        for (int c = 0; c < 4; c++) {
            int gcol = n0 + wn + c * 16 + (lane & 15);
            float bv = bias ? bias[gcol] : 0.f;
#pragma unroll
            for (int v = 0; v < 4; v++) {
                float val = acc[r][c][v] + bv;
                if (ACT == 1) val = fmaxf(val, 0.f);
                if (OUTBF16)
                    ((__hip_bfloat16*)Cp)[(size_t)(grow + v) * N + gcol] = __float2bfloat16(val);
                else
                    ((float*)Cp)[(size_t)(grow + v) * N + gcol] = val;
            }
        }
    }
}

template <int ACT, int OUTBF16>
__global__ __launch_bounds__(256) void mfma_gemm(const __hip_bfloat16* __restrict__ A,
                                                 const __hip_bfloat16* __restrict__ Bt,
                                                 const float* __restrict__ bias,
                                                 void* __restrict__ Cp,
                                                 int M, int N, int K) {
    mfma_gemm_body<ACT, OUTBF16>(A, Bt, bias, Cp, M, N, K, blockIdx.x, blockIdx.y);
}

// paired version: blockIdx.z selects operand set (k vs v MLP layer 1)
__global__ __launch_bounds__(256) void mfma_gemm_pair(const __hip_bfloat16* A0,
                                                      const __hip_bfloat16* A1,
                                                      const __hip_bfloat16* Bt0,
                                                      const __hip_bfloat16* Bt1,
                                                      const float* bias0, const float* bias1,
                                                      __hip_bfloat16* C0, __hip_bfloat16* C1,
                                                      int M, int N, int K) {
    if (blockIdx.z == 0)
        mfma_gemm_body<1, 1>(A0, Bt0, bias0, C0, M, N, K, blockIdx.x, blockIdx.y);
    else
        mfma_gemm_body<1, 1>(A1, Bt1, bias1, C1, M, N, K, blockIdx.x, blockIdx.y);
}

// ---------------- Split-K skinny MFMA GEMM body: C += A @ Bt^T (atomicAdd) ----------
__device__ __forceinline__ void skgemm_body(const __hip_bfloat16* __restrict__ A,
                                            const __hip_bfloat16* __restrict__ Bt,
                                            float* __restrict__ C,
                                            int M, int Nout, int K, int by, int bz, int nz) {
    __shared__ __align__(16) short As[128 * 32];
    __shared__ __align__(16) short Bs[64 * 32];
    int tid = threadIdx.x;
    int lane = tid & 63, wave = tid >> 6;
    int m0 = by * 128;
    int wm = wave * 32;
    int kchunk = K / nz;
    int kbase = bz * kchunk;
    f32x4 acc[2][4];
    for (int r = 0; r < 2; r++)
        for (int c = 0; c < 4; c++) acc[r][c] = (f32x4){0.f, 0.f, 0.f, 0.f};

    int ra = tid >> 2, kc = (tid & 3) * 8;
    for (int k0 = kbase; k0 < kbase + kchunk; k0 += 32) {
        __syncthreads();
        *(uint4*)&As[ra * 32 + kc] = *(const uint4*)(A + (size_t)(m0 + ra) * K + k0 + kc);
        *(uint4*)&As[(ra + 64) * 32 + kc] =
            *(const uint4*)(A + (size_t)(m0 + ra + 64) * K + k0 + kc);
        uint4 bv = (uint4){0u, 0u, 0u, 0u};
        if (ra < Nout) bv = *(const uint4*)(Bt + (size_t)ra * K + k0 + kc);
        *(uint4*)&Bs[ra * 32 + kc] = bv;
        __syncthreads();
        bf16x8 af[2], bfr[4];
#pragma unroll
        for (int r = 0; r < 2; r++)
            af[r] = *(const bf16x8*)&As[(wm + r * 16 + (lane & 15)) * 32 + (lane >> 4) * 8];
#pragma unroll
        for (int c = 0; c < 4; c++)
            bfr[c] = *(const bf16x8*)&Bs[(c * 16 + (lane & 15)) * 32 + (lane >> 4) * 8];
#pragma unroll
        for (int r = 0; r < 2; r++)
#pragma unroll
            for (int c = 0; c < 4; c++)
                acc[r][c] = __builtin_amdgcn_mfma_f32_16x16x32_bf16(af[r], bfr[c], acc[r][c], 0, 0, 0);
    }
    for (int r = 0; r < 2; r++) {
        int grow = m0 + wm + r * 16 + (lane >> 4) * 4;
        for (int c = 0; c < 4; c++) {
            int gcol = c * 16 + (lane & 15);
            if (gcol >= Nout) continue;
#pragma unroll
            for (int v = 0; v < 4; v++)
                atomicAdd(&C[(size_t)(grow + v) * Nout + gcol], acc[r][c][v]);
        }
    }
}

__global__ __launch_bounds__(256) void skgemm_kernel(const __hip_bfloat16* __restrict__ A,
                                                     const __hip_bfloat16* __restrict__ Bt,
                                                     float* __restrict__ C,
                                                     int M, int Nout, int K) {
    skgemm_body(A, Bt, C, M, Nout, K, blockIdx.y, blockIdx.z, gridDim.z);
}

__global__ __launch_bounds__(256) void skgemm_pair(const __hip_bfloat16* A0,
                                                   const __hip_bfloat16* A1,
                                                   const __hip_bfloat16* Bt0,
                                                   const __hip_bfloat16* Bt1,
                                                   float* C0, float* C1,
                                                   int M, int Nout, int K) {
    if (blockIdx.x == 0)
        skgemm_body(A0, Bt0, C0, M, Nout, K, blockIdx.y, blockIdx.z, gridDim.z);
    else
        skgemm_body(A1, Bt1, C1, M, Nout, K, blockIdx.y, blockIdx.z, gridDim.z);
}

// ---------------- init with broadcast bias (two outputs) ----------------
__global__ __launch_bounds__(256) void initbias2_kernel(float* __restrict__ C0,
                                                        const float* __restrict__ b0,
                                                        float* __restrict__ C1,
                                                        const float* __restrict__ b1,
                                                        int M, int Nout) {
    int idx = blockIdx.x * 256 + threadIdx.x;
    int tot = M * Nout;
    if (idx < tot) C0[idx] = b0[idx % Nout];
    else if (idx < 2 * tot) { idx -= tot; C1[idx] = b1[idx % Nout]; }
}

__global__ __launch_bounds__(256) void initbias_kernel(float* __restrict__ C,
                                                       const float* __restrict__ bias,
                                                       int M, int Nout) {
    int idx = blockIdx.x * 256 + threadIdx.x;
    if (idx < M * Nout) C[idx] = bias[idx % Nout];
}

// ---------------- Build compressed windows (bf16 MLP input) ----------------
__global__ __launch_bounds__(256) void buildwin_kernel(const float* __restrict__ qkv,
                                                       const float* __restrict__ k_pos,
                                                       const float* __restrict__ v_pos,
                                                       __hip_bfloat16* __restrict__ kwflat,
                                                       __hip_bfloat16* __restrict__ vwflat) {
    size_t total = (size_t)(KVH * NCB) * HIDN;
    for (size_t e = (size_t)blockIdx.x * 256 + threadIdx.x; e < total;
         e += (size_t)gridDim.x * 256) {
        int r = (int)(e >> 11);
        int c = (int)(e & 2047);
        int j = c >> 6, d = c & 63;
        int h = r >> 7, i = r & 127;
        int p = i * STRIDE + j - (CBS - STRIDE);
        float kb = k_pos[((size_t)h * CBS + j) * HD + d];
        float vb = v_pos[((size_t)h * CBS + j) * HD + d];
        float kv = 0.f, vv = 0.f;
        if (p >= 0) {
            kv = qkv[(size_t)p * 2048 + 1024 + h * HD + d];
            vv = qkv[(size_t)p * 2048 + 1536 + h * HD + d];
        }
        kwflat[e] = __float2bfloat16(kv + kb);
        vwflat[e] = __float2bfloat16(vv + vb);
    }
}

// ---------------- RoPE + transpose ----------------
__global__ __launch_bounds__(256) void rope_kernel(const float* __restrict__ qkv,
                                                   float* __restrict__ rq,
                                                   float* __restrict__ rk,
                                                   float* __restrict__ vt) {
    int n = blockIdx.x;
    int t = threadIdx.x;
    for (int idx = t; idx < NH * 32; idx += 256) {
        int h = idx >> 5, f = idx & 31;
        float inv = exp2f((float)f * -0.41524101186092f);
        float ang = (float)n * inv;
        float cc = cosf(ang), ssn = sinf(ang);
        float a = qkv[(size_t)n * 2048 + h * HD + 2 * f];
        float b = qkv[(size_t)n * 2048 + h * HD + 2 * f + 1];
        float* o = rq + ((size_t)h * NTOK + n) * HD + 2 * f;
        o[0] = a * cc - b * ssn;
        o[1] = b * cc + a * ssn;
    }
    for (int idx = t; idx < KVH * 32; idx += 256) {
        int h = idx >> 5, f = idx & 31;
        float inv = exp2f((float)f * -0.41524101186092f);
        float ang = (float)n * inv;
        float cc = cosf(ang), ssn = sinf(ang);
        float a = qkv[(size_t)n * 2048 + 1024 + h * HD + 2 * f];
        float b = qkv[(size_t)n * 2048 + 1024 + h * HD + 2 * f + 1];
        float* o = rk + ((size_t)h * NTOK + n) * HD + 2 * f;
        o[0] = a * cc - b * ssn;
        o[1] = b * cc + a * ssn;
    }
    for (int idx = t; idx < KVH * HD; idx += 256) {
        int h = idx >> 6, d = idx & 63;
        vt[((size_t)h * NTOK + n) * HD + d] = qkv[(size_t)n * 2048 + 1536 + h * HD + d];
    }
}

// ---------------- Compressed attention + importance (tiled) ----------------
__global__ __launch_bounds__(256) void cattn2_kernel(const float* __restrict__ qkv,
                                                     const float* __restrict__ ckraw,
                                                     const float* __restrict__ cvraw,
                                                     const float* __restrict__ memkv,
                                                     float* __restrict__ cout,
                                                     float* __restrict__ imp) {
    int h = blockIdx.x >> 6;
    int i0 = (blockIdx.x & 63) * 32;
    int t = threadIdx.x;
    __shared__ float qs[64][68];
    __shared__ float sc[64][132];
    __shared__ float scratch[32 * 68];
    __shared__ float memk[64], memv[64];
    __shared__ float impm[32], impd[32];

    for (int idx = t; idx < 4096; idx += 256) {
        int row = idx >> 6, d = idx & 63;
        int g = row >> 5, qi = row & 31;
        qs[row][d] = qkv[(size_t)(i0 + qi) * 2048 + (h * 2 + g) * 64 + d];
    }
    if (t < 64) { memk[t] = memkv[h * 64 + t]; memv[t] = memkv[(8 + h) * 64 + t]; }
    __syncthreads();
    if (t < 64) {
        float s = 0.f;
        for (int d = 0; d < 64; d++) s += qs[t][d] * memk[d];
        sc[t][0] = s * SCALE;
    }
    int rg = t >> 3, kg = t & 7;
    for (int c = 0; c < 4; c++) {
        __syncthreads();
        for (int idx = t; idx < 2048; idx += 256) {
            int jj = idx >> 6, d = idx & 63;
            scratch[jj * 68 + d] = ckraw[((size_t)h * 128 + c * 32 + jj) * 64 + d];
        }
        __syncthreads();
        float a0[4] = {}, a1[4] = {};
        for (int d = 0; d < 64; d += 4) {
            float4 q0 = *(const float4*)&qs[rg * 2][d];
            float4 q1 = *(const float4*)&qs[rg * 2 + 1][d];
#pragma unroll
            for (int kk = 0; kk < 4; kk++) {
                float4 kv = *(const float4*)&scratch[(kg + kk * 8) * 68 + d];
                a0[kk] += q0.x * kv.x + q0.y * kv.y + q0.z * kv.z + q0.w * kv.w;
                a1[kk] += q1.x * kv.x + q1.y * kv.y + q1.z * kv.z + q1.w * kv.w;
            }
        }
#pragma unroll
        for (int kk = 0; kk < 4; kk++) {
            sc[rg * 2][1 + c * 32 + kg + kk * 8] = a0[kk] * SCALE;
            sc[rg * 2 + 1][1 + c * 32 + kg + kk * 8] = a1[kk] * SCALE;
        }
    }
    __syncthreads();
    for (int idx = t; idx < 2048; idx += 256) {
        int qi = idx >> 6, fb = idx & 63;
        float v = 0.25f * (sc[qi][1 + 2 * fb] + sc[qi][2 + 2 * fb] +
                           sc[32 + qi][1 + 2 * fb] + sc[32 + qi][2 + 2 * fb]);
        if (fb == ((i0 + qi) >> 5)) v = NEGF;
        scratch[qi * 66 + fb] = v;
    }
    __syncthreads();
    if (t < 32) {
        float m = -1000.f;
        for (int j = 0; j < 64; j++) m = fmaxf(m, scratch[t * 66 + j]);
        float den = expf(-1000.f - m);
        for (int j = 0; j < 64; j++) den += expf(scratch[t * 66 + j] - m);
        impm[t] = m; impd[t] = 1.f / den;
    } else if (t >= 64 && t < 128) {
        int r = t - 64;
        float m = NEGF;
        for (int j = 0; j < 129; j++) m = fmaxf(m, sc[r][j]);
        float den = 0.f;
        for (int j = 0; j < 129; j++) { float e = expf(sc[r][j] - m); sc[r][j] = e; den += e; }
        float inv = 1.f / den;
        for (int j = 0; j < 129; j++) sc[r][j] *= inv;
    }
    __syncthreads();
    for (int idx = t; idx < 2048; idx += 256) {
        int qi = idx >> 6, fb = idx & 63;
        imp[((size_t)h * NTOK + i0 + qi) * 64 + fb] =
            expf(scratch[qi * 66 + fb] - impm[qi]) * impd[qi];
    }
    int dg = t & 7;
    float o0[8], o1[8];
    {
        float p0 = sc[rg * 2][0], p1 = sc[rg * 2 + 1][0];
#pragma unroll
        for (int dd = 0; dd < 8; dd++) {
            float v = memv[dg + dd * 8];
            o0[dd] = p0 * v;
            o1[dd] = p1 * v;
        }
    }
    for (int c = 0; c < 4; c++) {
        __syncthreads();
        for (int idx = t; idx < 2048; idx += 256) {
            int jj = idx >> 6, d = idx & 63;
            scratch[jj * 68 + d] = cvraw[((size_t)h * 128 + c * 32 + jj) * 64 + d];
        }
        __syncthreads();
        for (int jj = 0; jj < 32; jj++) {
            float p0 = sc[rg * 2][1 + c * 32 + jj];
            float p1 = sc[rg * 2 + 1][1 + c * 32 + jj];
#pragma unroll
            for (int dd = 0; dd < 8; dd++) {
                float v = scratch[jj * 68 + dg + dd * 8];
                o0[dd] += p0 * v;
                o1[dd] += p1 * v;
            }
        }
    }
    {
        int row = rg * 2;
        int g = row >> 5, qi = row & 31;
        int g2 = (row + 1) >> 5, qi2 = (row + 1) & 31;
#pragma unroll
        for (int dd = 0; dd < 8; dd++) {
            cout[(((size_t)(h * 2 + g)) * NTOK + i0 + qi) * 64 + dd * 8 + dg] = o0[dd];
            cout[(((size_t)(h * 2 + g2)) * NTOK + i0 + qi2) * 64 + dd * 8 + dg] = o1[dd];
        }
    }
}

// ---------------- Top-k selection ----------------
__global__ __launch_bounds__(256) void topk_kernel(const float* __restrict__ imp,
                                                   int* __restrict__ selidx,
                                                   int* __restrict__ selmask) {
    int idx = blockIdx.x * 256 + threadIdx.x;
    if (idx >= KVH * NTOK) return;
    const float* ip = imp + (size_t)idx * NFB;
    float v[NFB];
    for (int j = 0; j < NFB; j++) v[j] = ip[j];
    unsigned long long taken = 0ull;
    int mk = 0;
    int i = idx & 2047;
    for (int p = 0; p < NSEL; p++) {
        float bv = NEGF;
        int bi = 0;
        for (int j = 0; j < NFB; j++) {
            if (!((taken >> j) & 1ull) && v[j] > bv) { bv = v[j]; bi = j; }
        }
        taken |= 1ull << bi;
        selidx[(size_t)idx * 5 + p] = bi;
        if (bv > 1e-10f) mk |= 1 << p;
    }
    selidx[(size_t)idx * 5 + 4] = i >> 5;
    selmask[idx] = mk;
}

// ---------------- Fine attention: one wave per (h, i) ----------------
__global__ __launch_bounds__(256) void fattn2_kernel(const float* __restrict__ rq,
                                                     const float* __restrict__ rk,
                                                     const float* __restrict__ vt,
                                                     const int* __restrict__ selidx,
                                                     const int* __restrict__ selmask,
                                                     float* __restrict__ fout) {
    int ws = threadIdx.x >> 6, lane = threadIdx.x & 63;
    int wid = blockIdx.x * 4 + ws;
    int h = wid >> 11, i = wid & 2047;
    __shared__ float sp[4][2][160];
    __shared__ int sel[4][5];
    __shared__ int smk[4];
    float* p0 = sp[ws][0];
    float* p1 = sp[ws][1];
    if (lane < 5) sel[ws][lane] = selidx[((size_t)h * NTOK + i) * 5 + lane];
    if (lane == 5) smk[ws] = selmask[h * NTOK + i];

    int kk = lane & 15, c = lane >> 4;
    const float* q0p = rq + ((size_t)(h * 2 + 0) * NTOK + i) * 64 + c * 16;
    const float* q1p = rq + ((size_t)(h * 2 + 1) * NTOK + i) * 64 + c * 16;
    float4 q0[4], q1[4];
#pragma unroll
    for (int u = 0; u < 4; u++) {
        q0[u] = *(const float4*)(q0p + u * 4);
        q1[u] = *(const float4*)(q1p + u * 4);
    }
    __syncthreads();  // sel/smk visible
    int mk = smk[ws];
    int iq = i & 31;
#pragma unroll
    for (int kt = 0; kt < 10; kt++) {
        int slot = kt >> 1;
        int blk = sel[ws][slot];
        int key = kt * 16 + kk;
        int jj = key & 31;
        int kpos = blk * 32 + jj;
        bool valid = (slot < 4) ? (((mk >> slot) & 1) != 0) : (jj <= iq);
        const float* kr = rk + ((size_t)h * NTOK + kpos) * 64 + c * 16;
        float s0 = 0.f, s1 = 0.f;
#pragma unroll
        for (int u = 0; u < 4; u++) {
            float4 kv = *(const float4*)(kr + u * 4);
            s0 += q0[u].x * kv.x + q0[u].y * kv.y + q0[u].z * kv.z + q0[u].w * kv.w;
            s1 += q1[u].x * kv.x + q1[u].y * kv.y + q1[u].z * kv.z + q1[u].w * kv.w;
        }
        s0 += __shfl_xor(s0, 16); s0 += __shfl_xor(s0, 32);
        s1 += __shfl_xor(s1, 16); s1 += __shfl_xor(s1, 32);
        if (c == 0) {
            p0[key] = valid ? s0 * SCALE : NEG10F;
            p1[key] = valid ? s1 * SCALE : NEG10F;
        }
    }
    __syncthreads();
    // softmax over 160
    {
        float a0 = p0[lane], b0 = p0[lane + 64];
        float c0 = (lane < 32) ? p0[lane + 128] : NEG10F;
        float a1 = p1[lane], b1 = p1[lane + 64];
        float c1 = (lane < 32) ? p1[lane + 128] : NEG10F;
        float m0 = fmaxf(fmaxf(a0, b0), c0);
        float m1 = fmaxf(fmaxf(a1, b1), c1);
#pragma unroll
        for (int o = 1; o < 64; o <<= 1) {
            m0 = fmaxf(m0, __shfl_xor(m0, o));
            m1 = fmaxf(m1, __shfl_xor(m1, o));
        }
        float ea0 = __expf(a0 - m0), eb0 = __expf(b0 - m0), ec0 = (lane < 32) ? __expf(c0 - m0) : 0.f;
        float ea1 = __expf(a1 - m1), eb1 = __expf(b1 - m1), ec1 = (lane < 32) ? __expf(c1 - m1) : 0.f;
        float d0 = ea0 + eb0 + ec0;
        float d1 = ea1 + eb1 + ec1;
#pragma unroll
        for (int o = 1; o < 64; o <<= 1) {
            d0 += __shfl_xor(d0, o);
            d1 += __shfl_xor(d1, o);
        }
        float inv0 = 1.f / d0, inv1 = 1.f / d1;
        p0[lane] = ea0 * inv0; p0[lane + 64] = eb0 * inv0;
        p1[lane] = ea1 * inv1; p1[lane + 64] = eb1 * inv1;
        if (lane < 32) { p0[lane + 128] = ec0 * inv0; p1[lane + 128] = ec1 * inv1; }
    }
    __syncthreads();
    // PV: lane = (kk4 in 0..3 keys, c4 in 0..15 dim-chunks of 4 floats)
    int kk4 = lane >> 4, c4 = lane & 15;
    int selreg[5];
#pragma unroll
    for (int s = 0; s < 5; s++) selreg[s] = sel[ws][s];
    float4 o0 = (float4){0.f, 0.f, 0.f, 0.f};
    float4 o1 = (float4){0.f, 0.f, 0.f, 0.f};
#pragma unroll
    for (int slot = 0; slot < 5; slot++) {
        const float* vbase = vt + ((size_t)h * NTOK + selreg[slot] * 32) * 64 + c4 * 4;
#pragma unroll
        for (int j8 = 0; j8 < 8; j8++) {
            int j = j8 * 4 + kk4;
            float4 v = *(const float4*)(vbase + j * 64);
            float pa = p0[slot * 32 + j], pb = p1[slot * 32 + j];
            o0.x = fmaf(pa, v.x, o0.x); o0.y = fmaf(pa, v.y, o0.y);
            o0.z = fmaf(pa, v.z, o0.z); o0.w = fmaf(pa, v.w, o0.w);
            o1.x = fmaf(pb, v.x, o1.x); o1.y = fmaf(pb, v.y, o1.y);
            o1.z = fmaf(pb, v.z, o1.z); o1.w = fmaf(pb, v.w, o1.w);
        }
    }
#pragma unroll
    for (int o = 16; o <= 32; o <<= 1) {
        o0.x += __shfl_xor(o0.x, o); o0.y += __shfl_xor(o0.y, o);
        o0.z += __shfl_xor(o0.z, o); o0.w += __shfl_xor(o0.w, o);
        o1.x += __shfl_xor(o1.x, o); o1.y += __shfl_xor(o1.y, o);
        o1.z += __shfl_xor(o1.z, o); o1.w += __shfl_xor(o1.w, o);
    }
    if (kk4 == 0) {
        *(float4*)(fout + ((size_t)(h * 2 + 0) * NTOK + i) * 64 + c4 * 4) = o0;
        *(float4*)(fout + ((size_t)(h * 2 + 1) * NTOK + i) * 64 + c4 * 4) = o1;
    }
}

// ---------------- Sliding-window attention: one wave per (h, i) ----------------
__global__ __launch_bounds__(256) void sattn2_kernel(const float* __restrict__ rq,
                                                     const float* __restrict__ rk,
                                                     const float* __restrict__ vt,
                                                     float* __restrict__ sout) {
    int ws = threadIdx.x >> 6, lane = threadIdx.x & 63;
    int wid = blockIdx.x * 4 + ws;
    int h = wid >> 11, i = wid & 2047;
    __shared__ float sp[4][2][64];
    float* p0 = sp[ws][0];
    float* p1 = sp[ws][1];

    int kk = lane & 15, c = lane >> 4;
    const float* q0p = rq + ((size_t)(h * 2 + 0) * NTOK + i) * 64 + c * 16;
    const float* q1p = rq + ((size_t)(h * 2 + 1) * NTOK + i) * 64 + c * 16;
    float4 q0[4], q1[4];
#pragma unroll
    for (int u = 0; u < 4; u++) {
        q0[u] = *(const float4*)(q0p + u * 4);
        q1[u] = *(const float4*)(q1p + u * 4);
    }
#pragma unroll
    for (int kt = 0; kt < 4; kt++) {
        int key = kt * 16 + kk;
        int kpos = i - 63 + key;
        int kp = kpos < 0 ? 0 : kpos;
        const float* kr = rk + ((size_t)h * NTOK + kp) * 64 + c * 16;
        float s0 = 0.f, s1 = 0.f;
#pragma unroll
        for (int u = 0; u < 4; u++) {
            float4 kv = *(const float4*)(kr + u * 4);
            s0 += q0[u].x * kv.x + q0[u].y * kv.y + q0[u].z * kv.z + q0[u].w * kv.w;
            s1 += q1[u].x * kv.x + q1[u].y * kv.y + q1[u].z * kv.z + q1[u].w * kv.w;
        }
        s0 += __shfl_xor(s0, 16); s0 += __shfl_xor(s0, 32);
        s1 += __shfl_xor(s1, 16); s1 += __shfl_xor(s1, 32);
        if (c == 0) {
            p0[key] = (kpos >= 0) ? s0 * SCALE : NEG10F;
            p1[key] = (kpos >= 0) ? s1 * SCALE : NEG10F;
        }
    }
    __syncthreads();
    {
        float a0 = p0[lane], a1 = p1[lane];
        float m0 = a0, m1 = a1;
#pragma unroll
        for (int o = 1; o < 64; o <<= 1) {
            m0 = fmaxf(m0, __shfl_xor(m0, o));
            m1 = fmaxf(m1, __shfl_xor(m1, o));
        }
        float e0 = __expf(a0 - m0), e1 = __expf(a1 - m1);
        float d0 = e0, d1 = e1;
#pragma unroll
        for (int o = 1; o < 64; o <<= 1) {
            d0 += __shfl_xor(d0, o);
            d1 += __shfl_xor(d1, o);
        }
        p0[lane] = e0 / d0;
        p1[lane] = e1 / d1;
    }
    __syncthreads();
    // PV: lane = (kk4, c4), float4 V loads over 4 contiguous keys
    int kk4 = lane >> 4, c4 = lane & 15;
    int base = i - 63;
    const float* vbase = vt + (size_t)h * NTOK * 64 + c4 * 4;
    float4 o0 = (float4){0.f, 0.f, 0.f, 0.f};
    float4 o1 = (float4){0.f, 0.f, 0.f, 0.f};
#pragma unroll
    for (int j4 = 0; j4 < 16; j4++) {
        int j = j4 * 4 + kk4;
        int kpos = base + j;
        int kp = kpos < 0 ? 0 : kpos;  // p==0 for invalid, product is 0
        float4 v = *(const float4*)(vbase + (size_t)kp * 64);
        float pa = p0[j], pb = p1[j];
        o0.x = fmaf(pa, v.x, o0.x); o0.y = fmaf(pa, v.y, o0.y);
        o0.z = fmaf(pa, v.z, o0.z); o0.w = fmaf(pa, v.w, o0.w);
        o1.x = fmaf(pb, v.x, o1.x); o1.y = fmaf(pb, v.y, o1.y);
        o1.z = fmaf(pb, v.z, o1.z); o1.w = fmaf(pb, v.w, o1.w);
    }
#pragma unroll
    for (int o = 16; o <= 32; o <<= 1) {
        o0.x += __shfl_xor(o0.x, o); o0.y += __shfl_xor(o0.y, o);
        o0.z += __shfl_xor(o0.z, o); o0.w += __shfl_xor(o0.w, o);
        o1.x += __shfl_xor(o1.x, o); o1.y += __shfl_xor(o1.y, o);
        o1.z += __shfl_xor(o1.z, o); o1.w += __shfl_xor(o1.w, o);
    }
    if (kk4 == 0) {
        *(float4*)(sout + ((size_t)(h * 2 + 0) * NTOK + i) * 64 + c4 * 4) = o0;
        *(float4*)(sout + ((size_t)(h * 2 + 1) * NTOK + i) * 64 + c4 * 4) = o1;
    }
}

// ---------------- Gated combine (sigmoid applied here; writes bf16) ----------------
__global__ __launch_bounds__(256) void combine_kernel(const float* __restrict__ gateslin,
                                                      const float* __restrict__ cout,
                                                      const float* __restrict__ fout,
                                                      const float* __restrict__ sout,
                                                      __hip_bfloat16* __restrict__ att) {
    int n = blockIdx.x;
    for (int c = threadIdx.x; c < NH * HD; c += 256) {
        int hd = c >> 6, d = c & 63;
        float g0 = 1.f / (1.f + expf(-gateslin[(size_t)n * (NH * 3) + hd * 3 + 0]));
        float g1 = 1.f / (1.f + expf(-gateslin[(size_t)n * (NH * 3) + hd * 3 + 1]));
        float g2 = 1.f / (1.f + expf(-gateslin[(size_t)n * (NH * 3) + hd * 3 + 2]));
        size_t o = ((size_t)hd * NTOK + n) * HD + d;
        att[(size_t)n * (NH * HD) + c] =
            __float2bfloat16(g0 * cout[o] + g1 * fout[o] + g2 * sout[o]);
    }
}

extern "C" void kernel_launch(void* const* d_in, const int* in_sizes, int n_in,
                              void* d_out, int out_size, void* d_ws, size_t ws_size,
                              hipStream_t stream) {
    const float* inp    = (const float*)d_in[0];
    const float* norm_g = (const float*)d_in[1];
    const float* Wqkv   = (const float*)d_in[2];
    const float* mem_kv = (const float*)d_in[3];
    const float* k_pos  = (const float*)d_in[4];
    const float* v_pos  = (const float*)d_in[5];
    const float* kW1    = (const float*)d_in[6];
    const float* kb1    = (const float*)d_in[7];
    const float* kW2    = (const float*)d_in[8];
    const float* kb2    = (const float*)d_in[9];
    const float* vW1    = (const float*)d_in[10];
    const float* vb1    = (const float*)d_in[11];
    const float* vW2    = (const float*)d_in[12];
    const float* vb2    = (const float*)d_in[13];
    const float* combW  = (const float*)d_in[14];
    const float* combB  = (const float*)d_in[15];
    const float* Wout   = (const float*)d_in[16];
    float* out = (float*)d_out;

    char* base = (char*)d_ws;
    size_t off = 0;
    auto alloc = [&](size_t bytes) {
        void* p = base + off;
        off += (bytes + 255) & ~(size_t)255;
        return p;
    };
    float* x            = (float*)alloc((size_t)NTOK * DIM * 4);
    __hip_bfloat16* xb  = (__hip_bfloat16*)alloc((size_t)NTOK * DIM * 2);
    float* qkv          = (float*)alloc((size_t)NTOK * 2048 * 4);
    __hip_bfloat16* Wqkvt = (__hip_bfloat16*)alloc((size_t)2048 * 1024 * 2);
    __hip_bfloat16* kW1t  = (__hip_bfloat16*)alloc((size_t)2048 * 2048 * 2);
    __hip_bfloat16* vW1t  = (__hip_bfloat16*)alloc((size_t)2048 * 2048 * 2);
    __hip_bfloat16* Woutt = (__hip_bfloat16*)alloc((size_t)1024 * 1024 * 2);
    __hip_bfloat16* combWt = (__hip_bfloat16*)alloc((size_t)48 * 1024 * 2);
    __hip_bfloat16* kW2t  = (__hip_bfloat16*)alloc((size_t)64 * 2048 * 2);
    __hip_bfloat16* vW2t  = (__hip_bfloat16*)alloc((size_t)64 * 2048 * 2);
    __hip_bfloat16* kwflat = (__hip_bfloat16*)alloc((size_t)KVH * NCB * HIDN * 2);
    __hip_bfloat16* vwflat = (__hip_bfloat16*)alloc((size_t)KVH * NCB * HIDN * 2);
    __hip_bfloat16* hidkb = (__hip_bfloat16*)alloc((size_t)KVH * NCB * HIDN * 2);
    __hip_bfloat16* hidvb = (__hip_bfloat16*)alloc((size_t)KVH * NCB * HIDN * 2);
    float* ckraw        = (float*)alloc((size_t)KVH * NCB * HD * 4);
    float* cvraw        = (float*)alloc((size_t)KVH * NCB * HD * 4);
    float* rq           = (float*)alloc((size_t)NH * NTOK * HD * 4);
    float* rk           = (float*)alloc((size_t)KVH * NTOK * HD * 4);
    float* vt           = (float*)alloc((size_t)KVH * NTOK * HD * 4);
    float* coutb        = (float*)alloc((size_t)NH * NTOK * HD * 4);
    float* foutb        = (float*)alloc((size_t)NH * NTOK * HD * 4);
    float* soutb        = (float*)alloc((size_t)NH * NTOK * HD * 4);
    float* impb         = (float*)alloc((size_t)KVH * NTOK * NFB * 4);
    float* gatesb       = (float*)alloc((size_t)NTOK * NH * 3 * 4);
    __hip_bfloat16* attb = (__hip_bfloat16*)alloc((size_t)NTOK * DIM * 2);
    int* selidx         = (int*)alloc((size_t)KVH * NTOK * 5 * 4);
    int* selmask        = (int*)alloc((size_t)KVH * NTOK * 4);
    (void)ws_size; (void)in_sizes; (void)n_in; (void)out_size;

    // 1. RMSNorm (fp32 + bf16)
    rmsnorm_kernel<<<NTOK, 256, 0, stream>>>(inp, norm_g, x, xb);
    // 2. merged transpose-cast of all weights to bf16 NxK
    transpose_all_kernel<<<11584, 256, 0, stream>>>(Wqkv, Wqkvt, kW1, kW1t, vW1, vW1t,
                                                    Wout, Woutt, combW, combWt,
                                                    kW2, kW2t, vW2, vW2t);
    // 3. qkv = x @ Wqkv  (MFMA)
    mfma_gemm<0, 0><<<dim3(16, 16), 256, 0, stream>>>(xb, Wqkvt, nullptr, qkv, 2048, 2048, 1024);
    // 4. gates linear = x @ combW + combB  (split-K MFMA, sigmoid in combine)
    initbias_kernel<<<(NTOK * 48 + 255) / 256, 256, 0, stream>>>(gatesb, combB, NTOK, 48);
    skgemm_kernel<<<dim3(1, 16, 4), 256, 0, stream>>>(xb, combWt, gatesb, 2048, 48, 1024);
    // 5. build compressed windows (bf16)
    buildwin_kernel<<<4096, 256, 0, stream>>>(qkv, k_pos, v_pos, kwflat, vwflat);
    // 6. compressed k/v MLP layer 1 (batched: 256 blocks)
    mfma_gemm_pair<<<dim3(16, 8, 2), 256, 0, stream>>>(kwflat, vwflat, kW1t, vW1t,
                                                       kb1, vb1, hidkb, hidvb,
                                                       1024, 2048, 2048);
    // 7. compressed k/v MLP layer 2 (batched split-K)
    initbias2_kernel<<<(2 * 1024 * 64 + 255) / 256, 256, 0, stream>>>(ckraw, kb2, cvraw, vb2, 1024, 64);
    skgemm_pair<<<dim3(2, 8, 8), 256, 0, stream>>>(hidkb, hidvb, kW2t, vW2t,
                                                   ckraw, cvraw, 1024, 64, 2048);
    // 8. RoPE + transposes
    rope_kernel<<<NTOK, 256, 0, stream>>>(qkv, rq, rk, vt);
    // 9. compressed attention + importance (tiled)
    cattn2_kernel<<<KVH * (NTOK / 32), 256, 0, stream>>>(qkv, ckraw, cvraw, mem_kv, coutb, impb);
    // 10. top-k block selection
    topk_kernel<<<(KVH * NTOK) / 256, 256, 0, stream>>>(impb, selidx, selmask);
    // 11. fine attention (wave per query)
    fattn2_kernel<<<KVH * NTOK / 4, 256, 0, stream>>>(rq, rk, vt, selidx, selmask, foutb);
    // 12. sliding-window attention (wave per query)
    sattn2_kernel<<<KVH * NTOK / 4, 256, 0, stream>>>(rq, rk, vt, soutb);
    // 13. gated combine (sigmoid here, bf16 out)
    combine_kernel<<<NTOK, 256, 0, stream>>>(gatesb, coutb, foutb, soutb, attb);
    // 14. out projection (MFMA)
    mfma_gemm<0, 0><<<dim3(8, 16), 256, 0, stream>>>(attb, Woutt, nullptr, out, 2048, 1024, 1024);
}

// Round 6
// 423.810 us; speedup vs baseline: 7.2465x; 1.1363x over previous
//
#include <hip/hip_runtime.h>
#include <hip/hip_bf16.h>

// Problem constants
#define NTOK 2048
#define DIM 1024
#define NH 16
#define KVH 8
#define GQ 2
#define HD 64
#define WS 64
#define CBS 32
#define STRIDE 16
#define SEL_BLK 32
#define NSEL 4
#define NMEM 1
#define NCB 128          // N/STRIDE
#define NFB 64           // N/SEL_BLK
#define HIDN 2048        // CBS*D
#define SCALE 0.125f
#define NEGF (-3.4028234663852886e38f)
#define NEG10F (-3.4028234663852886e37f)

typedef __attribute__((ext_vector_type(8))) short bf16x8;
typedef __attribute__((ext_vector_type(4))) float f32x4;

__device__ __forceinline__ float bflo(unsigned u) { return __uint_as_float(u << 16); }
__device__ __forceinline__ float bfhi(unsigned u) { return __uint_as_float(u & 0xffff0000u); }
__device__ __forceinline__ void dot8(const float4& qa, const float4& qb, uint4 a, float& s) {
    s += qa.x * bflo(a.x) + qa.y * bfhi(a.x) + qa.z * bflo(a.y) + qa.w * bfhi(a.y) +
         qb.x * bflo(a.z) + qb.y * bfhi(a.z) + qb.z * bflo(a.w) + qb.w * bfhi(a.w);
}

// ---------------- RMSNorm (writes fp32 x and bf16 xb) ----------------
__global__ __launch_bounds__(256) void rmsnorm_kernel(const float* __restrict__ inp,
                                                      const float* __restrict__ g,
                                                      float* __restrict__ x,
                                                      __hip_bfloat16* __restrict__ xb) {
    int n = blockIdx.x;
    const float* row = inp + (size_t)n * DIM;
    float ss = 0.f;
    for (int c = threadIdx.x; c < DIM; c += 256) { float v = row[c]; ss += v * v; }
    __shared__ float red[4];
    for (int o = 32; o; o >>= 1) ss += __shfl_down(ss, o, 64);
    if ((threadIdx.x & 63) == 0) red[threadIdx.x >> 6] = ss;
    __syncthreads();
    if (threadIdx.x == 0) red[0] = red[0] + red[1] + red[2] + red[3];
    __syncthreads();
    float rs = 1.0f / sqrtf(red[0] / (float)DIM + 1.1920928955078125e-07f);
    float* xr = x + (size_t)n * DIM;
    __hip_bfloat16* xbr = xb + (size_t)n * DIM;
    for (int c = threadIdx.x; c < DIM; c += 256) {
        float v = row[c] * rs * g[c];
        xr[c] = v;
        xbr[c] = __float2bfloat16(v);
    }
}

// ---------------- Merged transpose+cast of all 7 weights ----------------
__device__ __forceinline__ void transpose_body(const float* __restrict__ B,
                                               __hip_bfloat16* __restrict__ Bt,
                                               int K, int N, int bx, int by) {
    __shared__ float tile[32][33];
    int n0 = bx * 32, k0 = by * 32;
    int x = threadIdx.x & 31, y = threadIdx.x >> 5;
    for (int i = 0; i < 4; i++) {
        int k = k0 + y + 8 * i, n = n0 + x;
        tile[y + 8 * i][x] = (k < K && n < N) ? B[(size_t)k * N + n] : 0.f;
    }
    __syncthreads();
    for (int i = 0; i < 4; i++) {
        int n = n0 + y + 8 * i, k = k0 + x;
        if (n < N && k < K) Bt[(size_t)n * K + k] = __float2bfloat16(tile[x][y + 8 * i]);
    }
}

__global__ __launch_bounds__(256) void transpose_all_kernel(
    const float* Wqkv, __hip_bfloat16* Wqkvt,
    const float* kW1, __hip_bfloat16* kW1t,
    const float* vW1, __hip_bfloat16* vW1t,
    const float* Wout, __hip_bfloat16* Woutt,
    const float* combW, __hip_bfloat16* combWt,
    const float* kW2, __hip_bfloat16* kW2t,
    const float* vW2, __hip_bfloat16* vW2t) {
    int b = blockIdx.x;
    if (b < 2048) { transpose_body(Wqkv, Wqkvt, 1024, 2048, b % 64, b / 64); return; }
    b -= 2048;
    if (b < 4096) { transpose_body(kW1, kW1t, 2048, 2048, b % 64, b / 64); return; }
    b -= 4096;
    if (b < 4096) { transpose_body(vW1, vW1t, 2048, 2048, b % 64, b / 64); return; }
    b -= 4096;
    if (b < 1024) { transpose_body(Wout, Woutt, 1024, 1024, b % 32, b / 32); return; }
    b -= 1024;
    if (b < 64) { transpose_body(combW, combWt, 1024, 48, b % 2, b / 2); return; }
    b -= 64;
    if (b < 128) { transpose_body(kW2, kW2t, 2048, 64, b % 2, b / 2); return; }
    b -= 128;
    transpose_body(vW2, vW2t, 2048, 64, b % 2, b / 2);
}

// ---------------- bf16 MFMA GEMM body ----------------
template <int ACT, int OUTBF16>
__device__ __forceinline__ void mfma_gemm_body(const __hip_bfloat16* __restrict__ A,
                                               const __hip_bfloat16* __restrict__ Bt,
                                               const float* __restrict__ bias,
                                               void* __restrict__ Cp,
                                               int M, int N, int K, int bx, int by) {
    __shared__ __align__(16) short As[128 * 32];
    __shared__ __align__(16) short Bs[128 * 32];
    int tid = threadIdx.x;
    int lane = tid & 63, wave = tid >> 6;
    int wm = (wave >> 1) * 64, wn = (wave & 1) * 64;
    int m0 = by * 128, n0 = bx * 128;
    f32x4 acc[4][4];
    for (int r = 0; r < 4; r++)
        for (int c = 0; c < 4; c++)
            acc[r][c] = (f32x4){0.f, 0.f, 0.f, 0.f};

    int r0 = tid >> 2, kc0 = tid & 3;
    int r1 = (tid + 256) >> 2, kc1 = tid & 3;

    for (int k0 = 0; k0 < K; k0 += 32) {
        __syncthreads();
        *(uint4*)&As[r0 * 32 + kc0 * 8] =
            *(const uint4*)(A + (size_t)(m0 + r0) * K + k0 + kc0 * 8);
        *(uint4*)&As[r1 * 32 + kc1 * 8] =
            *(const uint4*)(A + (size_t)(m0 + r1) * K + k0 + kc1 * 8);
        *(uint4*)&Bs[r0 * 32 + kc0 * 8] =
            *(const uint4*)(Bt + (size_t)(n0 + r0) * K + k0 + kc0 * 8);
        *(uint4*)&Bs[r1 * 32 + kc1 * 8] =
            *(const uint4*)(Bt + (size_t)(n0 + r1) * K + k0 + kc1 * 8);
        __syncthreads();
        bf16x8 af[4], bfr[4];
#pragma unroll
        for (int r = 0; r < 4; r++)
            af[r] = *(const bf16x8*)&As[(wm + r * 16 + (lane & 15)) * 32 + (lane >> 4) * 8];
#pragma unroll
        for (int c = 0; c < 4; c++)
            bfr[c] = *(const bf16x8*)&Bs[(wn + c * 16 + (lane & 15)) * 32 + (lane >> 4) * 8];
#pragma unroll
        for (int r = 0; r < 4; r++)
#pragma unroll
            for (int c = 0; c < 4; c++)
                acc[r][c] = __builtin_amdgcn_mfma_f32_16x16x32_bf16(af[r], bfr[c], acc[r][c], 0, 0, 0);
    }
    for (int r = 0; r < 4; r++) {
        int grow = m0 + wm + r * 16 + (lane >> 4) * 4;
        for (int c = 0; c < 4; c++) {
            int gcol = n0 + wn + c * 16 + (lane & 15);
            float bv = bias ? bias[gcol] : 0.f;
#pragma unroll
            for (int v = 0; v < 4; v++) {
                float val = acc[r][c][v] + bv;
                if (ACT == 1) val = fmaxf(val, 0.f);
                if (OUTBF16)
                    ((__hip_bfloat16*)Cp)[(size_t)(grow + v) * N + gcol] = __float2bfloat16(val);
                else
                    ((float*)Cp)[(size_t)(grow + v) * N + gcol] = val;
            }
        }
    }
}

template <int ACT, int OUTBF16>
__global__ __launch_bounds__(256) void mfma_gemm(const __hip_bfloat16* __restrict__ A,
                                                 const __hip_bfloat16* __restrict__ Bt,
                                                 const float* __restrict__ bias,
                                                 void* __restrict__ Cp,
                                                 int M, int N, int K) {
    mfma_gemm_body<ACT, OUTBF16>(A, Bt, bias, Cp, M, N, K, blockIdx.x, blockIdx.y);
}

__global__ __launch_bounds__(256) void mfma_gemm_pair(const __hip_bfloat16* A0,
                                                      const __hip_bfloat16* A1,
                                                      const __hip_bfloat16* Bt0,
                                                      const __hip_bfloat16* Bt1,
                                                      const float* bias0, const float* bias1,
                                                      __hip_bfloat16* C0, __hip_bfloat16* C1,
                                                      int M, int N, int K) {
    if (blockIdx.z == 0)
        mfma_gemm_body<1, 1>(A0, Bt0, bias0, C0, M, N, K, blockIdx.x, blockIdx.y);
    else
        mfma_gemm_body<1, 1>(A1, Bt1, bias1, C1, M, N, K, blockIdx.x, blockIdx.y);
}

// ---------------- Split-K skinny MFMA GEMM body: C += A @ Bt^T (atomicAdd) ----------
__device__ __forceinline__ void skgemm_body(const __hip_bfloat16* __restrict__ A,
                                            const __hip_bfloat16* __restrict__ Bt,
                                            float* __restrict__ C,
                                            int M, int Nout, int K, int by, int bz, int nz) {
    __shared__ __align__(16) short As[128 * 32];
    __shared__ __align__(16) short Bs[64 * 32];
    int tid = threadIdx.x;
    int lane = tid & 63, wave = tid >> 6;
    int m0 = by * 128;
    int wm = wave * 32;
    int kchunk = K / nz;
    int kbase = bz * kchunk;
    f32x4 acc[2][4];
    for (int r = 0; r < 2; r++)
        for (int c = 0; c < 4; c++) acc[r][c] = (f32x4){0.f, 0.f, 0.f, 0.f};

    int ra = tid >> 2, kc = (tid & 3) * 8;
    for (int k0 = kbase; k0 < kbase + kchunk; k0 += 32) {
        __syncthreads();
        *(uint4*)&As[ra * 32 + kc] = *(const uint4*)(A + (size_t)(m0 + ra) * K + k0 + kc);
        *(uint4*)&As[(ra + 64) * 32 + kc] =
            *(const uint4*)(A + (size_t)(m0 + ra + 64) * K + k0 + kc);
        uint4 bv = (uint4){0u, 0u, 0u, 0u};
        if (ra < Nout) bv = *(const uint4*)(Bt + (size_t)ra * K + k0 + kc);
        *(uint4*)&Bs[ra * 32 + kc] = bv;
        __syncthreads();
        bf16x8 af[2], bfr[4];
#pragma unroll
        for (int r = 0; r < 2; r++)
            af[r] = *(const bf16x8*)&As[(wm + r * 16 + (lane & 15)) * 32 + (lane >> 4) * 8];
#pragma unroll
        for (int c = 0; c < 4; c++)
            bfr[c] = *(const bf16x8*)&Bs[(c * 16 + (lane & 15)) * 32 + (lane >> 4) * 8];
#pragma unroll
        for (int r = 0; r < 2; r++)
#pragma unroll
            for (int c = 0; c < 4; c++)
                acc[r][c] = __builtin_amdgcn_mfma_f32_16x16x32_bf16(af[r], bfr[c], acc[r][c], 0, 0, 0);
    }
    for (int r = 0; r < 2; r++) {
        int grow = m0 + wm + r * 16 + (lane >> 4) * 4;
        for (int c = 0; c < 4; c++) {
            int gcol = c * 16 + (lane & 15);
            if (gcol >= Nout) continue;
#pragma unroll
            for (int v = 0; v < 4; v++)
                atomicAdd(&C[(size_t)(grow + v) * Nout + gcol], acc[r][c][v]);
        }
    }
}

__global__ __launch_bounds__(256) void skgemm_kernel(const __hip_bfloat16* __restrict__ A,
                                                     const __hip_bfloat16* __restrict__ Bt,
                                                     float* __restrict__ C,
                                                     int M, int Nout, int K) {
    skgemm_body(A, Bt, C, M, Nout, K, blockIdx.y, blockIdx.z, gridDim.z);
}

__global__ __launch_bounds__(256) void skgemm_pair(const __hip_bfloat16* A0,
                                                   const __hip_bfloat16* A1,
                                                   const __hip_bfloat16* Bt0,
                                                   const __hip_bfloat16* Bt1,
                                                   float* C0, float* C1,
                                                   int M, int Nout, int K) {
    if (blockIdx.x == 0)
        skgemm_body(A0, Bt0, C0, M, Nout, K, blockIdx.y, blockIdx.z, gridDim.z);
    else
        skgemm_body(A1, Bt1, C1, M, Nout, K, blockIdx.y, blockIdx.z, gridDim.z);
}

// ---------------- init with broadcast bias ----------------
__global__ __launch_bounds__(256) void initbias2_kernel(float* __restrict__ C0,
                                                        const float* __restrict__ b0,
                                                        float* __restrict__ C1,
                                                        const float* __restrict__ b1,
                                                        int M, int Nout) {
    int idx = blockIdx.x * 256 + threadIdx.x;
    int tot = M * Nout;
    if (idx < tot) C0[idx] = b0[idx % Nout];
    else if (idx < 2 * tot) { idx -= tot; C1[idx] = b1[idx % Nout]; }
}

__global__ __launch_bounds__(256) void initbias_kernel(float* __restrict__ C,
                                                       const float* __restrict__ bias,
                                                       int M, int Nout) {
    int idx = blockIdx.x * 256 + threadIdx.x;
    if (idx < M * Nout) C[idx] = bias[idx % Nout];
}

// ---------------- Build compressed windows (bf16 MLP input) ----------------
__global__ __launch_bounds__(256) void buildwin_kernel(const float* __restrict__ qkv,
                                                       const float* __restrict__ k_pos,
                                                       const float* __restrict__ v_pos,
                                                       __hip_bfloat16* __restrict__ kwflat,
                                                       __hip_bfloat16* __restrict__ vwflat) {
    size_t total = (size_t)(KVH * NCB) * HIDN;
    for (size_t e = (size_t)blockIdx.x * 256 + threadIdx.x; e < total;
         e += (size_t)gridDim.x * 256) {
        int r = (int)(e >> 11);
        int c = (int)(e & 2047);
        int j = c >> 6, d = c & 63;
        int h = r >> 7, i = r & 127;
        int p = i * STRIDE + j - (CBS - STRIDE);
        float kb = k_pos[((size_t)h * CBS + j) * HD + d];
        float vb = v_pos[((size_t)h * CBS + j) * HD + d];
        float kv = 0.f, vv = 0.f;
        if (p >= 0) {
            kv = qkv[(size_t)p * 2048 + 1024 + h * HD + d];
            vv = qkv[(size_t)p * 2048 + 1536 + h * HD + d];
        }
        kwflat[e] = __float2bfloat16(kv + kb);
        vwflat[e] = __float2bfloat16(vv + vb);
    }
}

// ---------------- RoPE + transpose (rq fp32; rk/vt bf16) ----------------
__global__ __launch_bounds__(256) void rope_kernel(const float* __restrict__ qkv,
                                                   float* __restrict__ rq,
                                                   __hip_bfloat16* __restrict__ rk,
                                                   __hip_bfloat16* __restrict__ vt) {
    int n = blockIdx.x;
    int t = threadIdx.x;
    for (int idx = t; idx < NH * 32; idx += 256) {
        int h = idx >> 5, f = idx & 31;
        float inv = exp2f((float)f * -0.41524101186092f);
        float ang = (float)n * inv;
        float cc = cosf(ang), ssn = sinf(ang);
        float a = qkv[(size_t)n * 2048 + h * HD + 2 * f];
        float b = qkv[(size_t)n * 2048 + h * HD + 2 * f + 1];
        float* o = rq + ((size_t)h * NTOK + n) * HD + 2 * f;
        o[0] = a * cc - b * ssn;
        o[1] = b * cc + a * ssn;
    }
    for (int idx = t; idx < KVH * 32; idx += 256) {
        int h = idx >> 5, f = idx & 31;
        float inv = exp2f((float)f * -0.41524101186092f);
        float ang = (float)n * inv;
        float cc = cosf(ang), ssn = sinf(ang);
        float a = qkv[(size_t)n * 2048 + 1024 + h * HD + 2 * f];
        float b = qkv[(size_t)n * 2048 + 1024 + h * HD + 2 * f + 1];
        __hip_bfloat16* o = rk + ((size_t)h * NTOK + n) * HD + 2 * f;
        o[0] = __float2bfloat16(a * cc - b * ssn);
        o[1] = __float2bfloat16(b * cc + a * ssn);
    }
    for (int idx = t; idx < KVH * HD; idx += 256) {
        int h = idx >> 6, d = idx & 63;
        vt[((size_t)h * NTOK + n) * HD + d] =
            __float2bfloat16(qkv[(size_t)n * 2048 + 1536 + h * HD + d]);
    }
}

// ---------------- Compressed attention + importance (tiled) ----------------
__global__ __launch_bounds__(256) void cattn2_kernel(const float* __restrict__ qkv,
                                                     const float* __restrict__ ckraw,
                                                     const float* __restrict__ cvraw,
                                                     const float* __restrict__ memkv,
                                                     float* __restrict__ cout,
                                                     float* __restrict__ imp) {
    int h = blockIdx.x >> 6;
    int i0 = (blockIdx.x & 63) * 32;
    int t = threadIdx.x;
    __shared__ float qs[64][68];
    __shared__ float sc[64][132];
    __shared__ float scratch[32 * 68];
    __shared__ float memk[64], memv[64];
    __shared__ float impm[32], impd[32];

    for (int idx = t; idx < 4096; idx += 256) {
        int row = idx >> 6, d = idx & 63;
        int g = row >> 5, qi = row & 31;
        qs[row][d] = qkv[(size_t)(i0 + qi) * 2048 + (h * 2 + g) * 64 + d];
    }
    if (t < 64) { memk[t] = memkv[h * 64 + t]; memv[t] = memkv[(8 + h) * 64 + t]; }
    __syncthreads();
    if (t < 64) {
        float s = 0.f;
        for (int d = 0; d < 64; d++) s += qs[t][d] * memk[d];
        sc[t][0] = s * SCALE;
    }
    int rg = t >> 3, kg = t & 7;
    for (int c = 0; c < 4; c++) {
        __syncthreads();
        for (int idx = t; idx < 2048; idx += 256) {
            int jj = idx >> 6, d = idx & 63;
            scratch[jj * 68 + d] = ckraw[((size_t)h * 128 + c * 32 + jj) * 64 + d];
        }
        __syncthreads();
        float a0[4] = {}, a1[4] = {};
        for (int d = 0; d < 64; d += 4) {
            float4 q0 = *(const float4*)&qs[rg * 2][d];
            float4 q1 = *(const float4*)&qs[rg * 2 + 1][d];
#pragma unroll
            for (int kk = 0; kk < 4; kk++) {
                float4 kv = *(const float4*)&scratch[(kg + kk * 8) * 68 + d];
                a0[kk] += q0.x * kv.x + q0.y * kv.y + q0.z * kv.z + q0.w * kv.w;
                a1[kk] += q1.x * kv.x + q1.y * kv.y + q1.z * kv.z + q1.w * kv.w;
            }
        }
#pragma unroll
        for (int kk = 0; kk < 4; kk++) {
            sc[rg * 2][1 + c * 32 + kg + kk * 8] = a0[kk] * SCALE;
            sc[rg * 2 + 1][1 + c * 32 + kg + kk * 8] = a1[kk] * SCALE;
        }
    }
    __syncthreads();
    for (int idx = t; idx < 2048; idx += 256) {
        int qi = idx >> 6, fb = idx & 63;
        float v = 0.25f * (sc[qi][1 + 2 * fb] + sc[qi][2 + 2 * fb] +
                           sc[32 + qi][1 + 2 * fb] + sc[32 + qi][2 + 2 * fb]);
        if (fb == ((i0 + qi) >> 5)) v = NEGF;
        scratch[qi * 66 + fb] = v;
    }
    __syncthreads();
    if (t < 32) {
        float m = -1000.f;
        for (int j = 0; j < 64; j++) m = fmaxf(m, scratch[t * 66 + j]);
        float den = expf(-1000.f - m);
        for (int j = 0; j < 64; j++) den += expf(scratch[t * 66 + j] - m);
        impm[t] = m; impd[t] = 1.f / den;
    } else if (t >= 64 && t < 128) {
        int r = t - 64;
        float m = NEGF;
        for (int j = 0; j < 129; j++) m = fmaxf(m, sc[r][j]);
        float den = 0.f;
        for (int j = 0; j < 129; j++) { float e = expf(sc[r][j] - m); sc[r][j] = e; den += e; }
        float inv = 1.f / den;
        for (int j = 0; j < 129; j++) sc[r][j] *= inv;
    }
    __syncthreads();
    for (int idx = t; idx < 2048; idx += 256) {
        int qi = idx >> 6, fb = idx & 63;
        imp[((size_t)h * NTOK + i0 + qi) * 64 + fb] =
            expf(scratch[qi * 66 + fb] - impm[qi]) * impd[qi];
    }
    int dg = t & 7;
    float o0[8], o1[8];
    {
        float p0 = sc[rg * 2][0], p1 = sc[rg * 2 + 1][0];
#pragma unroll
        for (int dd = 0; dd < 8; dd++) {
            float v = memv[dg + dd * 8];
            o0[dd] = p0 * v;
            o1[dd] = p1 * v;
        }
    }
    for (int c = 0; c < 4; c++) {
        __syncthreads();
        for (int idx = t; idx < 2048; idx += 256) {
            int jj = idx >> 6, d = idx & 63;
            scratch[jj * 68 + d] = cvraw[((size_t)h * 128 + c * 32 + jj) * 64 + d];
        }
        __syncthreads();
        for (int jj = 0; jj < 32; jj++) {
            float p0 = sc[rg * 2][1 + c * 32 + jj];
            float p1 = sc[rg * 2 + 1][1 + c * 32 + jj];
#pragma unroll
            for (int dd = 0; dd < 8; dd++) {
                float v = scratch[jj * 68 + dg + dd * 8];
                o0[dd] += p0 * v;
                o1[dd] += p1 * v;
            }
        }
    }
    {
        int row = rg * 2;
        int g = row >> 5, qi = row & 31;
        int g2 = (row + 1) >> 5, qi2 = (row + 1) & 31;
#pragma unroll
        for (int dd = 0; dd < 8; dd++) {
            cout[(((size_t)(h * 2 + g)) * NTOK + i0 + qi) * 64 + dd * 8 + dg] = o0[dd];
            cout[(((size_t)(h * 2 + g2)) * NTOK + i0 + qi2) * 64 + dd * 8 + dg] = o1[dd];
        }
    }
}

// ---------------- Top-k selection ----------------
__global__ __launch_bounds__(256) void topk_kernel(const float* __restrict__ imp,
                                                   int* __restrict__ selidx,
                                                   int* __restrict__ selmask) {
    int idx = blockIdx.x * 256 + threadIdx.x;
    if (idx >= KVH * NTOK) return;
    const float* ip = imp + (size_t)idx * NFB;
    float v[NFB];
    for (int j = 0; j < NFB; j++) v[j] = ip[j];
    unsigned long long taken = 0ull;
    int mk = 0;
    int i = idx & 2047;
    for (int p = 0; p < NSEL; p++) {
        float bv = NEGF;
        int bi = 0;
        for (int j = 0; j < NFB; j++) {
            if (!((taken >> j) & 1ull) && v[j] > bv) { bv = v[j]; bi = j; }
        }
        taken |= 1ull << bi;
        selidx[(size_t)idx * 5 + p] = bi;
        if (bv > 1e-10f) mk |= 1 << p;
    }
    selidx[(size_t)idx * 5 + 4] = i >> 5;
    selmask[idx] = mk;
}

// ---------------- Fused fine + sliding attention (bf16 K/V, wave per query) -------
// blocks [0,4096): fine attention; [4096,8192): sliding window.
__global__ __launch_bounds__(256) void attn_fused_kernel(const float* __restrict__ rq,
                                                         const __hip_bfloat16* __restrict__ rk,
                                                         const __hip_bfloat16* __restrict__ vt,
                                                         const int* __restrict__ selidx,
                                                         const int* __restrict__ selmask,
                                                         float* __restrict__ fout,
                                                         float* __restrict__ sout) {
    int ws = threadIdx.x >> 6, lane = threadIdx.x & 63;
    __shared__ float sp[4][2][160];
    __shared__ int sel[4][5];
    __shared__ int smk[4];
    float* p0 = sp[ws][0];
    float* p1 = sp[ws][1];

    // QK lane layout: key-major. kq = lane>>2 (16 keys), c = lane&3 (4 chunks of 16 dims)
    int kq = lane >> 2, c = lane & 3;
    // PV lane layout: kv8 = lane>>3 (8 keys), c8 = lane&7 (8 chunks of 8 dims)
    int kv8 = lane >> 3, c8 = lane & 7;

    if (blockIdx.x < 4096) {
        // ---------- fine attention ----------
        int wid = blockIdx.x * 4 + ws;
        int h = wid >> 11, i = wid & 2047;
        if (lane < 5) sel[ws][lane] = selidx[((size_t)h * NTOK + i) * 5 + lane];
        if (lane == 5) smk[ws] = selmask[h * NTOK + i];

        const float* q0p = rq + ((size_t)(h * 2 + 0) * NTOK + i) * 64 + c * 16;
        const float* q1p = rq + ((size_t)(h * 2 + 1) * NTOK + i) * 64 + c * 16;
        float4 q0[4], q1[4];
#pragma unroll
        for (int u = 0; u < 4; u++) {
            q0[u] = *(const float4*)(q0p + u * 4);
            q1[u] = *(const float4*)(q1p + u * 4);
        }
        __syncthreads();
        int mk = smk[ws];
        int iq = i & 31;
#pragma unroll
        for (int kt = 0; kt < 10; kt++) {
            int slot = kt >> 1;
            int blk = sel[ws][slot];
            int key = kt * 16 + kq;
            int jj = key & 31;
            int kpos = blk * 32 + jj;
            bool valid = (slot < 4) ? (((mk >> slot) & 1) != 0) : (jj <= iq);
            const __hip_bfloat16* kr = rk + ((size_t)h * NTOK + kpos) * 64 + c * 16;
            float s0 = 0.f, s1 = 0.f;
            uint4 a = *(const uint4*)(kr);
            uint4 b = *(const uint4*)(kr + 8);
            dot8(q0[0], q0[1], a, s0); dot8(q0[2], q0[3], b, s0);
            dot8(q1[0], q1[1], a, s1); dot8(q1[2], q1[3], b, s1);
            s0 += __shfl_xor(s0, 1); s0 += __shfl_xor(s0, 2);
            s1 += __shfl_xor(s1, 1); s1 += __shfl_xor(s1, 2);
            if (c == 0) {
                p0[key] = valid ? s0 * SCALE : NEG10F;
                p1[key] = valid ? s1 * SCALE : NEG10F;
            }
        }
        __syncthreads();
        // softmax over 160
        {
            float a0 = p0[lane], b0 = p0[lane + 64];
            float c0 = (lane < 32) ? p0[lane + 128] : NEG10F;
            float a1 = p1[lane], b1 = p1[lane + 64];
            float c1 = (lane < 32) ? p1[lane + 128] : NEG10F;
            float m0 = fmaxf(fmaxf(a0, b0), c0);
            float m1 = fmaxf(fmaxf(a1, b1), c1);
#pragma unroll
            for (int o = 1; o < 64; o <<= 1) {
                m0 = fmaxf(m0, __shfl_xor(m0, o));
                m1 = fmaxf(m1, __shfl_xor(m1, o));
            }
            float ea0 = __expf(a0 - m0), eb0 = __expf(b0 - m0), ec0 = (lane < 32) ? __expf(c0 - m0) : 0.f;
            float ea1 = __expf(a1 - m1), eb1 = __expf(b1 - m1), ec1 = (lane < 32) ? __expf(c1 - m1) : 0.f;
            float d0 = ea0 + eb0 + ec0;
            float d1 = ea1 + eb1 + ec1;
#pragma unroll
            for (int o = 1; o < 64; o <<= 1) {
                d0 += __shfl_xor(d0, o);
                d1 += __shfl_xor(d1, o);
            }
            float inv0 = 1.f / d0, inv1 = 1.f / d1;
            p0[lane] = ea0 * inv0; p0[lane + 64] = eb0 * inv0;
            p1[lane] = ea1 * inv1; p1[lane + 64] = eb1 * inv1;
            if (lane < 32) { p0[lane + 128] = ec0 * inv0; p1[lane + 128] = ec1 * inv1; }
        }
        __syncthreads();
        // PV
        float o0[8] = {}, o1[8] = {};
#pragma unroll
        for (int slot = 0; slot < 5; slot++) {
            const __hip_bfloat16* vbase = vt + ((size_t)h * NTOK + sel[ws][slot] * 32) * 64;
#pragma unroll
            for (int pass = 0; pass < 4; pass++) {
                int j = pass * 8 + kv8;
                uint4 v = *(const uint4*)(vbase + j * 64 + c8 * 8);
                float pa = p0[slot * 32 + j], pb = p1[slot * 32 + j];
                float e0 = bflo(v.x), e1 = bfhi(v.x), e2 = bflo(v.y), e3 = bfhi(v.y);
                float e4 = bflo(v.z), e5 = bfhi(v.z), e6 = bflo(v.w), e7 = bfhi(v.w);
                o0[0] = fmaf(pa, e0, o0[0]); o0[1] = fmaf(pa, e1, o0[1]);
                o0[2] = fmaf(pa, e2, o0[2]); o0[3] = fmaf(pa, e3, o0[3]);
                o0[4] = fmaf(pa, e4, o0[4]); o0[5] = fmaf(pa, e5, o0[5]);
                o0[6] = fmaf(pa, e6, o0[6]); o0[7] = fmaf(pa, e7, o0[7]);
                o1[0] = fmaf(pb, e0, o1[0]); o1[1] = fmaf(pb, e1, o1[1]);
                o1[2] = fmaf(pb, e2, o1[2]); o1[3] = fmaf(pb, e3, o1[3]);
                o1[4] = fmaf(pb, e4, o1[4]); o1[5] = fmaf(pb, e5, o1[5]);
                o1[6] = fmaf(pb, e6, o1[6]); o1[7] = fmaf(pb, e7, o1[7]);
            }
        }
#pragma unroll
        for (int o = 8; o <= 32; o <<= 1)
#pragma unroll
            for (int d = 0; d < 8; d++) {
                o0[d] += __shfl_xor(o0[d], o);
                o1[d] += __shfl_xor(o1[d], o);
            }
        if (kv8 == 0) {
            float* f0 = fout + ((size_t)(h * 2 + 0) * NTOK + i) * 64 + c8 * 8;
            float* f1 = fout + ((size_t)(h * 2 + 1) * NTOK + i) * 64 + c8 * 8;
            *(float4*)(f0) = (float4){o0[0], o0[1], o0[2], o0[3]};
            *(float4*)(f0 + 4) = (float4){o0[4], o0[5], o0[6], o0[7]};
            *(float4*)(f1) = (float4){o1[0], o1[1], o1[2], o1[3]};
            *(float4*)(f1 + 4) = (float4){o1[4], o1[5], o1[6], o1[7]};
        }
    } else {
        // ---------- sliding-window attention ----------
        int wid = (blockIdx.x - 4096) * 4 + ws;
        int h = wid >> 11, i = wid & 2047;
        const float* q0p = rq + ((size_t)(h * 2 + 0) * NTOK + i) * 64 + c * 16;
        const float* q1p = rq + ((size_t)(h * 2 + 1) * NTOK + i) * 64 + c * 16;
        float4 q0[4], q1[4];
#pragma unroll
        for (int u = 0; u < 4; u++) {
            q0[u] = *(const float4*)(q0p + u * 4);
            q1[u] = *(const float4*)(q1p + u * 4);
        }
#pragma unroll
        for (int kt = 0; kt < 4; kt++) {
            int key = kt * 16 + kq;
            int kpos = i - 63 + key;
            int kp = kpos < 0 ? 0 : kpos;
            const __hip_bfloat16* kr = rk + ((size_t)h * NTOK + kp) * 64 + c * 16;
            float s0 = 0.f, s1 = 0.f;
            uint4 a = *(const uint4*)(kr);
            uint4 b = *(const uint4*)(kr + 8);
            dot8(q0[0], q0[1], a, s0); dot8(q0[2], q0[3], b, s0);
            dot8(q1[0], q1[1], a, s1); dot8(q1[2], q1[3], b, s1);
            s0 += __shfl_xor(s0, 1); s0 += __shfl_xor(s0, 2);
            s1 += __shfl_xor(s1, 1); s1 += __shfl_xor(s1, 2);
            if (c == 0) {
                p0[key] = (kpos >= 0) ? s0 * SCALE : NEG10F;
                p1[key] = (kpos >= 0) ? s1 * SCALE : NEG10F;
            }
        }
        __syncthreads();
        {
            float a0 = p0[lane], a1 = p1[lane];
            float m0 = a0, m1 = a1;
#pragma unroll
            for (int o = 1; o < 64; o <<= 1) {
                m0 = fmaxf(m0, __shfl_xor(m0, o));
                m1 = fmaxf(m1, __shfl_xor(m1, o));
            }
            float e0 = __expf(a0 - m0), e1 = __expf(a1 - m1);
            float d0 = e0, d1 = e1;
#pragma unroll
            for (int o = 1; o < 64; o <<= 1) {
                d0 += __shfl_xor(d0, o);
                d1 += __shfl_xor(d1, o);
            }
            p0[lane] = e0 / d0;
            p1[lane] = e1 / d1;
        }
        __syncthreads();
        int base = i - 63;
        float o0[8] = {}, o1[8] = {};
        const __hip_bfloat16* vbase = vt + (size_t)h * NTOK * 64;
#pragma unroll
        for (int pass = 0; pass < 8; pass++) {
            int j = pass * 8 + kv8;
            int kpos = base + j;
            int kp = kpos < 0 ? 0 : kpos;  // prob is exactly 0 for invalid
            uint4 v = *(const uint4*)(vbase + (size_t)kp * 64 + c8 * 8);
            float pa = p0[j], pb = p1[j];
            float e0 = bflo(v.x), e1 = bfhi(v.x), e2 = bflo(v.y), e3 = bfhi(v.y);
            float e4 = bflo(v.z), e5 = bfhi(v.z), e6 = bflo(v.w), e7 = bfhi(v.w);
            o0[0] = fmaf(pa, e0, o0[0]); o0[1] = fmaf(pa, e1, o0[1]);
            o0[2] = fmaf(pa, e2, o0[2]); o0[3] = fmaf(pa, e3, o0[3]);
            o0[4] = fmaf(pa, e4, o0[4]); o0[5] = fmaf(pa, e5, o0[5]);
            o0[6] = fmaf(pa, e6, o0[6]); o0[7] = fmaf(pa, e7, o0[7]);
            o1[0] = fmaf(pb, e0, o1[0]); o1[1] = fmaf(pb, e1, o1[1]);
            o1[2] = fmaf(pb, e2, o1[2]); o1[3] = fmaf(pb, e3, o1[3]);
            o1[4] = fmaf(pb, e4, o1[4]); o1[5] = fmaf(pb, e5, o1[5]);
            o1[6] = fmaf(pb, e6, o1[6]); o1[7] = fmaf(pb, e7, o1[7]);
        }
#pragma unroll
        for (int o = 8; o <= 32; o <<= 1)
#pragma unroll
            for (int d = 0; d < 8; d++) {
                o0[d] += __shfl_xor(o0[d], o);
                o1[d] += __shfl_xor(o1[d], o);
            }
        if (kv8 == 0) {
            float* s0p = sout + ((size_t)(h * 2 + 0) * NTOK + i) * 64 + c8 * 8;
            float* s1p = sout + ((size_t)(h * 2 + 1) * NTOK + i) * 64 + c8 * 8;
            *(float4*)(s0p) = (float4){o0[0], o0[1], o0[2], o0[3]};
            *(float4*)(s0p + 4) = (float4){o0[4], o0[5], o0[6], o0[7]};
            *(float4*)(s1p) = (float4){o1[0], o1[1], o1[2], o1[3]};
            *(float4*)(s1p + 4) = (float4){o1[4], o1[5], o1[6], o1[7]};
        }
    }
}

// ---------------- Gated combine (sigmoid applied here; writes bf16) ----------------
__global__ __launch_bounds__(256) void combine_kernel(const float* __restrict__ gateslin,
                                                      const float* __restrict__ cout,
                                                      const float* __restrict__ fout,
                                                      const float* __restrict__ sout,
                                                      __hip_bfloat16* __restrict__ att) {
    int n = blockIdx.x;
    for (int c = threadIdx.x; c < NH * HD; c += 256) {
        int hd = c >> 6, d = c & 63;
        float g0 = 1.f / (1.f + expf(-gateslin[(size_t)n * (NH * 3) + hd * 3 + 0]));
        float g1 = 1.f / (1.f + expf(-gateslin[(size_t)n * (NH * 3) + hd * 3 + 1]));
        float g2 = 1.f / (1.f + expf(-gateslin[(size_t)n * (NH * 3) + hd * 3 + 2]));
        size_t o = ((size_t)hd * NTOK + n) * HD + d;
        att[(size_t)n * (NH * HD) + c] =
            __float2bfloat16(g0 * cout[o] + g1 * fout[o] + g2 * sout[o]);
    }
}

extern "C" void kernel_launch(void* const* d_in, const int* in_sizes, int n_in,
                              void* d_out, int out_size, void* d_ws, size_t ws_size,
                              hipStream_t stream) {
    const float* inp    = (const float*)d_in[0];
    const float* norm_g = (const float*)d_in[1];
    const float* Wqkv   = (const float*)d_in[2];
    const float* mem_kv = (const float*)d_in[3];
    const float* k_pos  = (const float*)d_in[4];
    const float* v_pos  = (const float*)d_in[5];
    const float* kW1    = (const float*)d_in[6];
    const float* kb1    = (const float*)d_in[7];
    const float* kW2    = (const float*)d_in[8];
    const float* kb2    = (const float*)d_in[9];
    const float* vW1    = (const float*)d_in[10];
    const float* vb1    = (const float*)d_in[11];
    const float* vW2    = (const float*)d_in[12];
    const float* vb2    = (const float*)d_in[13];
    const float* combW  = (const float*)d_in[14];
    const float* combB  = (const float*)d_in[15];
    const float* Wout   = (const float*)d_in[16];
    float* out = (float*)d_out;

    char* base = (char*)d_ws;
    size_t off = 0;
    auto alloc = [&](size_t bytes) {
        void* p = base + off;
        off += (bytes + 255) & ~(size_t)255;
        return p;
    };
    float* x            = (float*)alloc((size_t)NTOK * DIM * 4);
    __hip_bfloat16* xb  = (__hip_bfloat16*)alloc((size_t)NTOK * DIM * 2);
    float* qkv          = (float*)alloc((size_t)NTOK * 2048 * 4);
    __hip_bfloat16* Wqkvt = (__hip_bfloat16*)alloc((size_t)2048 * 1024 * 2);
    __hip_bfloat16* kW1t  = (__hip_bfloat16*)alloc((size_t)2048 * 2048 * 2);
    __hip_bfloat16* vW1t  = (__hip_bfloat16*)alloc((size_t)2048 * 2048 * 2);
    __hip_bfloat16* Woutt = (__hip_bfloat16*)alloc((size_t)1024 * 1024 * 2);
    __hip_bfloat16* combWt = (__hip_bfloat16*)alloc((size_t)48 * 1024 * 2);
    __hip_bfloat16* kW2t  = (__hip_bfloat16*)alloc((size_t)64 * 2048 * 2);
    __hip_bfloat16* vW2t  = (__hip_bfloat16*)alloc((size_t)64 * 2048 * 2);
    __hip_bfloat16* kwflat = (__hip_bfloat16*)alloc((size_t)KVH * NCB * HIDN * 2);
    __hip_bfloat16* vwflat = (__hip_bfloat16*)alloc((size_t)KVH * NCB * HIDN * 2);
    __hip_bfloat16* hidkb = (__hip_bfloat16*)alloc((size_t)KVH * NCB * HIDN * 2);
    __hip_bfloat16* hidvb = (__hip_bfloat16*)alloc((size_t)KVH * NCB * HIDN * 2);
    float* ckraw        = (float*)alloc((size_t)KVH * NCB * HD * 4);
    float* cvraw        = (float*)alloc((size_t)KVH * NCB * HD * 4);
    float* rq           = (float*)alloc((size_t)NH * NTOK * HD * 4);
    __hip_bfloat16* rk  = (__hip_bfloat16*)alloc((size_t)KVH * NTOK * HD * 2);
    __hip_bfloat16* vt  = (__hip_bfloat16*)alloc((size_t)KVH * NTOK * HD * 2);
    float* coutb        = (float*)alloc((size_t)NH * NTOK * HD * 4);
    float* foutb        = (float*)alloc((size_t)NH * NTOK * HD * 4);
    float* soutb        = (float*)alloc((size_t)NH * NTOK * HD * 4);
    float* impb         = (float*)alloc((size_t)KVH * NTOK * NFB * 4);
    float* gatesb       = (float*)alloc((size_t)NTOK * NH * 3 * 4);
    __hip_bfloat16* attb = (__hip_bfloat16*)alloc((size_t)NTOK * DIM * 2);
    int* selidx         = (int*)alloc((size_t)KVH * NTOK * 5 * 4);
    int* selmask        = (int*)alloc((size_t)KVH * NTOK * 4);
    (void)ws_size; (void)in_sizes; (void)n_in; (void)out_size;

    // 1. RMSNorm (fp32 + bf16)
    rmsnorm_kernel<<<NTOK, 256, 0, stream>>>(inp, norm_g, x, xb);
    // 2. merged transpose-cast of all weights to bf16 NxK
    transpose_all_kernel<<<11584, 256, 0, stream>>>(Wqkv, Wqkvt, kW1, kW1t, vW1, vW1t,
                                                    Wout, Woutt, combW, combWt,
                                                    kW2, kW2t, vW2, vW2t);
    // 3. qkv = x @ Wqkv  (MFMA)
    mfma_gemm<0, 0><<<dim3(16, 16), 256, 0, stream>>>(xb, Wqkvt, nullptr, qkv, 2048, 2048, 1024);
    // 4. gates linear = x @ combW + combB  (split-K MFMA, sigmoid in combine)
    initbias_kernel<<<(NTOK * 48 + 255) / 256, 256, 0, stream>>>(gatesb, combB, NTOK, 48);
    skgemm_kernel<<<dim3(1, 16, 4), 256, 0, stream>>>(xb, combWt, gatesb, 2048, 48, 1024);
    // 5. build compressed windows (bf16)
    buildwin_kernel<<<4096, 256, 0, stream>>>(qkv, k_pos, v_pos, kwflat, vwflat);
    // 6. compressed k/v MLP layer 1 (batched: 256 blocks)
    mfma_gemm_pair<<<dim3(16, 8, 2), 256, 0, stream>>>(kwflat, vwflat, kW1t, vW1t,
                                                       kb1, vb1, hidkb, hidvb,
                                                       1024, 2048, 2048);
    // 7. compressed k/v MLP layer 2 (batched split-K)
    initbias2_kernel<<<(2 * 1024 * 64 + 255) / 256, 256, 0, stream>>>(ckraw, kb2, cvraw, vb2, 1024, 64);
    skgemm_pair<<<dim3(2, 8, 8), 256, 0, stream>>>(hidkb, hidvb, kW2t, vW2t,
                                                   ckraw, cvraw, 1024, 64, 2048);
    // 8. RoPE + transposes (rk/vt bf16)
    rope_kernel<<<NTOK, 256, 0, stream>>>(qkv, rq, rk, vt);
    // 9. compressed attention + importance (tiled)
    cattn2_kernel<<<KVH * (NTOK / 32), 256, 0, stream>>>(qkv, ckraw, cvraw, mem_kv, coutb, impb);
    // 10. top-k block selection
    topk_kernel<<<(KVH * NTOK) / 256, 256, 0, stream>>>(impb, selidx, selmask);
    // 11+12. fused fine + sliding attention
    attn_fused_kernel<<<8192, 256, 0, stream>>>(rq, rk, vt, selidx, selmask, foutb, soutb);
    // 13. gated combine (sigmoid here, bf16 out)
    combine_kernel<<<NTOK, 256, 0, stream>>>(gatesb, coutb, foutb, soutb, attb);
    // 14. out projection (MFMA)
    mfma_gemm<0, 0><<<dim3(8, 16), 256, 0, stream>>>(attb, Woutt, nullptr, out, 2048, 1024, 1024);
}

// Round 7
// 411.832 us; speedup vs baseline: 7.4573x; 1.0291x over previous
//
#include <hip/hip_runtime.h>
#include <hip/hip_bf16.h>

// Problem constants
#define NTOK 2048
#define DIM 1024
#define NH 16
#define KVH 8
#define GQ 2
#define HD 64
#define WS 64
#define CBS 32
#define STRIDE 16
#define SEL_BLK 32
#define NSEL 4
#define NMEM 1
#define NCB 128          // N/STRIDE
#define NFB 64           // N/SEL_BLK
#define HIDN 2048        // CBS*D
#define SCALE 0.125f
#define NEGF (-3.4028234663852886e38f)
#define NEG10F (-3.4028234663852886e37f)

typedef __attribute__((ext_vector_type(8))) short bf16x8;
typedef __attribute__((ext_vector_type(4))) float f32x4;

__device__ __forceinline__ float bflo(unsigned u) { return __uint_as_float(u << 16); }
__device__ __forceinline__ float bfhi(unsigned u) { return __uint_as_float(u & 0xffff0000u); }
__device__ __forceinline__ void dot8(const float4& qa, const float4& qb, uint4 a, float& s) {
    s += qa.x * bflo(a.x) + qa.y * bfhi(a.x) + qa.z * bflo(a.y) + qa.w * bfhi(a.y) +
         qb.x * bflo(a.z) + qb.y * bfhi(a.z) + qb.z * bflo(a.w) + qb.w * bfhi(a.w);
}

// async 16B global -> LDS (LDS dest must be wave-uniform base + lane*16)
__device__ __forceinline__ void gload_lds16(const void* g, void* l) {
    __builtin_amdgcn_global_load_lds((const __attribute__((address_space(1))) unsigned*)g,
                                     (__attribute__((address_space(3))) unsigned*)l, 16, 0, 0);
}

// ---------------- RMSNorm (writes fp32 x and bf16 xb) ----------------
__global__ __launch_bounds__(256) void rmsnorm_kernel(const float* __restrict__ inp,
                                                      const float* __restrict__ g,
                                                      float* __restrict__ x,
                                                      __hip_bfloat16* __restrict__ xb) {
    int n = blockIdx.x;
    const float* row = inp + (size_t)n * DIM;
    float ss = 0.f;
    for (int c = threadIdx.x; c < DIM; c += 256) { float v = row[c]; ss += v * v; }
    __shared__ float red[4];
    for (int o = 32; o; o >>= 1) ss += __shfl_down(ss, o, 64);
    if ((threadIdx.x & 63) == 0) red[threadIdx.x >> 6] = ss;
    __syncthreads();
    if (threadIdx.x == 0) red[0] = red[0] + red[1] + red[2] + red[3];
    __syncthreads();
    float rs = 1.0f / sqrtf(red[0] / (float)DIM + 1.1920928955078125e-07f);
    float* xr = x + (size_t)n * DIM;
    __hip_bfloat16* xbr = xb + (size_t)n * DIM;
    for (int c = threadIdx.x; c < DIM; c += 256) {
        float v = row[c] * rs * g[c];
        xr[c] = v;
        xbr[c] = __float2bfloat16(v);
    }
}

// ---------------- Merged transpose+cast of all 7 weights ----------------
__device__ __forceinline__ void transpose_body(const float* __restrict__ B,
                                               __hip_bfloat16* __restrict__ Bt,
                                               int K, int N, int bx, int by) {
    __shared__ float tile[32][33];
    int n0 = bx * 32, k0 = by * 32;
    int x = threadIdx.x & 31, y = threadIdx.x >> 5;
    for (int i = 0; i < 4; i++) {
        int k = k0 + y + 8 * i, n = n0 + x;
        tile[y + 8 * i][x] = (k < K && n < N) ? B[(size_t)k * N + n] : 0.f;
    }
    __syncthreads();
    for (int i = 0; i < 4; i++) {
        int n = n0 + y + 8 * i, k = k0 + x;
        if (n < N && k < K) Bt[(size_t)n * K + k] = __float2bfloat16(tile[x][y + 8 * i]);
    }
}

__global__ __launch_bounds__(256) void transpose_all_kernel(
    const float* Wqkv, __hip_bfloat16* Wqkvt,
    const float* kW1, __hip_bfloat16* kW1t,
    const float* vW1, __hip_bfloat16* vW1t,
    const float* Wout, __hip_bfloat16* Woutt,
    const float* combW, __hip_bfloat16* combWt,
    const float* kW2, __hip_bfloat16* kW2t,
    const float* vW2, __hip_bfloat16* vW2t) {
    int b = blockIdx.x;
    if (b < 2048) { transpose_body(Wqkv, Wqkvt, 1024, 2048, b % 64, b / 64); return; }
    b -= 2048;
    if (b < 4096) { transpose_body(kW1, kW1t, 2048, 2048, b % 64, b / 64); return; }
    b -= 4096;
    if (b < 4096) { transpose_body(vW1, vW1t, 2048, 2048, b % 64, b / 64); return; }
    b -= 4096;
    if (b < 1024) { transpose_body(Wout, Woutt, 1024, 1024, b % 32, b / 32); return; }
    b -= 1024;
    if (b < 64) { transpose_body(combW, combWt, 1024, 48, b % 2, b / 2); return; }
    b -= 64;
    if (b < 128) { transpose_body(kW2, kW2t, 2048, 64, b % 2, b / 2); return; }
    b -= 128;
    transpose_body(vW2, vW2t, 2048, 64, b % 2, b / 2);
}

// ---------------- bf16 MFMA GEMM body (global_load_lds staging) ----------------
template <int ACT, int OUTBF16>
__device__ __forceinline__ void mfma_gemm_body(const __hip_bfloat16* __restrict__ A,
                                               const __hip_bfloat16* __restrict__ Bt,
                                               const float* __restrict__ bias,
                                               void* __restrict__ Cp,
                                               int M, int N, int K, int bx, int by) {
    __shared__ __align__(16) short As[128 * 32];
    __shared__ __align__(16) short Bs[128 * 32];
    int tid = threadIdx.x;
    int lane = tid & 63, wave = tid >> 6;
    int wm = (wave >> 1) * 64, wn = (wave & 1) * 64;
    int m0 = by * 128, n0 = bx * 128;
    f32x4 acc[4][4];
    for (int r = 0; r < 4; r++)
        for (int c = 0; c < 4; c++)
            acc[r][c] = (f32x4){0.f, 0.f, 0.f, 0.f};

    int r0 = tid >> 2, kc0 = (tid & 3) * 8;
    int r1 = r0 + 64;

    for (int k0 = 0; k0 < K; k0 += 32) {
        __syncthreads();
        gload_lds16(A + (size_t)(m0 + r0) * K + k0 + kc0, &As[r0 * 32 + kc0]);
        gload_lds16(A + (size_t)(m0 + r1) * K + k0 + kc0, &As[r1 * 32 + kc0]);
        gload_lds16(Bt + (size_t)(n0 + r0) * K + k0 + kc0, &Bs[r0 * 32 + kc0]);
        gload_lds16(Bt + (size_t)(n0 + r1) * K + k0 + kc0, &Bs[r1 * 32 + kc0]);
        __syncthreads();
        bf16x8 af[4], bfr[4];
#pragma unroll
        for (int r = 0; r < 4; r++)
            af[r] = *(const bf16x8*)&As[(wm + r * 16 + (lane & 15)) * 32 + (lane >> 4) * 8];
#pragma unroll
        for (int c = 0; c < 4; c++)
            bfr[c] = *(const bf16x8*)&Bs[(wn + c * 16 + (lane & 15)) * 32 + (lane >> 4) * 8];
#pragma unroll
        for (int r = 0; r < 4; r++)
#pragma unroll
            for (int c = 0; c < 4; c++)
                acc[r][c] = __builtin_amdgcn_mfma_f32_16x16x32_bf16(af[r], bfr[c], acc[r][c], 0, 0, 0);
    }
    for (int r = 0; r < 4; r++) {
        int grow = m0 + wm + r * 16 + (lane >> 4) * 4;
        for (int c = 0; c < 4; c++) {
            int gcol = n0 + wn + c * 16 + (lane & 15);
            float bv = bias ? bias[gcol] : 0.f;
#pragma unroll
            for (int v = 0; v < 4; v++) {
                float val = acc[r][c][v] + bv;
                if (ACT == 1) val = fmaxf(val, 0.f);
                if (OUTBF16)
                    ((__hip_bfloat16*)Cp)[(size_t)(grow + v) * N + gcol] = __float2bfloat16(val);
                else
                    ((float*)Cp)[(size_t)(grow + v) * N + gcol] = val;
            }
        }
    }
}

template <int ACT, int OUTBF16>
__global__ __launch_bounds__(256) void mfma_gemm(const __hip_bfloat16* __restrict__ A,
                                                 const __hip_bfloat16* __restrict__ Bt,
                                                 const float* __restrict__ bias,
                                                 void* __restrict__ Cp,
                                                 int M, int N, int K) {
    mfma_gemm_body<ACT, OUTBF16>(A, Bt, bias, Cp, M, N, K, blockIdx.x, blockIdx.y);
}

__global__ __launch_bounds__(256) void mfma_gemm_pair(const __hip_bfloat16* A0,
                                                      const __hip_bfloat16* A1,
                                                      const __hip_bfloat16* Bt0,
                                                      const __hip_bfloat16* Bt1,
                                                      const float* bias0, const float* bias1,
                                                      __hip_bfloat16* C0, __hip_bfloat16* C1,
                                                      int M, int N, int K) {
    if (blockIdx.z == 0)
        mfma_gemm_body<1, 1>(A0, Bt0, bias0, C0, M, N, K, blockIdx.x, blockIdx.y);
    else
        mfma_gemm_body<1, 1>(A1, Bt1, bias1, C1, M, N, K, blockIdx.x, blockIdx.y);
}

// ---------------- Split-K skinny MFMA GEMM body: C += A @ Bt^T (atomicAdd) ----------
__device__ __forceinline__ void skgemm_body(const __hip_bfloat16* __restrict__ A,
                                            const __hip_bfloat16* __restrict__ Bt,
                                            float* __restrict__ C,
                                            int M, int Nout, int K, int by, int bz, int nz) {
    __shared__ __align__(16) short As[128 * 32];
    __shared__ __align__(16) short Bs[64 * 32];
    int tid = threadIdx.x;
    int lane = tid & 63, wave = tid >> 6;
    int m0 = by * 128;
    int wm = wave * 32;
    int kchunk = K / nz;
    int kbase = bz * kchunk;
    f32x4 acc[2][4];
    for (int r = 0; r < 2; r++)
        for (int c = 0; c < 4; c++) acc[r][c] = (f32x4){0.f, 0.f, 0.f, 0.f};

    int ra = tid >> 2, kc = (tid & 3) * 8;
    int rb = ra < Nout ? ra : Nout - 1;   // clamp: rows >= Nout hold copies, cols discarded at store
    for (int k0 = kbase; k0 < kbase + kchunk; k0 += 32) {
        __syncthreads();
        gload_lds16(A + (size_t)(m0 + ra) * K + k0 + kc, &As[ra * 32 + kc]);
        gload_lds16(A + (size_t)(m0 + ra + 64) * K + k0 + kc, &As[(ra + 64) * 32 + kc]);
        gload_lds16(Bt + (size_t)rb * K + k0 + kc, &Bs[ra * 32 + kc]);
        __syncthreads();
        bf16x8 af[2], bfr[4];
#pragma unroll
        for (int r = 0; r < 2; r++)
            af[r] = *(const bf16x8*)&As[(wm + r * 16 + (lane & 15)) * 32 + (lane >> 4) * 8];
#pragma unroll
        for (int c = 0; c < 4; c++)
            bfr[c] = *(const bf16x8*)&Bs[(c * 16 + (lane & 15)) * 32 + (lane >> 4) * 8];
#pragma unroll
        for (int r = 0; r < 2; r++)
#pragma unroll
            for (int c = 0; c < 4; c++)
                acc[r][c] = __builtin_amdgcn_mfma_f32_16x16x32_bf16(af[r], bfr[c], acc[r][c], 0, 0, 0);
    }
    for (int r = 0; r < 2; r++) {
        int grow = m0 + wm + r * 16 + (lane >> 4) * 4;
        for (int c = 0; c < 4; c++) {
            int gcol = c * 16 + (lane & 15);
            if (gcol >= Nout) continue;
#pragma unroll
            for (int v = 0; v < 4; v++)
                atomicAdd(&C[(size_t)(grow + v) * Nout + gcol], acc[r][c][v]);
        }
    }
}

__global__ __launch_bounds__(256) void skgemm_kernel(const __hip_bfloat16* __restrict__ A,
                                                     const __hip_bfloat16* __restrict__ Bt,
                                                     float* __restrict__ C,
                                                     int M, int Nout, int K) {
    skgemm_body(A, Bt, C, M, Nout, K, blockIdx.y, blockIdx.z, gridDim.z);
}

__global__ __launch_bounds__(256) void skgemm_pair(const __hip_bfloat16* A0,
                                                   const __hip_bfloat16* A1,
                                                   const __hip_bfloat16* Bt0,
                                                   const __hip_bfloat16* Bt1,
                                                   float* C0, float* C1,
                                                   int M, int Nout, int K) {
    if (blockIdx.x == 0)
        skgemm_body(A0, Bt0, C0, M, Nout, K, blockIdx.y, blockIdx.z, gridDim.z);
    else
        skgemm_body(A1, Bt1, C1, M, Nout, K, blockIdx.y, blockIdx.z, gridDim.z);
}

// ---------------- init with broadcast bias ----------------
__global__ __launch_bounds__(256) void initbias2_kernel(float* __restrict__ C0,
                                                        const float* __restrict__ b0,
                                                        float* __restrict__ C1,
                                                        const float* __restrict__ b1,
                                                        int M, int Nout) {
    int idx = blockIdx.x * 256 + threadIdx.x;
    int tot = M * Nout;
    if (idx < tot) C0[idx] = b0[idx % Nout];
    else if (idx < 2 * tot) { idx -= tot; C1[idx] = b1[idx % Nout]; }
}

__global__ __launch_bounds__(256) void initbias_kernel(float* __restrict__ C,
                                                       const float* __restrict__ bias,
                                                       int M, int Nout) {
    int idx = blockIdx.x * 256 + threadIdx.x;
    if (idx < M * Nout) C[idx] = bias[idx % Nout];
}

// ---------------- Build compressed windows (bf16 MLP input) ----------------
__global__ __launch_bounds__(256) void buildwin_kernel(const float* __restrict__ qkv,
                                                       const float* __restrict__ k_pos,
                                                       const float* __restrict__ v_pos,
                                                       __hip_bfloat16* __restrict__ kwflat,
                                                       __hip_bfloat16* __restrict__ vwflat) {
    size_t total = (size_t)(KVH * NCB) * HIDN;
    for (size_t e = (size_t)blockIdx.x * 256 + threadIdx.x; e < total;
         e += (size_t)gridDim.x * 256) {
        int r = (int)(e >> 11);
        int c = (int)(e & 2047);
        int j = c >> 6, d = c & 63;
        int h = r >> 7, i = r & 127;
        int p = i * STRIDE + j - (CBS - STRIDE);
        float kb = k_pos[((size_t)h * CBS + j) * HD + d];
        float vb = v_pos[((size_t)h * CBS + j) * HD + d];
        float kv = 0.f, vv = 0.f;
        if (p >= 0) {
            kv = qkv[(size_t)p * 2048 + 1024 + h * HD + d];
            vv = qkv[(size_t)p * 2048 + 1536 + h * HD + d];
        }
        kwflat[e] = __float2bfloat16(kv + kb);
        vwflat[e] = __float2bfloat16(vv + vb);
    }
}

// ---------------- RoPE + transpose (rq fp32; rk/vt bf16) ----------------
__global__ __launch_bounds__(256) void rope_kernel(const float* __restrict__ qkv,
                                                   float* __restrict__ rq,
                                                   __hip_bfloat16* __restrict__ rk,
                                                   __hip_bfloat16* __restrict__ vt) {
    int n = blockIdx.x;
    int t = threadIdx.x;
    for (int idx = t; idx < NH * 32; idx += 256) {
        int h = idx >> 5, f = idx & 31;
        float inv = exp2f((float)f * -0.41524101186092f);
        float ang = (float)n * inv;
        float cc = cosf(ang), ssn = sinf(ang);
        float a = qkv[(size_t)n * 2048 + h * HD + 2 * f];
        float b = qkv[(size_t)n * 2048 + h * HD + 2 * f + 1];
        float* o = rq + ((size_t)h * NTOK + n) * HD + 2 * f;
        o[0] = a * cc - b * ssn;
        o[1] = b * cc + a * ssn;
    }
    for (int idx = t; idx < KVH * 32; idx += 256) {
        int h = idx >> 5, f = idx & 31;
        float inv = exp2f((float)f * -0.41524101186092f);
        float ang = (float)n * inv;
        float cc = cosf(ang), ssn = sinf(ang);
        float a = qkv[(size_t)n * 2048 + 1024 + h * HD + 2 * f];
        float b = qkv[(size_t)n * 2048 + 1024 + h * HD + 2 * f + 1];
        __hip_bfloat16* o = rk + ((size_t)h * NTOK + n) * HD + 2 * f;
        o[0] = __float2bfloat16(a * cc - b * ssn);
        o[1] = __float2bfloat16(b * cc + a * ssn);
    }
    for (int idx = t; idx < KVH * HD; idx += 256) {
        int h = idx >> 6, d = idx & 63;
        vt[((size_t)h * NTOK + n) * HD + d] =
            __float2bfloat16(qkv[(size_t)n * 2048 + 1536 + h * HD + d]);
    }
}

// ---------------- Compressed attention + importance + fused top-k ----------------
__global__ __launch_bounds__(256) void cattn2_kernel(const float* __restrict__ qkv,
                                                     const float* __restrict__ ckraw,
                                                     const float* __restrict__ cvraw,
                                                     const float* __restrict__ memkv,
                                                     float* __restrict__ cout,
                                                     int* __restrict__ selidx,
                                                     int* __restrict__ selmask) {
    int h = blockIdx.x >> 6;
    int i0 = (blockIdx.x & 63) * 32;
    int t = threadIdx.x;
    __shared__ float qs[64][68];
    __shared__ float sc[64][132];
    __shared__ float scratch[32 * 68];
    __shared__ float memk[64], memv[64];

    for (int idx = t; idx < 4096; idx += 256) {
        int row = idx >> 6, d = idx & 63;
        int g = row >> 5, qi = row & 31;
        qs[row][d] = qkv[(size_t)(i0 + qi) * 2048 + (h * 2 + g) * 64 + d];
    }
    if (t < 64) { memk[t] = memkv[h * 64 + t]; memv[t] = memkv[(8 + h) * 64 + t]; }
    __syncthreads();
    if (t < 64) {
        float s = 0.f;
        for (int d = 0; d < 64; d++) s += qs[t][d] * memk[d];
        sc[t][0] = s * SCALE;
    }
    int rg = t >> 3, kg = t & 7;
    for (int c = 0; c < 4; c++) {
        __syncthreads();
        for (int idx = t; idx < 2048; idx += 256) {
            int jj = idx >> 6, d = idx & 63;
            scratch[jj * 68 + d] = ckraw[((size_t)h * 128 + c * 32 + jj) * 64 + d];
        }
        __syncthreads();
        float a0[4] = {}, a1[4] = {};
        for (int d = 0; d < 64; d += 4) {
            float4 q0 = *(const float4*)&qs[rg * 2][d];
            float4 q1 = *(const float4*)&qs[rg * 2 + 1][d];
#pragma unroll
            for (int kk = 0; kk < 4; kk++) {
                float4 kv = *(const float4*)&scratch[(kg + kk * 8) * 68 + d];
                a0[kk] += q0.x * kv.x + q0.y * kv.y + q0.z * kv.z + q0.w * kv.w;
                a1[kk] += q1.x * kv.x + q1.y * kv.y + q1.z * kv.z + q1.w * kv.w;
            }
        }
#pragma unroll
        for (int kk = 0; kk < 4; kk++) {
            sc[rg * 2][1 + c * 32 + kg + kk * 8] = a0[kk] * SCALE;
            sc[rg * 2 + 1][1 + c * 32 + kg + kk * 8] = a1[kk] * SCALE;
        }
    }
    __syncthreads();
    for (int idx = t; idx < 2048; idx += 256) {
        int qi = idx >> 6, fb = idx & 63;
        float v = 0.25f * (sc[qi][1 + 2 * fb] + sc[qi][2 + 2 * fb] +
                           sc[32 + qi][1 + 2 * fb] + sc[32 + qi][2 + 2 * fb]);
        if (fb == ((i0 + qi) >> 5)) v = NEGF;
        scratch[qi * 66 + fb] = v;
    }
    __syncthreads();
    if (t < 32) {
        // importance softmax stats + fused top-k for query i0+t
        float* row = &scratch[t * 66];
        float m = -1000.f;
        for (int j = 0; j < 64; j++) m = fmaxf(m, row[j]);
        float den = __expf(-1000.f - m);
        for (int j = 0; j < 64; j++) den += __expf(row[j] - m);
        float invd = 1.f / den;
        unsigned long long taken = 0ull;
        int mk = 0;
        size_t base = ((size_t)h * NTOK + i0 + t) * 5;
        for (int p = 0; p < NSEL; p++) {
            float bv = NEGF;
            int bi = 0;
            for (int j = 0; j < 64; j++) {
                if (!((taken >> j) & 1ull) && row[j] > bv) { bv = row[j]; bi = j; }
            }
            taken |= 1ull << bi;
            selidx[base + p] = bi;
            if (__expf(bv - m) * invd > 1e-10f) mk |= 1 << p;
        }
        selidx[base + 4] = (i0 + t) >> 5;
        selmask[h * NTOK + i0 + t] = mk;
    } else if (t >= 64 && t < 128) {
        int r = t - 64;
        float m = NEGF;
        for (int j = 0; j < 129; j++) m = fmaxf(m, sc[r][j]);
        float den = 0.f;
        for (int j = 0; j < 129; j++) { float e = __expf(sc[r][j] - m); sc[r][j] = e; den += e; }
        float inv = 1.f / den;
        for (int j = 0; j < 129; j++) sc[r][j] *= inv;
    }
    __syncthreads();
    int dg = t & 7;
    float o0[8], o1[8];
    {
        float p0 = sc[rg * 2][0], p1 = sc[rg * 2 + 1][0];
#pragma unroll
        for (int dd = 0; dd < 8; dd++) {
            float v = memv[dg + dd * 8];
            o0[dd] = p0 * v;
            o1[dd] = p1 * v;
        }
    }
    for (int c = 0; c < 4; c++) {
        __syncthreads();
        for (int idx = t; idx < 2048; idx += 256) {
            int jj = idx >> 6, d = idx & 63;
            scratch[jj * 68 + d] = cvraw[((size_t)h * 128 + c * 32 + jj) * 64 + d];
        }
        __syncthreads();
        for (int jj = 0; jj < 32; jj++) {
            float p0 = sc[rg * 2][1 + c * 32 + jj];
            float p1 = sc[rg * 2 + 1][1 + c * 32 + jj];
#pragma unroll
            for (int dd = 0; dd < 8; dd++) {
                float v = scratch[jj * 68 + dg + dd * 8];
                o0[dd] += p0 * v;
                o1[dd] += p1 * v;
            }
        }
    }
    {
        int row = rg * 2;
        int g = row >> 5, qi = row & 31;
        int g2 = (row + 1) >> 5, qi2 = (row + 1) & 31;
#pragma unroll
        for (int dd = 0; dd < 8; dd++) {
            cout[(((size_t)(h * 2 + g)) * NTOK + i0 + qi) * 64 + dd * 8 + dg] = o0[dd];
            cout[(((size_t)(h * 2 + g2)) * NTOK + i0 + qi2) * 64 + dd * 8 + dg] = o1[dd];
        }
    }
}

// ---------------- Fused fine + sliding attention (bf16 K/V, wave per query) -------
__global__ __launch_bounds__(256) void attn_fused_kernel(const float* __restrict__ rq,
                                                         const __hip_bfloat16* __restrict__ rk,
                                                         const __hip_bfloat16* __restrict__ vt,
                                                         const int* __restrict__ selidx,
                                                         const int* __restrict__ selmask,
                                                         float* __restrict__ fout,
                                                         float* __restrict__ sout) {
    int ws = threadIdx.x >> 6, lane = threadIdx.x & 63;
    __shared__ float sp[4][2][160];
    __shared__ int sel[4][5];
    __shared__ int smk[4];
    float* p0 = sp[ws][0];
    float* p1 = sp[ws][1];

    int kq = lane >> 2, c = lane & 3;
    int kv8 = lane >> 3, c8 = lane & 7;

    if (blockIdx.x < 4096) {
        // ---------- fine attention ----------
        int wid = blockIdx.x * 4 + ws;
        int h = wid >> 11, i = wid & 2047;
        if (lane < 5) sel[ws][lane] = selidx[((size_t)h * NTOK + i) * 5 + lane];
        if (lane == 5) smk[ws] = selmask[h * NTOK + i];

        const float* q0p = rq + ((size_t)(h * 2 + 0) * NTOK + i) * 64 + c * 16;
        const float* q1p = rq + ((size_t)(h * 2 + 1) * NTOK + i) * 64 + c * 16;
        float4 q0[4], q1[4];
#pragma unroll
        for (int u = 0; u < 4; u++) {
            q0[u] = *(const float4*)(q0p + u * 4);
            q1[u] = *(const float4*)(q1p + u * 4);
        }
        __syncthreads();
        int mk = smk[ws];
        int iq = i & 31;
#pragma unroll
        for (int kt = 0; kt < 10; kt++) {
            int slot = kt >> 1;
            int blk = sel[ws][slot];
            int key = kt * 16 + kq;
            int jj = key & 31;
            int kpos = blk * 32 + jj;
            bool valid = (slot < 4) ? (((mk >> slot) & 1) != 0) : (jj <= iq);
            const __hip_bfloat16* kr = rk + ((size_t)h * NTOK + kpos) * 64 + c * 16;
            float s0 = 0.f, s1 = 0.f;
            uint4 a = *(const uint4*)(kr);
            uint4 b = *(const uint4*)(kr + 8);
            dot8(q0[0], q0[1], a, s0); dot8(q0[2], q0[3], b, s0);
            dot8(q1[0], q1[1], a, s1); dot8(q1[2], q1[3], b, s1);
            s0 += __shfl_xor(s0, 1); s0 += __shfl_xor(s0, 2);
            s1 += __shfl_xor(s1, 1); s1 += __shfl_xor(s1, 2);
            if (c == 0) {
                p0[key] = valid ? s0 * SCALE : NEG10F;
                p1[key] = valid ? s1 * SCALE : NEG10F;
            }
        }
        __syncthreads();
        {
            float a0 = p0[lane], b0 = p0[lane + 64];
            float c0 = (lane < 32) ? p0[lane + 128] : NEG10F;
            float a1 = p1[lane], b1 = p1[lane + 64];
            float c1 = (lane < 32) ? p1[lane + 128] : NEG10F;
            float m0 = fmaxf(fmaxf(a0, b0), c0);
            float m1 = fmaxf(fmaxf(a1, b1), c1);
#pragma unroll
            for (int o = 1; o < 64; o <<= 1) {
                m0 = fmaxf(m0, __shfl_xor(m0, o));
                m1 = fmaxf(m1, __shfl_xor(m1, o));
            }
            float ea0 = __expf(a0 - m0), eb0 = __expf(b0 - m0), ec0 = (lane < 32) ? __expf(c0 - m0) : 0.f;
            float ea1 = __expf(a1 - m1), eb1 = __expf(b1 - m1), ec1 = (lane < 32) ? __expf(c1 - m1) : 0.f;
            float d0 = ea0 + eb0 + ec0;
            float d1 = ea1 + eb1 + ec1;
#pragma unroll
            for (int o = 1; o < 64; o <<= 1) {
                d0 += __shfl_xor(d0, o);
                d1 += __shfl_xor(d1, o);
            }
            float inv0 = 1.f / d0, inv1 = 1.f / d1;
            p0[lane] = ea0 * inv0; p0[lane + 64] = eb0 * inv0;
            p1[lane] = ea1 * inv1; p1[lane + 64] = eb1 * inv1;
            if (lane < 32) { p0[lane + 128] = ec0 * inv0; p1[lane + 128] = ec1 * inv1; }
        }
        __syncthreads();
        float o0[8] = {}, o1[8] = {};
#pragma unroll
        for (int slot = 0; slot < 5; slot++) {
            const __hip_bfloat16* vbase = vt + ((size_t)h * NTOK + sel[ws][slot] * 32) * 64;
#pragma unroll
            for (int pass = 0; pass < 4; pass++) {
                int j = pass * 8 + kv8;
                uint4 v = *(const uint4*)(vbase + j * 64 + c8 * 8);
                float pa = p0[slot * 32 + j], pb = p1[slot * 32 + j];
                float e0 = bflo(v.x), e1 = bfhi(v.x), e2 = bflo(v.y), e3 = bfhi(v.y);
                float e4 = bflo(v.z), e5 = bfhi(v.z), e6 = bflo(v.w), e7 = bfhi(v.w);
                o0[0] = fmaf(pa, e0, o0[0]); o0[1] = fmaf(pa, e1, o0[1]);
                o0[2] = fmaf(pa, e2, o0[2]); o0[3] = fmaf(pa, e3, o0[3]);
                o0[4] = fmaf(pa, e4, o0[4]); o0[5] = fmaf(pa, e5, o0[5]);
                o0[6] = fmaf(pa, e6, o0[6]); o0[7] = fmaf(pa, e7, o0[7]);
                o1[0] = fmaf(pb, e0, o1[0]); o1[1] = fmaf(pb, e1, o1[1]);
                o1[2] = fmaf(pb, e2, o1[2]); o1[3] = fmaf(pb, e3, o1[3]);
                o1[4] = fmaf(pb, e4, o1[4]); o1[5] = fmaf(pb, e5, o1[5]);
                o1[6] = fmaf(pb, e6, o1[6]); o1[7] = fmaf(pb, e7, o1[7]);
            }
        }
#pragma unroll
        for (int o = 8; o <= 32; o <<= 1)
#pragma unroll
            for (int d = 0; d < 8; d++) {
                o0[d] += __shfl_xor(o0[d], o);
                o1[d] += __shfl_xor(o1[d], o);
            }
        if (kv8 == 0) {
            float* f0 = fout + ((size_t)(h * 2 + 0) * NTOK + i) * 64 + c8 * 8;
            float* f1 = fout + ((size_t)(h * 2 + 1) * NTOK + i) * 64 + c8 * 8;
            *(float4*)(f0) = (float4){o0[0], o0[1], o0[2], o0[3]};
            *(float4*)(f0 + 4) = (float4){o0[4], o0[5], o0[6], o0[7]};
            *(float4*)(f1) = (float4){o1[0], o1[1], o1[2], o1[3]};
            *(float4*)(f1 + 4) = (float4){o1[4], o1[5], o1[6], o1[7]};
        }
    } else {
        // ---------- sliding-window attention ----------
        int wid = (blockIdx.x - 4096) * 4 + ws;
        int h = wid >> 11, i = wid & 2047;
        const float* q0p = rq + ((size_t)(h * 2 + 0) * NTOK + i) * 64 + c * 16;
        const float* q1p = rq + ((size_t)(h * 2 + 1) * NTOK + i) * 64 + c * 16;
        float4 q0[4], q1[4];
#pragma unroll
        for (int u = 0; u < 4; u++) {
            q0[u] = *(const float4*)(q0p + u * 4);
            q1[u] = *(const float4*)(q1p + u * 4);
        }
#pragma unroll
        for (int kt = 0; kt < 4; kt++) {
            int key = kt * 16 + kq;
            int kpos = i - 63 + key;
            int kp = kpos < 0 ? 0 : kpos;
            const __hip_bfloat16* kr = rk + ((size_t)h * NTOK + kp) * 64 + c * 16;
            float s0 = 0.f, s1 = 0.f;
            uint4 a = *(const uint4*)(kr);
            uint4 b = *(const uint4*)(kr + 8);
            dot8(q0[0], q0[1], a, s0); dot8(q0[2], q0[3], b, s0);
            dot8(q1[0], q1[1], a, s1); dot8(q1[2], q1[3], b, s1);
            s0 += __shfl_xor(s0, 1); s0 += __shfl_xor(s0, 2);
            s1 += __shfl_xor(s1, 1); s1 += __shfl_xor(s1, 2);
            if (c == 0) {
                p0[key] = (kpos >= 0) ? s0 * SCALE : NEG10F;
                p1[key] = (kpos >= 0) ? s1 * SCALE : NEG10F;
            }
        }
        __syncthreads();
        {
            float a0 = p0[lane], a1 = p1[lane];
            float m0 = a0, m1 = a1;
#pragma unroll
            for (int o = 1; o < 64; o <<= 1) {
                m0 = fmaxf(m0, __shfl_xor(m0, o));
                m1 = fmaxf(m1, __shfl_xor(m1, o));
            }
            float e0 = __expf(a0 - m0), e1 = __expf(a1 - m1);
            float d0 = e0, d1 = e1;
#pragma unroll
            for (int o = 1; o < 64; o <<= 1) {
                d0 += __shfl_xor(d0, o);
                d1 += __shfl_xor(d1, o);
            }
            p0[lane] = e0 / d0;
            p1[lane] = e1 / d1;
        }
        __syncthreads();
        int base = i - 63;
        float o0[8] = {}, o1[8] = {};
        const __hip_bfloat16* vbase = vt + (size_t)h * NTOK * 64;
#pragma unroll
        for (int pass = 0; pass < 8; pass++) {
            int j = pass * 8 + kv8;
            int kpos = base + j;
            int kp = kpos < 0 ? 0 : kpos;
            uint4 v = *(const uint4*)(vbase + (size_t)kp * 64 + c8 * 8);
            float pa = p0[j], pb = p1[j];
            float e0 = bflo(v.x), e1 = bfhi(v.x), e2 = bflo(v.y), e3 = bfhi(v.y);
            float e4 = bflo(v.z), e5 = bfhi(v.z), e6 = bflo(v.w), e7 = bfhi(v.w);
            o0[0] = fmaf(pa, e0, o0[0]); o0[1] = fmaf(pa, e1, o0[1]);
            o0[2] = fmaf(pa, e2, o0[2]); o0[3] = fmaf(pa, e3, o0[3]);
            o0[4] = fmaf(pa, e4, o0[4]); o0[5] = fmaf(pa, e5, o0[5]);
            o0[6] = fmaf(pa, e6, o0[6]); o0[7] = fmaf(pa, e7, o0[7]);
            o1[0] = fmaf(pb, e0, o1[0]); o1[1] = fmaf(pb, e1, o1[1]);
            o1[2] = fmaf(pb, e2, o1[2]); o1[3] = fmaf(pb, e3, o1[3]);
            o1[4] = fmaf(pb, e4, o1[4]); o1[5] = fmaf(pb, e5, o1[5]);
            o1[6] = fmaf(pb, e6, o1[6]); o1[7] = fmaf(pb, e7, o1[7]);
        }
#pragma unroll
        for (int o = 8; o <= 32; o <<= 1)
#pragma unroll
            for (int d = 0; d < 8; d++) {
                o0[d] += __shfl_xor(o0[d], o);
                o1[d] += __shfl_xor(o1[d], o);
            }
        if (kv8 == 0) {
            float* s0p = sout + ((size_t)(h * 2 + 0) * NTOK + i) * 64 + c8 * 8;
            float* s1p = sout + ((size_t)(h * 2 + 1) * NTOK + i) * 64 + c8 * 8;
            *(float4*)(s0p) = (float4){o0[0], o0[1], o0[2], o0[3]};
            *(float4*)(s0p + 4) = (float4){o0[4], o0[5], o0[6], o0[7]};
            *(float4*)(s1p) = (float4){o1[0], o1[1], o1[2], o1[3]};
            *(float4*)(s1p + 4) = (float4){o1[4], o1[5], o1[6], o1[7]};
        }
    }
}

// ---------------- Gated combine (sigmoid applied here; writes bf16) ----------------
__global__ __launch_bounds__(256) void combine_kernel(const float* __restrict__ gateslin,
                                                      const float* __restrict__ cout,
                                                      const float* __restrict__ fout,
                                                      const float* __restrict__ sout,
                                                      __hip_bfloat16* __restrict__ att) {
    int n = blockIdx.x;
    for (int c = threadIdx.x; c < NH * HD; c += 256) {
        int hd = c >> 6, d = c & 63;
        float g0 = 1.f / (1.f + expf(-gateslin[(size_t)n * (NH * 3) + hd * 3 + 0]));
        float g1 = 1.f / (1.f + expf(-gateslin[(size_t)n * (NH * 3) + hd * 3 + 1]));
        float g2 = 1.f / (1.f + expf(-gateslin[(size_t)n * (NH * 3) + hd * 3 + 2]));
        size_t o = ((size_t)hd * NTOK + n) * HD + d;
        att[(size_t)n * (NH * HD) + c] =
            __float2bfloat16(g0 * cout[o] + g1 * fout[o] + g2 * sout[o]);
    }
}

extern "C" void kernel_launch(void* const* d_in, const int* in_sizes, int n_in,
                              void* d_out, int out_size, void* d_ws, size_t ws_size,
                              hipStream_t stream) {
    const float* inp    = (const float*)d_in[0];
    const float* norm_g = (const float*)d_in[1];
    const float* Wqkv   = (const float*)d_in[2];
    const float* mem_kv = (const float*)d_in[3];
    const float* k_pos  = (const float*)d_in[4];
    const float* v_pos  = (const float*)d_in[5];
    const float* kW1    = (const float*)d_in[6];
    const float* kb1    = (const float*)d_in[7];
    const float* kW2    = (const float*)d_in[8];
    const float* kb2    = (const float*)d_in[9];
    const float* vW1    = (const float*)d_in[10];
    const float* vb1    = (const float*)d_in[11];
    const float* vW2    = (const float*)d_in[12];
    const float* vb2    = (const float*)d_in[13];
    const float* combW  = (const float*)d_in[14];
    const float* combB  = (const float*)d_in[15];
    const float* Wout   = (const float*)d_in[16];
    float* out = (float*)d_out;

    char* base = (char*)d_ws;
    size_t off = 0;
    auto alloc = [&](size_t bytes) {
        void* p = base + off;
        off += (bytes + 255) & ~(size_t)255;
        return p;
    };
    float* x            = (float*)alloc((size_t)NTOK * DIM * 4);
    __hip_bfloat16* xb  = (__hip_bfloat16*)alloc((size_t)NTOK * DIM * 2);
    float* qkv          = (float*)alloc((size_t)NTOK * 2048 * 4);
    __hip_bfloat16* Wqkvt = (__hip_bfloat16*)alloc((size_t)2048 * 1024 * 2);
    __hip_bfloat16* kW1t  = (__hip_bfloat16*)alloc((size_t)2048 * 2048 * 2);
    __hip_bfloat16* vW1t  = (__hip_bfloat16*)alloc((size_t)2048 * 2048 * 2);
    __hip_bfloat16* Woutt = (__hip_bfloat16*)alloc((size_t)1024 * 1024 * 2);
    __hip_bfloat16* combWt = (__hip_bfloat16*)alloc((size_t)48 * 1024 * 2);
    __hip_bfloat16* kW2t  = (__hip_bfloat16*)alloc((size_t)64 * 2048 * 2);
    __hip_bfloat16* vW2t  = (__hip_bfloat16*)alloc((size_t)64 * 2048 * 2);
    __hip_bfloat16* kwflat = (__hip_bfloat16*)alloc((size_t)KVH * NCB * HIDN * 2);
    __hip_bfloat16* vwflat = (__hip_bfloat16*)alloc((size_t)KVH * NCB * HIDN * 2);
    __hip_bfloat16* hidkb = (__hip_bfloat16*)alloc((size_t)KVH * NCB * HIDN * 2);
    __hip_bfloat16* hidvb = (__hip_bfloat16*)alloc((size_t)KVH * NCB * HIDN * 2);
    float* ckraw        = (float*)alloc((size_t)KVH * NCB * HD * 4);
    float* cvraw        = (float*)alloc((size_t)KVH * NCB * HD * 4);
    float* rq           = (float*)alloc((size_t)NH * NTOK * HD * 4);
    __hip_bfloat16* rk  = (__hip_bfloat16*)alloc((size_t)KVH * NTOK * HD * 2);
    __hip_bfloat16* vt  = (__hip_bfloat16*)alloc((size_t)KVH * NTOK * HD * 2);
    float* coutb        = (float*)alloc((size_t)NH * NTOK * HD * 4);
    float* foutb        = (float*)alloc((size_t)NH * NTOK * HD * 4);
    float* soutb        = (float*)alloc((size_t)NH * NTOK * HD * 4);
    float* gatesb       = (float*)alloc((size_t)NTOK * NH * 3 * 4);
    __hip_bfloat16* attb = (__hip_bfloat16*)alloc((size_t)NTOK * DIM * 2);
    int* selidx         = (int*)alloc((size_t)KVH * NTOK * 5 * 4);
    int* selmask        = (int*)alloc((size_t)KVH * NTOK * 4);
    (void)ws_size; (void)in_sizes; (void)n_in; (void)out_size;

    // 1. RMSNorm (fp32 + bf16)
    rmsnorm_kernel<<<NTOK, 256, 0, stream>>>(inp, norm_g, x, xb);
    // 2. merged transpose-cast of all weights to bf16 NxK
    transpose_all_kernel<<<11584, 256, 0, stream>>>(Wqkv, Wqkvt, kW1, kW1t, vW1, vW1t,
                                                    Wout, Woutt, combW, combWt,
                                                    kW2, kW2t, vW2, vW2t);
    // 3. qkv = x @ Wqkv  (MFMA, async staging)
    mfma_gemm<0, 0><<<dim3(16, 16), 256, 0, stream>>>(xb, Wqkvt, nullptr, qkv, 2048, 2048, 1024);
    // 4. gates linear = x @ combW + combB  (split-K MFMA, sigmoid in combine)
    initbias_kernel<<<(NTOK * 48 + 255) / 256, 256, 0, stream>>>(gatesb, combB, NTOK, 48);
    skgemm_kernel<<<dim3(1, 16, 4), 256, 0, stream>>>(xb, combWt, gatesb, 2048, 48, 1024);
    // 5. build compressed windows (bf16)
    buildwin_kernel<<<4096, 256, 0, stream>>>(qkv, k_pos, v_pos, kwflat, vwflat);
    // 6. compressed k/v MLP layer 1 (batched: 256 blocks)
    mfma_gemm_pair<<<dim3(16, 8, 2), 256, 0, stream>>>(kwflat, vwflat, kW1t, vW1t,
                                                       kb1, vb1, hidkb, hidvb,
                                                       1024, 2048, 2048);
    // 7. compressed k/v MLP layer 2 (batched split-K)
    initbias2_kernel<<<(2 * 1024 * 64 + 255) / 256, 256, 0, stream>>>(ckraw, kb2, cvraw, vb2, 1024, 64);
    skgemm_pair<<<dim3(2, 8, 8), 256, 0, stream>>>(hidkb, hidvb, kW2t, vW2t,
                                                   ckraw, cvraw, 1024, 64, 2048);
    // 8. RoPE + transposes (rk/vt bf16)
    rope_kernel<<<NTOK, 256, 0, stream>>>(qkv, rq, rk, vt);
    // 9. compressed attention + importance + fused top-k
    cattn2_kernel<<<KVH * (NTOK / 32), 256, 0, stream>>>(qkv, ckraw, cvraw, mem_kv,
                                                         coutb, selidx, selmask);
    // 10+11. fused fine + sliding attention
    attn_fused_kernel<<<8192, 256, 0, stream>>>(rq, rk, vt, selidx, selmask, foutb, soutb);
    // 12. gated combine (sigmoid here, bf16 out)
    combine_kernel<<<NTOK, 256, 0, stream>>>(gatesb, coutb, foutb, soutb, attb);
    // 13. out projection (MFMA)
    mfma_gemm<0, 0><<<dim3(8, 16), 256, 0, stream>>>(attb, Woutt, nullptr, out, 2048, 1024, 1024);
}

// Round 8
// 379.545 us; speedup vs baseline: 8.0917x; 1.0851x over previous
//
#include <hip/hip_runtime.h>
#include <hip/hip_bf16.h>

// Problem constants
#define NTOK 2048
#define DIM 1024
#define NH 16
#define KVH 8
#define GQ 2
#define HD 64
#define WS 64
#define CBS 32
#define STRIDE 16
#define SEL_BLK 32
#define NSEL 4
#define NMEM 1
#define NCB 128          // N/STRIDE
#define NFB 64           // N/SEL_BLK
#define HIDN 2048        // CBS*D
#define SCALE 0.125f
#define NEGF (-3.4028234663852886e38f)
#define NEG10F (-3.4028234663852886e37f)

typedef __attribute__((ext_vector_type(8))) short bf16x8;
typedef __attribute__((ext_vector_type(4))) float f32x4;

__device__ __forceinline__ float bflo(unsigned u) { return __uint_as_float(u << 16); }
__device__ __forceinline__ float bfhi(unsigned u) { return __uint_as_float(u & 0xffff0000u); }
__device__ __forceinline__ void dot8(const float4& qa, const float4& qb, uint4 a, float& s) {
    s += qa.x * bflo(a.x) + qa.y * bfhi(a.x) + qa.z * bflo(a.y) + qa.w * bfhi(a.y) +
         qb.x * bflo(a.z) + qb.y * bfhi(a.z) + qb.z * bflo(a.w) + qb.w * bfhi(a.w);
}

// async 16B global -> LDS (LDS dest must be wave-uniform base + lane*16)
__device__ __forceinline__ void gload_lds16(const void* g, void* l) {
    __builtin_amdgcn_global_load_lds((const __attribute__((address_space(1))) unsigned*)g,
                                     (__attribute__((address_space(3))) unsigned*)l, 16, 0, 0);
}

// ---------------- RMSNorm body ----------------
__device__ __forceinline__ void rms_body(const float* __restrict__ inp,
                                         const float* __restrict__ g,
                                         float* __restrict__ x,
                                         __hip_bfloat16* __restrict__ xb, int n) {
    const float* row = inp + (size_t)n * DIM;
    float ss = 0.f;
    for (int c = threadIdx.x; c < DIM; c += 256) { float v = row[c]; ss += v * v; }
    __shared__ float red[4];
    for (int o = 32; o; o >>= 1) ss += __shfl_down(ss, o, 64);
    if ((threadIdx.x & 63) == 0) red[threadIdx.x >> 6] = ss;
    __syncthreads();
    if (threadIdx.x == 0) red[0] = red[0] + red[1] + red[2] + red[3];
    __syncthreads();
    float rs = 1.0f / sqrtf(red[0] / (float)DIM + 1.1920928955078125e-07f);
    float* xr = x + (size_t)n * DIM;
    __hip_bfloat16* xbr = xb + (size_t)n * DIM;
    for (int c = threadIdx.x; c < DIM; c += 256) {
        float v = row[c] * rs * g[c];
        xr[c] = v;
        xbr[c] = __float2bfloat16(v);
    }
}

// ---------------- transpose body ----------------
__device__ __forceinline__ void transpose_body(const float* __restrict__ B,
                                               __hip_bfloat16* __restrict__ Bt,
                                               int K, int N, int bx, int by) {
    __shared__ float tile[32][33];
    int n0 = bx * 32, k0 = by * 32;
    int x = threadIdx.x & 31, y = threadIdx.x >> 5;
    for (int i = 0; i < 4; i++) {
        int k = k0 + y + 8 * i, n = n0 + x;
        tile[y + 8 * i][x] = (k < K && n < N) ? B[(size_t)k * N + n] : 0.f;
    }
    __syncthreads();
    for (int i = 0; i < 4; i++) {
        int n = n0 + y + 8 * i, k = k0 + x;
        if (n < N && k < K) Bt[(size_t)n * K + k] = __float2bfloat16(tile[x][y + 8 * i]);
    }
}

// ---------------- pre: rmsnorm + all transposes + bias inits ----------------
__global__ __launch_bounds__(256) void pre_kernel(
    const float* inp, const float* norm_g, float* x, __hip_bfloat16* xb,
    const float* Wqkv, __hip_bfloat16* Wqkvt,
    const float* kW1, __hip_bfloat16* kW1t,
    const float* vW1, __hip_bfloat16* vW1t,
    const float* Wout, __hip_bfloat16* Woutt,
    const float* combW, __hip_bfloat16* combWt,
    const float* kW2, __hip_bfloat16* kW2t,
    const float* vW2, __hip_bfloat16* vW2t,
    const float* combB, float* gatesb,
    const float* kb2, float* ckraw,
    const float* vb2, float* cvraw) {
    int b = blockIdx.x;
    if (b < 2048) { rms_body(inp, norm_g, x, xb, b); return; }
    b -= 2048;
    if (b < 2048) { transpose_body(Wqkv, Wqkvt, 1024, 2048, b % 64, b / 64); return; }
    b -= 2048;
    if (b < 4096) { transpose_body(kW1, kW1t, 2048, 2048, b % 64, b / 64); return; }
    b -= 4096;
    if (b < 4096) { transpose_body(vW1, vW1t, 2048, 2048, b % 64, b / 64); return; }
    b -= 4096;
    if (b < 1024) { transpose_body(Wout, Woutt, 1024, 1024, b % 32, b / 32); return; }
    b -= 1024;
    if (b < 64) { transpose_body(combW, combWt, 1024, 48, b % 2, b / 2); return; }
    b -= 64;
    if (b < 128) { transpose_body(kW2, kW2t, 2048, 64, b % 2, b / 2); return; }
    b -= 128;
    if (b < 128) { transpose_body(vW2, vW2t, 2048, 64, b % 2, b / 2); return; }
    b -= 128;
    if (b < 384) {  // gates bias init: 2048*48
        int idx = b * 256 + threadIdx.x;
        if (idx < 2048 * 48) gatesb[idx] = combB[idx % 48];
        return;
    }
    b -= 384;
    {   // ck/cv bias init: 2*1024*64
        int idx = b * 256 + threadIdx.x;
        int tot = 1024 * 64;
        if (idx < tot) ckraw[idx] = kb2[idx % 64];
        else if (idx < 2 * tot) { idx -= tot; cvraw[idx] = vb2[idx % 64]; }
        return;
    }
}
#define PRE_BLOCKS (2048 + 2048 + 4096 + 4096 + 1024 + 64 + 128 + 128 + 384 + 512)

// ---------------- bf16 MFMA GEMM body (global_load_lds staging) ----------------
template <int ACT, int OUTBF16>
__device__ __forceinline__ void mfma_gemm_body(const __hip_bfloat16* __restrict__ A,
                                               const __hip_bfloat16* __restrict__ Bt,
                                               const float* __restrict__ bias,
                                               void* __restrict__ Cp,
                                               int M, int N, int K, int bx, int by) {
    __shared__ __align__(16) short As[128 * 32];
    __shared__ __align__(16) short Bs[128 * 32];
    int tid = threadIdx.x;
    int lane = tid & 63, wave = tid >> 6;
    int wm = (wave >> 1) * 64, wn = (wave & 1) * 64;
    int m0 = by * 128, n0 = bx * 128;
    f32x4 acc[4][4];
    for (int r = 0; r < 4; r++)
        for (int c = 0; c < 4; c++)
            acc[r][c] = (f32x4){0.f, 0.f, 0.f, 0.f};

    int r0 = tid >> 2, kc0 = (tid & 3) * 8;
    int r1 = r0 + 64;

    for (int k0 = 0; k0 < K; k0 += 32) {
        __syncthreads();
        gload_lds16(A + (size_t)(m0 + r0) * K + k0 + kc0, &As[r0 * 32 + kc0]);
        gload_lds16(A + (size_t)(m0 + r1) * K + k0 + kc0, &As[r1 * 32 + kc0]);
        gload_lds16(Bt + (size_t)(n0 + r0) * K + k0 + kc0, &Bs[r0 * 32 + kc0]);
        gload_lds16(Bt + (size_t)(n0 + r1) * K + k0 + kc0, &Bs[r1 * 32 + kc0]);
        __syncthreads();
        bf16x8 af[4], bfr[4];
#pragma unroll
        for (int r = 0; r < 4; r++)
            af[r] = *(const bf16x8*)&As[(wm + r * 16 + (lane & 15)) * 32 + (lane >> 4) * 8];
#pragma unroll
        for (int c = 0; c < 4; c++)
            bfr[c] = *(const bf16x8*)&Bs[(wn + c * 16 + (lane & 15)) * 32 + (lane >> 4) * 8];
#pragma unroll
        for (int r = 0; r < 4; r++)
#pragma unroll
            for (int c = 0; c < 4; c++)
                acc[r][c] = __builtin_amdgcn_mfma_f32_16x16x32_bf16(af[r], bfr[c], acc[r][c], 0, 0, 0);
    }
    for (int r = 0; r < 4; r++) {
        int grow = m0 + wm + r * 16 + (lane >> 4) * 4;
        for (int c = 0; c < 4; c++) {
            int gcol = n0 + wn + c * 16 + (lane & 15);
            float bv = bias ? bias[gcol] : 0.f;
#pragma unroll
            for (int v = 0; v < 4; v++) {
                float val = acc[r][c][v] + bv;
                if (ACT == 1) val = fmaxf(val, 0.f);
                if (OUTBF16)
                    ((__hip_bfloat16*)Cp)[(size_t)(grow + v) * N + gcol] = __float2bfloat16(val);
                else
                    ((float*)Cp)[(size_t)(grow + v) * N + gcol] = val;
            }
        }
    }
}

template <int ACT, int OUTBF16>
__global__ __launch_bounds__(256) void mfma_gemm(const __hip_bfloat16* __restrict__ A,
                                                 const __hip_bfloat16* __restrict__ Bt,
                                                 const float* __restrict__ bias,
                                                 void* __restrict__ Cp,
                                                 int M, int N, int K) {
    mfma_gemm_body<ACT, OUTBF16>(A, Bt, bias, Cp, M, N, K, blockIdx.x, blockIdx.y);
}

__global__ __launch_bounds__(256) void mfma_gemm_pair(const __hip_bfloat16* A0,
                                                      const __hip_bfloat16* A1,
                                                      const __hip_bfloat16* Bt0,
                                                      const __hip_bfloat16* Bt1,
                                                      const float* bias0, const float* bias1,
                                                      __hip_bfloat16* C0, __hip_bfloat16* C1,
                                                      int M, int N, int K) {
    if (blockIdx.z == 0)
        mfma_gemm_body<1, 1>(A0, Bt0, bias0, C0, M, N, K, blockIdx.x, blockIdx.y);
    else
        mfma_gemm_body<1, 1>(A1, Bt1, bias1, C1, M, N, K, blockIdx.x, blockIdx.y);
}

// ---------------- Split-K skinny MFMA GEMM body: C += A @ Bt^T (atomicAdd) ----------
__device__ __forceinline__ void skgemm_body(const __hip_bfloat16* __restrict__ A,
                                            const __hip_bfloat16* __restrict__ Bt,
                                            float* __restrict__ C,
                                            int M, int Nout, int K, int by, int bz, int nz) {
    __shared__ __align__(16) short As2[128 * 32];
    __shared__ __align__(16) short Bs2[64 * 32];
    int tid = threadIdx.x;
    int lane = tid & 63, wave = tid >> 6;
    int m0 = by * 128;
    int wm = wave * 32;
    int kchunk = K / nz;
    int kbase = bz * kchunk;
    f32x4 acc[2][4];
    for (int r = 0; r < 2; r++)
        for (int c = 0; c < 4; c++) acc[r][c] = (f32x4){0.f, 0.f, 0.f, 0.f};

    int ra = tid >> 2, kc = (tid & 3) * 8;
    int rb = ra < Nout ? ra : Nout - 1;
    for (int k0 = kbase; k0 < kbase + kchunk; k0 += 32) {
        __syncthreads();
        gload_lds16(A + (size_t)(m0 + ra) * K + k0 + kc, &As2[ra * 32 + kc]);
        gload_lds16(A + (size_t)(m0 + ra + 64) * K + k0 + kc, &As2[(ra + 64) * 32 + kc]);
        gload_lds16(Bt + (size_t)rb * K + k0 + kc, &Bs2[ra * 32 + kc]);
        __syncthreads();
        bf16x8 af[2], bfr[4];
#pragma unroll
        for (int r = 0; r < 2; r++)
            af[r] = *(const bf16x8*)&As2[(wm + r * 16 + (lane & 15)) * 32 + (lane >> 4) * 8];
#pragma unroll
        for (int c = 0; c < 4; c++)
            bfr[c] = *(const bf16x8*)&Bs2[(c * 16 + (lane & 15)) * 32 + (lane >> 4) * 8];
#pragma unroll
        for (int r = 0; r < 2; r++)
#pragma unroll
            for (int c = 0; c < 4; c++)
                acc[r][c] = __builtin_amdgcn_mfma_f32_16x16x32_bf16(af[r], bfr[c], acc[r][c], 0, 0, 0);
    }
    for (int r = 0; r < 2; r++) {
        int grow = m0 + wm + r * 16 + (lane >> 4) * 4;
        for (int c = 0; c < 4; c++) {
            int gcol = c * 16 + (lane & 15);
            if (gcol >= Nout) continue;
#pragma unroll
            for (int v = 0; v < 4; v++)
                atomicAdd(&C[(size_t)(grow + v) * Nout + gcol], acc[r][c][v]);
        }
    }
}

// ---------------- qkv GEMM + gates split-K in one launch ----------------
__global__ __launch_bounds__(256) void qkv_gates_kernel(const __hip_bfloat16* xb,
                                                        const __hip_bfloat16* Wqkvt,
                                                        float* qkv,
                                                        const __hip_bfloat16* combWt,
                                                        float* gatesb) {
    int b = blockIdx.x;
    if (b < 256) {
        mfma_gemm_body<0, 0>(xb, Wqkvt, nullptr, qkv, 2048, 2048, 1024, b & 15, b >> 4);
    } else {
        int s = b - 256;  // 64 blocks: by = s&15, bz = s>>4 (nz=4)
        skgemm_body(xb, combWt, gatesb, 2048, 48, 1024, s & 15, s >> 4, 4);
    }
}

__global__ __launch_bounds__(256) void skgemm_pair(const __hip_bfloat16* A0,
                                                   const __hip_bfloat16* A1,
                                                   const __hip_bfloat16* Bt0,
                                                   const __hip_bfloat16* Bt1,
                                                   float* C0, float* C1,
                                                   int M, int Nout, int K) {
    if (blockIdx.x == 0)
        skgemm_body(A0, Bt0, C0, M, Nout, K, blockIdx.y, blockIdx.z, gridDim.z);
    else
        skgemm_body(A1, Bt1, C1, M, Nout, K, blockIdx.y, blockIdx.z, gridDim.z);
}

// ---------------- buildwin + rope fused ----------------
__global__ __launch_bounds__(256) void winrope_kernel(const float* __restrict__ qkv,
                                                      const float* __restrict__ k_pos,
                                                      const float* __restrict__ v_pos,
                                                      __hip_bfloat16* __restrict__ kwflat,
                                                      __hip_bfloat16* __restrict__ vwflat,
                                                      float* __restrict__ rq,
                                                      __hip_bfloat16* __restrict__ rk,
                                                      __hip_bfloat16* __restrict__ vt) {
    int b = blockIdx.x;
    int t = threadIdx.x;
    if (b < 4096) {
        size_t total = (size_t)(KVH * NCB) * HIDN;
        for (size_t e = (size_t)b * 256 + t; e < total; e += (size_t)4096 * 256) {
            int r = (int)(e >> 11);
            int c = (int)(e & 2047);
            int j = c >> 6, d = c & 63;
            int h = r >> 7, i = r & 127;
            int p = i * STRIDE + j - (CBS - STRIDE);
            float kb = k_pos[((size_t)h * CBS + j) * HD + d];
            float vb = v_pos[((size_t)h * CBS + j) * HD + d];
            float kv = 0.f, vv = 0.f;
            if (p >= 0) {
                kv = qkv[(size_t)p * 2048 + 1024 + h * HD + d];
                vv = qkv[(size_t)p * 2048 + 1536 + h * HD + d];
            }
            kwflat[e] = __float2bfloat16(kv + kb);
            vwflat[e] = __float2bfloat16(vv + vb);
        }
        return;
    }
    int n = b - 4096;
    for (int idx = t; idx < NH * 32; idx += 256) {
        int h = idx >> 5, f = idx & 31;
        float inv = exp2f((float)f * -0.41524101186092f);
        float ang = (float)n * inv;
        float cc = cosf(ang), ssn = sinf(ang);
        float a = qkv[(size_t)n * 2048 + h * HD + 2 * f];
        float bq = qkv[(size_t)n * 2048 + h * HD + 2 * f + 1];
        float* o = rq + ((size_t)h * NTOK + n) * HD + 2 * f;
        o[0] = a * cc - bq * ssn;
        o[1] = bq * cc + a * ssn;
    }
    for (int idx = t; idx < KVH * 32; idx += 256) {
        int h = idx >> 5, f = idx & 31;
        float inv = exp2f((float)f * -0.41524101186092f);
        float ang = (float)n * inv;
        float cc = cosf(ang), ssn = sinf(ang);
        float a = qkv[(size_t)n * 2048 + 1024 + h * HD + 2 * f];
        float bq = qkv[(size_t)n * 2048 + 1024 + h * HD + 2 * f + 1];
        __hip_bfloat16* o = rk + ((size_t)h * NTOK + n) * HD + 2 * f;
        o[0] = __float2bfloat16(a * cc - bq * ssn);
        o[1] = __float2bfloat16(bq * cc + a * ssn);
    }
    for (int idx = t; idx < KVH * HD; idx += 256) {
        int h = idx >> 6, d = idx & 63;
        vt[((size_t)h * NTOK + n) * HD + d] =
            __float2bfloat16(qkv[(size_t)n * 2048 + 1536 + h * HD + d]);
    }
}

// ---------------- Compressed attention + importance + fused top-k ----------------
__global__ __launch_bounds__(256) void cattn2_kernel(const float* __restrict__ qkv,
                                                     const float* __restrict__ ckraw,
                                                     const float* __restrict__ cvraw,
                                                     const float* __restrict__ memkv,
                                                     float* __restrict__ cout,
                                                     int* __restrict__ selidx,
                                                     int* __restrict__ selmask) {
    int h = blockIdx.x >> 6;
    int i0 = (blockIdx.x & 63) * 32;
    int t = threadIdx.x;
    __shared__ float qs[64][68];
    __shared__ float sc[64][132];
    __shared__ float scratch[32 * 68];
    __shared__ float memk[64], memv[64];

    for (int idx = t; idx < 4096; idx += 256) {
        int row = idx >> 6, d = idx & 63;
        int g = row >> 5, qi = row & 31;
        qs[row][d] = qkv[(size_t)(i0 + qi) * 2048 + (h * 2 + g) * 64 + d];
    }
    if (t < 64) { memk[t] = memkv[h * 64 + t]; memv[t] = memkv[(8 + h) * 64 + t]; }
    __syncthreads();
    if (t < 64) {
        float s = 0.f;
        for (int d = 0; d < 64; d++) s += qs[t][d] * memk[d];
        sc[t][0] = s * SCALE;
    }
    int rg = t >> 3, kg = t & 7;
    for (int c = 0; c < 4; c++) {
        __syncthreads();
        for (int idx = t; idx < 2048; idx += 256) {
            int jj = idx >> 6, d = idx & 63;
            scratch[jj * 68 + d] = ckraw[((size_t)h * 128 + c * 32 + jj) * 64 + d];
        }
        __syncthreads();
        float a0[4] = {}, a1[4] = {};
        for (int d = 0; d < 64; d += 4) {
            float4 q0 = *(const float4*)&qs[rg * 2][d];
            float4 q1 = *(const float4*)&qs[rg * 2 + 1][d];
#pragma unroll
            for (int kk = 0; kk < 4; kk++) {
                float4 kv = *(const float4*)&scratch[(kg + kk * 8) * 68 + d];
                a0[kk] += q0.x * kv.x + q0.y * kv.y + q0.z * kv.z + q0.w * kv.w;
                a1[kk] += q1.x * kv.x + q1.y * kv.y + q1.z * kv.z + q1.w * kv.w;
            }
        }
#pragma unroll
        for (int kk = 0; kk < 4; kk++) {
            sc[rg * 2][1 + c * 32 + kg + kk * 8] = a0[kk] * SCALE;
            sc[rg * 2 + 1][1 + c * 32 + kg + kk * 8] = a1[kk] * SCALE;
        }
    }
    __syncthreads();
    for (int idx = t; idx < 2048; idx += 256) {
        int qi = idx >> 6, fb = idx & 63;
        float v = 0.25f * (sc[qi][1 + 2 * fb] + sc[qi][2 + 2 * fb] +
                           sc[32 + qi][1 + 2 * fb] + sc[32 + qi][2 + 2 * fb]);
        if (fb == ((i0 + qi) >> 5)) v = NEGF;
        scratch[qi * 66 + fb] = v;
    }
    __syncthreads();
    if (t < 32) {
        float* row = &scratch[t * 66];
        float m = -1000.f;
        for (int j = 0; j < 64; j++) m = fmaxf(m, row[j]);
        float den = __expf(-1000.f - m);
        for (int j = 0; j < 64; j++) den += __expf(row[j] - m);
        float invd = 1.f / den;
        unsigned long long taken = 0ull;
        int mk = 0;
        size_t base = ((size_t)h * NTOK + i0 + t) * 5;
        for (int p = 0; p < NSEL; p++) {
            float bv = NEGF;
            int bi = 0;
            for (int j = 0; j < 64; j++) {
                if (!((taken >> j) & 1ull) && row[j] > bv) { bv = row[j]; bi = j; }
            }
            taken |= 1ull << bi;
            selidx[base + p] = bi;
            if (__expf(bv - m) * invd > 1e-10f) mk |= 1 << p;
        }
        selidx[base + 4] = (i0 + t) >> 5;
        selmask[h * NTOK + i0 + t] = mk;
    } else if (t >= 64 && t < 128) {
        int r = t - 64;
        float m = NEGF;
        for (int j = 0; j < 129; j++) m = fmaxf(m, sc[r][j]);
        float den = 0.f;
        for (int j = 0; j < 129; j++) { float e = __expf(sc[r][j] - m); sc[r][j] = e; den += e; }
        float inv = 1.f / den;
        for (int j = 0; j < 129; j++) sc[r][j] *= inv;
    }
    __syncthreads();
    int dg = t & 7;
    float o0[8], o1[8];
    {
        float p0 = sc[rg * 2][0], p1 = sc[rg * 2 + 1][0];
#pragma unroll
        for (int dd = 0; dd < 8; dd++) {
            float v = memv[dg + dd * 8];
            o0[dd] = p0 * v;
            o1[dd] = p1 * v;
        }
    }
    for (int c = 0; c < 4; c++) {
        __syncthreads();
        for (int idx = t; idx < 2048; idx += 256) {
            int jj = idx >> 6, d = idx & 63;
            scratch[jj * 68 + d] = cvraw[((size_t)h * 128 + c * 32 + jj) * 64 + d];
        }
        __syncthreads();
        for (int jj = 0; jj < 32; jj++) {
            float p0 = sc[rg * 2][1 + c * 32 + jj];
            float p1 = sc[rg * 2 + 1][1 + c * 32 + jj];
#pragma unroll
            for (int dd = 0; dd < 8; dd++) {
                float v = scratch[jj * 68 + dg + dd * 8];
                o0[dd] += p0 * v;
                o1[dd] += p1 * v;
            }
        }
    }
    {
        int row = rg * 2;
        int g = row >> 5, qi = row & 31;
        int g2 = (row + 1) >> 5, qi2 = (row + 1) & 31;
#pragma unroll
        for (int dd = 0; dd < 8; dd++) {
            cout[(((size_t)(h * 2 + g)) * NTOK + i0 + qi) * 64 + dd * 8 + dg] = o0[dd];
            cout[(((size_t)(h * 2 + g2)) * NTOK + i0 + qi2) * 64 + dd * 8 + dg] = o1[dd];
        }
    }
}

// ---------------- Fused attention: blocks [0,256) tiled sliding, [256,4352) fine ----
#define SWROWPAD 72   // shorts per K/V row in LDS (144 B: 16B-aligned, bank-rotated)
__global__ __launch_bounds__(256) void attn_fused2_kernel(const float* __restrict__ rq,
                                                          const __hip_bfloat16* __restrict__ rk,
                                                          const __hip_bfloat16* __restrict__ vt,
                                                          const int* __restrict__ selidx,
                                                          const int* __restrict__ selmask,
                                                          float* __restrict__ fout,
                                                          float* __restrict__ sout) {
    int tid = threadIdx.x;
    int ws = tid >> 6, lane = tid & 63;
    __shared__ __align__(16) char smem[2 * 128 * SWROWPAD * 2 + 4 * 128 * 4];  // 38912 B
    __shared__ int sel[4][5];
    __shared__ int smk[4];

    int kq = lane >> 2, c = lane & 3;
    int kv8 = lane >> 3, c8 = lane & 7;

    if (blockIdx.x < 256) {
        // ---------- tiled sliding-window: h, 64-query tile ----------
        int h = blockIdx.x >> 5;
        int q0 = (blockIdx.x & 31) * 64;
        short* ks = (short*)smem;
        short* vs = ks + 128 * SWROWPAD;
        float* ps = (float*)(vs + 128 * SWROWPAD);
        int basek = q0 - 63;
        for (int idx = tid; idx < 127 * 8; idx += 256) {
            int row = idx >> 3, ch = (idx & 7) * 8;
            int kpos = basek + row;
            uint4 kv = (uint4){0u, 0u, 0u, 0u}, vv = (uint4){0u, 0u, 0u, 0u};
            if (kpos >= 0) {
                kv = *(const uint4*)(rk + ((size_t)h * NTOK + kpos) * 64 + ch);
                vv = *(const uint4*)(vt + ((size_t)h * NTOK + kpos) * 64 + ch);
            }
            *(uint4*)&ks[row * SWROWPAD + ch] = kv;
            *(uint4*)&vs[row * SWROWPAD + ch] = vv;
        }
        __syncthreads();
        float* p0 = ps + ws * 128;
        float* p1 = p0 + 64;
#pragma unroll 1
        for (int tq = 0; tq < 16; tq++) {
            int i = q0 + ws * 16 + tq;
            int ibase = ws * 16 + tq;
            const float* q0p = rq + ((size_t)(h * 2 + 0) * NTOK + i) * 64 + c * 16;
            const float* q1p = rq + ((size_t)(h * 2 + 1) * NTOK + i) * 64 + c * 16;
            float4 qa[4], qb[4];
#pragma unroll
            for (int u = 0; u < 4; u++) {
                qa[u] = *(const float4*)(q0p + u * 4);
                qb[u] = *(const float4*)(q1p + u * 4);
            }
#pragma unroll
            for (int kt = 0; kt < 4; kt++) {
                int key = kt * 16 + kq;
                const short* kr = &ks[(ibase + key) * SWROWPAD + c * 16];
                float s0 = 0.f, s1 = 0.f;
                uint4 a = *(const uint4*)(kr);
                uint4 b = *(const uint4*)(kr + 8);
                dot8(qa[0], qa[1], a, s0); dot8(qa[2], qa[3], b, s0);
                dot8(qb[0], qb[1], a, s1); dot8(qb[2], qb[3], b, s1);
                s0 += __shfl_xor(s0, 1); s0 += __shfl_xor(s0, 2);
                s1 += __shfl_xor(s1, 1); s1 += __shfl_xor(s1, 2);
                int kpos = i - 63 + key;
                if (c == 0) {
                    p0[key] = (kpos >= 0) ? s0 * SCALE : NEG10F;
                    p1[key] = (kpos >= 0) ? s1 * SCALE : NEG10F;
                }
            }
            // wave-local softmax over 64 (same-wave LDS ordering is program-order)
            {
                float a0 = p0[lane], a1 = p1[lane];
                float m0 = a0, m1 = a1;
#pragma unroll
                for (int o = 1; o < 64; o <<= 1) {
                    m0 = fmaxf(m0, __shfl_xor(m0, o));
                    m1 = fmaxf(m1, __shfl_xor(m1, o));
                }
                float e0 = __expf(a0 - m0), e1 = __expf(a1 - m1);
                float d0 = e0, d1 = e1;
#pragma unroll
                for (int o = 1; o < 64; o <<= 1) {
                    d0 += __shfl_xor(d0, o);
                    d1 += __shfl_xor(d1, o);
                }
                p0[lane] = e0 / d0;
                p1[lane] = e1 / d1;
            }
            float o0[8] = {}, o1[8] = {};
#pragma unroll
            for (int pass = 0; pass < 8; pass++) {
                int j = pass * 8 + kv8;
                uint4 v = *(const uint4*)&vs[(ibase + j) * SWROWPAD + c8 * 8];
                float pa = p0[j], pb = p1[j];
                float e0 = bflo(v.x), e1 = bfhi(v.x), e2 = bflo(v.y), e3 = bfhi(v.y);
                float e4 = bflo(v.z), e5 = bfhi(v.z), e6 = bflo(v.w), e7 = bfhi(v.w);
                o0[0] = fmaf(pa, e0, o0[0]); o0[1] = fmaf(pa, e1, o0[1]);
                o0[2] = fmaf(pa, e2, o0[2]); o0[3] = fmaf(pa, e3, o0[3]);
                o0[4] = fmaf(pa, e4, o0[4]); o0[5] = fmaf(pa, e5, o0[5]);
                o0[6] = fmaf(pa, e6, o0[6]); o0[7] = fmaf(pa, e7, o0[7]);
                o1[0] = fmaf(pb, e0, o1[0]); o1[1] = fmaf(pb, e1, o1[1]);
                o1[2] = fmaf(pb, e2, o1[2]); o1[3] = fmaf(pb, e3, o1[3]);
                o1[4] = fmaf(pb, e4, o1[4]); o1[5] = fmaf(pb, e5, o1[5]);
                o1[6] = fmaf(pb, e6, o1[6]); o1[7] = fmaf(pb, e7, o1[7]);
            }
#pragma unroll
            for (int o = 8; o <= 32; o <<= 1)
#pragma unroll
                for (int d = 0; d < 8; d++) {
                    o0[d] += __shfl_xor(o0[d], o);
                    o1[d] += __shfl_xor(o1[d], o);
                }
            if (kv8 == 0) {
                float* s0p = sout + ((size_t)(h * 2 + 0) * NTOK + i) * 64 + c8 * 8;
                float* s1p = sout + ((size_t)(h * 2 + 1) * NTOK + i) * 64 + c8 * 8;
                *(float4*)(s0p) = (float4){o0[0], o0[1], o0[2], o0[3]};
                *(float4*)(s0p + 4) = (float4){o0[4], o0[5], o0[6], o0[7]};
                *(float4*)(s1p) = (float4){o1[0], o1[1], o1[2], o1[3]};
                *(float4*)(s1p + 4) = (float4){o1[4], o1[5], o1[6], o1[7]};
            }
        }
    } else {
        // ---------- fine attention (wave per query) ----------
        float* spbase = (float*)smem;
        float* p0 = spbase + ws * 320;
        float* p1 = p0 + 160;
        int wid = (blockIdx.x - 256) * 4 + ws;
        int h = wid >> 11, i = wid & 2047;
        if (lane < 5) sel[ws][lane] = selidx[((size_t)h * NTOK + i) * 5 + lane];
        if (lane == 5) smk[ws] = selmask[h * NTOK + i];

        const float* q0p = rq + ((size_t)(h * 2 + 0) * NTOK + i) * 64 + c * 16;
        const float* q1p = rq + ((size_t)(h * 2 + 1) * NTOK + i) * 64 + c * 16;
        float4 q0[4], q1[4];
#pragma unroll
        for (int u = 0; u < 4; u++) {
            q0[u] = *(const float4*)(q0p + u * 4);
            q1[u] = *(const float4*)(q1p + u * 4);
        }
        __syncthreads();
        int mk = smk[ws];
        int iq = i & 31;
#pragma unroll
        for (int kt = 0; kt < 10; kt++) {
            int slot = kt >> 1;
            int blk = sel[ws][slot];
            int key = kt * 16 + kq;
            int jj = key & 31;
            int kpos = blk * 32 + jj;
            bool valid = (slot < 4) ? (((mk >> slot) & 1) != 0) : (jj <= iq);
            const __hip_bfloat16* kr = rk + ((size_t)h * NTOK + kpos) * 64 + c * 16;
            float s0 = 0.f, s1 = 0.f;
            uint4 a = *(const uint4*)(kr);
            uint4 b = *(const uint4*)(kr + 8);
            dot8(q0[0], q0[1], a, s0); dot8(q0[2], q0[3], b, s0);
            dot8(q1[0], q1[1], a, s1); dot8(q1[2], q1[3], b, s1);
            s0 += __shfl_xor(s0, 1); s0 += __shfl_xor(s0, 2);
            s1 += __shfl_xor(s1, 1); s1 += __shfl_xor(s1, 2);
            if (c == 0) {
                p0[key] = valid ? s0 * SCALE : NEG10F;
                p1[key] = valid ? s1 * SCALE : NEG10F;
            }
        }
        __syncthreads();
        {
            float a0 = p0[lane], b0 = p0[lane + 64];
            float c0 = (lane < 32) ? p0[lane + 128] : NEG10F;
            float a1 = p1[lane], b1 = p1[lane + 64];
            float c1 = (lane < 32) ? p1[lane + 128] : NEG10F;
            float m0 = fmaxf(fmaxf(a0, b0), c0);
            float m1 = fmaxf(fmaxf(a1, b1), c1);
#pragma unroll
            for (int o = 1; o < 64; o <<= 1) {
                m0 = fmaxf(m0, __shfl_xor(m0, o));
                m1 = fmaxf(m1, __shfl_xor(m1, o));
            }
            float ea0 = __expf(a0 - m0), eb0 = __expf(b0 - m0), ec0 = (lane < 32) ? __expf(c0 - m0) : 0.f;
            float ea1 = __expf(a1 - m1), eb1 = __expf(b1 - m1), ec1 = (lane < 32) ? __expf(c1 - m1) : 0.f;
            float d0 = ea0 + eb0 + ec0;
            float d1 = ea1 + eb1 + ec1;
#pragma unroll
            for (int o = 1; o < 64; o <<= 1) {
                d0 += __shfl_xor(d0, o);
                d1 += __shfl_xor(d1, o);
            }
            float inv0 = 1.f / d0, inv1 = 1.f / d1;
            p0[lane] = ea0 * inv0; p0[lane + 64] = eb0 * inv0;
            p1[lane] = ea1 * inv1; p1[lane + 64] = eb1 * inv1;
            if (lane < 32) { p0[lane + 128] = ec0 * inv0; p1[lane + 128] = ec1 * inv1; }
        }
        __syncthreads();
        float o0[8] = {}, o1[8] = {};
#pragma unroll
        for (int slot = 0; slot < 5; slot++) {
            const __hip_bfloat16* vbase = vt + ((size_t)h * NTOK + sel[ws][slot] * 32) * 64;
#pragma unroll
            for (int pass = 0; pass < 4; pass++) {
                int j = pass * 8 + kv8;
                uint4 v = *(const uint4*)(vbase + j * 64 + c8 * 8);
                float pa = p0[slot * 32 + j], pb = p1[slot * 32 + j];
                float e0 = bflo(v.x), e1 = bfhi(v.x), e2 = bflo(v.y), e3 = bfhi(v.y);
                float e4 = bflo(v.z), e5 = bfhi(v.z), e6 = bflo(v.w), e7 = bfhi(v.w);
                o0[0] = fmaf(pa, e0, o0[0]); o0[1] = fmaf(pa, e1, o0[1]);
                o0[2] = fmaf(pa, e2, o0[2]); o0[3] = fmaf(pa, e3, o0[3]);
                o0[4] = fmaf(pa, e4, o0[4]); o0[5] = fmaf(pa, e5, o0[5]);
                o0[6] = fmaf(pa, e6, o0[6]); o0[7] = fmaf(pa, e7, o0[7]);
                o1[0] = fmaf(pb, e0, o1[0]); o1[1] = fmaf(pb, e1, o1[1]);
                o1[2] = fmaf(pb, e2, o1[2]); o1[3] = fmaf(pb, e3, o1[3]);
                o1[4] = fmaf(pb, e4, o1[4]); o1[5] = fmaf(pb, e5, o1[5]);
                o1[6] = fmaf(pb, e6, o1[6]); o1[7] = fmaf(pb, e7, o1[7]);
            }
        }
#pragma unroll
        for (int o = 8; o <= 32; o <<= 1)
#pragma unroll
            for (int d = 0; d < 8; d++) {
                o0[d] += __shfl_xor(o0[d], o);
                o1[d] += __shfl_xor(o1[d], o);
            }
        if (kv8 == 0) {
            float* f0 = fout + ((size_t)(h * 2 + 0) * NTOK + i) * 64 + c8 * 8;
            float* f1 = fout + ((size_t)(h * 2 + 1) * NTOK + i) * 64 + c8 * 8;
            *(float4*)(f0) = (float4){o0[0], o0[1], o0[2], o0[3]};
            *(float4*)(f0 + 4) = (float4){o0[4], o0[5], o0[6], o0[7]};
            *(float4*)(f1) = (float4){o1[0], o1[1], o1[2], o1[3]};
            *(float4*)(f1 + 4) = (float4){o1[4], o1[5], o1[6], o1[7]};
        }
    }
}

// ---------------- Gated combine (sigmoid applied here; writes bf16) ----------------
__global__ __launch_bounds__(256) void combine_kernel(const float* __restrict__ gateslin,
                                                      const float* __restrict__ cout,
                                                      const float* __restrict__ fout,
                                                      const float* __restrict__ sout,
                                                      __hip_bfloat16* __restrict__ att) {
    int n = blockIdx.x;
    for (int c = threadIdx.x; c < NH * HD; c += 256) {
        int hd = c >> 6, d = c & 63;
        float g0 = 1.f / (1.f + expf(-gateslin[(size_t)n * (NH * 3) + hd * 3 + 0]));
        float g1 = 1.f / (1.f + expf(-gateslin[(size_t)n * (NH * 3) + hd * 3 + 1]));
        float g2 = 1.f / (1.f + expf(-gateslin[(size_t)n * (NH * 3) + hd * 3 + 2]));
        size_t o = ((size_t)hd * NTOK + n) * HD + d;
        att[(size_t)n * (NH * HD) + c] =
            __float2bfloat16(g0 * cout[o] + g1 * fout[o] + g2 * sout[o]);
    }
}

extern "C" void kernel_launch(void* const* d_in, const int* in_sizes, int n_in,
                              void* d_out, int out_size, void* d_ws, size_t ws_size,
                              hipStream_t stream) {
    const float* inp    = (const float*)d_in[0];
    const float* norm_g = (const float*)d_in[1];
    const float* Wqkv   = (const float*)d_in[2];
    const float* mem_kv = (const float*)d_in[3];
    const float* k_pos  = (const float*)d_in[4];
    const float* v_pos  = (const float*)d_in[5];
    const float* kW1    = (const float*)d_in[6];
    const float* kb1    = (const float*)d_in[7];
    const float* kW2    = (const float*)d_in[8];
    const float* kb2    = (const float*)d_in[9];
    const float* vW1    = (const float*)d_in[10];
    const float* vb1    = (const float*)d_in[11];
    const float* vW2    = (const float*)d_in[12];
    const float* vb2    = (const float*)d_in[13];
    const float* combW  = (const float*)d_in[14];
    const float* combB  = (const float*)d_in[15];
    const float* Wout   = (const float*)d_in[16];
    float* out = (float*)d_out;

    char* base = (char*)d_ws;
    size_t off = 0;
    auto alloc = [&](size_t bytes) {
        void* p = base + off;
        off += (bytes + 255) & ~(size_t)255;
        return p;
    };
    float* x            = (float*)alloc((size_t)NTOK * DIM * 4);
    __hip_bfloat16* xb  = (__hip_bfloat16*)alloc((size_t)NTOK * DIM * 2);
    float* qkv          = (float*)alloc((size_t)NTOK * 2048 * 4);
    __hip_bfloat16* Wqkvt = (__hip_bfloat16*)alloc((size_t)2048 * 1024 * 2);
    __hip_bfloat16* kW1t  = (__hip_bfloat16*)alloc((size_t)2048 * 2048 * 2);
    __hip_bfloat16* vW1t  = (__hip_bfloat16*)alloc((size_t)2048 * 2048 * 2);
    __hip_bfloat16* Woutt = (__hip_bfloat16*)alloc((size_t)1024 * 1024 * 2);
    __hip_bfloat16* combWt = (__hip_bfloat16*)alloc((size_t)48 * 1024 * 2);
    __hip_bfloat16* kW2t  = (__hip_bfloat16*)alloc((size_t)64 * 2048 * 2);
    __hip_bfloat16* vW2t  = (__hip_bfloat16*)alloc((size_t)64 * 2048 * 2);
    __hip_bfloat16* kwflat = (__hip_bfloat16*)alloc((size_t)KVH * NCB * HIDN * 2);
    __hip_bfloat16* vwflat = (__hip_bfloat16*)alloc((size_t)KVH * NCB * HIDN * 2);
    __hip_bfloat16* hidkb = (__hip_bfloat16*)alloc((size_t)KVH * NCB * HIDN * 2);
    __hip_bfloat16* hidvb = (__hip_bfloat16*)alloc((size_t)KVH * NCB * HIDN * 2);
    float* ckraw        = (float*)alloc((size_t)KVH * NCB * HD * 4);
    float* cvraw        = (float*)alloc((size_t)KVH * NCB * HD * 4);
    float* rq           = (float*)alloc((size_t)NH * NTOK * HD * 4);
    __hip_bfloat16* rk  = (__hip_bfloat16*)alloc((size_t)KVH * NTOK * HD * 2);
    __hip_bfloat16* vt  = (__hip_bfloat16*)alloc((size_t)KVH * NTOK * HD * 2);
    float* coutb        = (float*)alloc((size_t)NH * NTOK * HD * 4);
    float* foutb        = (float*)alloc((size_t)NH * NTOK * HD * 4);
    float* soutb        = (float*)alloc((size_t)NH * NTOK * HD * 4);
    float* gatesb       = (float*)alloc((size_t)NTOK * NH * 3 * 4);
    __hip_bfloat16* attb = (__hip_bfloat16*)alloc((size_t)NTOK * DIM * 2);
    int* selidx         = (int*)alloc((size_t)KVH * NTOK * 5 * 4);
    int* selmask        = (int*)alloc((size_t)KVH * NTOK * 4);
    (void)ws_size; (void)in_sizes; (void)n_in; (void)out_size;

    // 1. rmsnorm + weight transposes + bias inits
    pre_kernel<<<PRE_BLOCKS, 256, 0, stream>>>(inp, norm_g, x, xb,
                                               Wqkv, Wqkvt, kW1, kW1t, vW1, vW1t,
                                               Wout, Woutt, combW, combWt,
                                               kW2, kW2t, vW2, vW2t,
                                               combB, gatesb, kb2, ckraw, vb2, cvraw);
    // 2. qkv GEMM + gates split-K
    qkv_gates_kernel<<<320, 256, 0, stream>>>(xb, Wqkvt, qkv, combWt, gatesb);
    // 3. build compressed windows + RoPE
    winrope_kernel<<<4096 + 2048, 256, 0, stream>>>(qkv, k_pos, v_pos, kwflat, vwflat,
                                                    rq, rk, vt);
    // 4. compressed k/v MLP layer 1
    mfma_gemm_pair<<<dim3(16, 8, 2), 256, 0, stream>>>(kwflat, vwflat, kW1t, vW1t,
                                                       kb1, vb1, hidkb, hidvb,
                                                       1024, 2048, 2048);
    // 5. compressed k/v MLP layer 2 (batched split-K)
    skgemm_pair<<<dim3(2, 8, 8), 256, 0, stream>>>(hidkb, hidvb, kW2t, vW2t,
                                                   ckraw, cvraw, 1024, 64, 2048);
    // 6. compressed attention + importance + fused top-k
    cattn2_kernel<<<KVH * (NTOK / 32), 256, 0, stream>>>(qkv, ckraw, cvraw, mem_kv,
                                                         coutb, selidx, selmask);
    // 7. fused tiled-sliding + fine attention
    attn_fused2_kernel<<<256 + 4096, 256, 0, stream>>>(rq, rk, vt, selidx, selmask,
                                                       foutb, soutb);
    // 8. gated combine
    combine_kernel<<<NTOK, 256, 0, stream>>>(gatesb, coutb, foutb, soutb, attb);
    // 9. out projection
    mfma_gemm<0, 0><<<dim3(8, 16), 256, 0, stream>>>(attb, Woutt, nullptr, out, 2048, 1024, 1024);
}